// Round 7
// baseline (307.230 us; speedup 1.0000x reference)
//
#include <hip/hip_runtime.h>

typedef unsigned short u16;
typedef unsigned int u32;
typedef u16  u16x8 __attribute__((ext_vector_type(8)));
typedef u16  u16x4 __attribute__((ext_vector_type(4)));
typedef u32  u32x4 __attribute__((ext_vector_type(4)));
typedef __bf16 bf16x2 __attribute__((ext_vector_type(2)));
typedef __bf16 bf16x8 __attribute__((ext_vector_type(8)));
typedef float f32x4 __attribute__((ext_vector_type(4)));
typedef float f32x16 __attribute__((ext_vector_type(16)));

// ALiBi prefix window (keys with slope_nat*j > 40 negligible): kb_w per head,
// kb_w = floor(40*2^((h+1)/2)) >> 6. Verified vs round-6 float computation.
__constant__ int KBW[16]  = {0,1,1,2,3,5,7,10,14,20,28,40,56,80,113,160};
// cumulative split-chunk slots before head h (chunks only stored when T>8)
__constant__ int CUMH[16] = {0,0,0,0,0,0,0,0,24,48,80,116,152,188,224,260};
#define TOTCH 296           // total chunk slots per batch
#define CHW   2176          // floats per wave slot: 64*32 o + 64 m + 64 l
#define CHS   (4 * 2176)    // floats per chunk (4 waves)

// fp32 -> bf16 round-to-nearest-even
static __device__ __forceinline__ u16 f2bf(float f) {
  unsigned int u = __float_as_uint(f);
  u += 0x7FFFu + ((u >> 16) & 1u);
  return (u16)(u >> 16);
}

static __device__ __forceinline__ u32 packbf(float a, float b) {
  bf16x2 t;
  t[0] = (__bf16)a;
  t[1] = (__bf16)b;
  return __builtin_bit_cast(u32, t);
}

static __device__ __forceinline__ f32x4 mfma16(bf16x8 a, bf16x8 b, f32x4 c) {
  return __builtin_amdgcn_mfma_f32_16x16x32_bf16(a, b, c, 0, 0, 0);
}
static __device__ __forceinline__ f32x16 mfma32(bf16x8 a, bf16x8 b, f32x16 c) {
  return __builtin_amdgcn_mfma_f32_32x32x16_bf16(a, b, c, 0, 0, 0);
}

static __device__ __forceinline__ void gload16(const void* g, void* lds) {
  __builtin_amdgcn_global_load_lds(
      (const __attribute__((address_space(1))) unsigned int*)g,
      (__attribute__((address_space(3))) unsigned int*)lds, 16, 0, 0);
}

// chunk slot base for (h, qb): CUMH[h] + chunks of earlier qb in same head
static __device__ __forceinline__ int chunk_base(int h, int qb) {
  int s = CUMH[h];
  int kw = KBW[h];
  for (int q2 = 0; q2 < qb; q2++) {
    int T = min(2 * q2 + 1, kw) + 1;
    if (T > 8) s += (T + 7) >> 3;
  }
  return s;
}

// ---------------- cast x (fp32 -> bf16), 8 elems/thread ----------------
__global__ __launch_bounds__(256) void k_cast_x(const float* __restrict__ in,
                                                u16* __restrict__ out) {
  size_t i = (size_t)blockIdx.x * 256 + threadIdx.x;
  const float4* p = reinterpret_cast<const float4*>(in) + i * 2;
  float4 a = p[0], b = p[1];
  u16x8 r;
  r[0] = f2bf(a.x); r[1] = f2bf(a.y); r[2] = f2bf(a.z); r[3] = f2bf(a.w);
  r[4] = f2bf(b.x); r[5] = f2bf(b.y); r[6] = f2bf(b.z); r[7] = f2bf(b.w);
  *reinterpret_cast<u16x8*>(out + i * 8) = r;
}

// ---------------- fold LoRA into weights + cast to bf16 ----------------
__global__ __launch_bounds__(256) void k_fold_w(
    const float* __restrict__ Wq, const float* __restrict__ Aq, const float* __restrict__ Bq,
    const float* __restrict__ Wk, const float* __restrict__ Ak, const float* __restrict__ Bk,
    const float* __restrict__ Wv, const float* __restrict__ Av, const float* __restrict__ Bv,
    const float* __restrict__ Wp, u16* __restrict__ wqkv, u16* __restrict__ wp) {
  int n = blockIdx.x;
  int widx = n >> 10, nr = n & 1023;
  const float *W, *A, *Bm; u16* dst;
  if (widx == 0)      { W = Wq; A = Aq; Bm = Bq; dst = wqkv; }
  else if (widx == 1) { W = Wk; A = Ak; Bm = Bk; dst = wqkv + (1 << 20); }
  else if (widx == 2) { W = Wv; A = Av; Bm = Bv; dst = wqkv + (2 << 20); }
  else                { W = Wp; A = nullptr; Bm = nullptr; dst = wp; }
  int e0 = threadIdx.x * 4;
  float4 w = *reinterpret_cast<const float4*>(W + (size_t)nr * 1024 + e0);
  if (widx < 3) {
    float acx = 0.f, acy = 0.f, acz = 0.f, acw = 0.f;
#pragma unroll
    for (int r = 0; r < 8; r++) {
      float ar = A[nr * 8 + r];
      float4 bm = *reinterpret_cast<const float4*>(Bm + (size_t)r * 1024 + e0);
      acx += ar * bm.x; acy += ar * bm.y; acz += ar * bm.z; acw += ar * bm.w;
    }
    w.x += 2.0f * acx; w.y += 2.0f * acy; w.z += 2.0f * acz; w.w += 2.0f * acw;
  }
  u16x4 r4; r4[0] = f2bf(w.x); r4[1] = f2bf(w.y); r4[2] = f2bf(w.z); r4[3] = f2bf(w.w);
  *reinterpret_cast<u16x4*>(dst + (size_t)nr * 1024 + e0) = r4;
}

// ---------------- GEMM: C[M,N] = A[M,K(lda)] * Bw[N,K]^T ----------------
template<int OUTF32>
__global__ __launch_bounds__(256) void k_gemm_bt(const u16* __restrict__ A,
                                                 const u16* __restrict__ Bw,
                                                 void* __restrict__ C, int K, int N, int lda) {
  __shared__ __align__(16) u16 As[128 * 64];
  __shared__ __align__(16) u16 Bs[128 * 64];
  const int tid = threadIdx.x;
  const int wave = tid >> 6, lane = tid & 63;
  const int l15 = lane & 15, lg = lane >> 4;
  const int m0 = blockIdx.x * 128, n0 = blockIdx.y * 128;
  const int wr = wave >> 1, wc = wave & 1;

  f32x4 acc[4][4];
#pragma unroll
  for (int i = 0; i < 4; i++)
#pragma unroll
    for (int j = 0; j < 4; j++) acc[i][j] = (f32x4)0.0f;

  for (int k0 = 0; k0 < K; k0 += 64) {
#pragma unroll
    for (int i = 0; i < 4; i++) {
      int idx = i * 256 + tid;
      int row = idx >> 3, col = (idx & 7) << 3;
      gload16(A  + (size_t)(m0 + row) * lda + k0 + col, As + (i * 4 + wave) * 512);
      gload16(Bw + (size_t)(n0 + row) * K   + k0 + col, Bs + (i * 4 + wave) * 512);
    }
    __syncthreads();
#pragma unroll
    for (int c = 0; c < 2; c++) {
      bf16x8 af[4], bfr[4];
#pragma unroll
      for (int t = 0; t < 4; t++) {
        af[t]  = *reinterpret_cast<const bf16x8*>(As + (wr * 64 + t * 16 + l15) * 64 + c * 32 + lg * 8);
        bfr[t] = *reinterpret_cast<const bf16x8*>(Bs + (wc * 64 + t * 16 + l15) * 64 + c * 32 + lg * 8);
      }
#pragma unroll
      for (int mi = 0; mi < 4; mi++)
#pragma unroll
        for (int ni = 0; ni < 4; ni++)
          acc[mi][ni] = mfma16(af[mi], bfr[ni], acc[mi][ni]);
    }
    __syncthreads();
  }

  const int rbase = m0 + wr * 64, cbase = n0 + wc * 64;
#pragma unroll
  for (int mi = 0; mi < 4; mi++)
#pragma unroll
    for (int ni = 0; ni < 4; ni++)
#pragma unroll
      for (int j = 0; j < 4; j++) {
        int r  = rbase + mi * 16 + lg * 4 + j;
        int cc = cbase + ni * 16 + l15;
        if constexpr (OUTF32) {
          reinterpret_cast<float*>(C)[(size_t)r * N + cc] = acc[mi][ni][j];
        } else {
          reinterpret_cast<u16*>(C)[(size_t)r * N + cc] = f2bf(acc[mi][ni][j]);
        }
      }
}

// ---------------- V transpose: qkv V-section -> vt[b][h][d][t] ----------------
__global__ __launch_bounds__(256) void k_vt(const u16* __restrict__ qkv,
                                            u16* __restrict__ vt) {
  __shared__ __align__(16) u16 tile[64 * 64];
  const int tb = blockIdx.x, h = blockIdx.y, b = blockIdx.z;
  const int tid = threadIdx.x;
  const size_t rb = (size_t)b * 2048;
  const int hv = 2048 + h * 64;
#pragma unroll
  for (int p = 0; p < 2; p++) {
    int r = p * 32 + (tid >> 3);
    int c = (tid & 7) * 8;
    u16x8 v = *reinterpret_cast<const u16x8*>(qkv + (rb + tb * 64 + r) * 3072 + hv + c);
    int slot = (c >> 3) ^ (r & 7) ^ ((r >> 3) & 7);
    *reinterpret_cast<u16x8*>(tile + r * 64 + slot * 8) = v;
  }
  __syncthreads();
#pragma unroll
  for (int p = 0; p < 2; p++) {
    int d = p * 32 + (tid >> 3);
    int t0 = (tid & 7) * 8;
    u16x8 v;
#pragma unroll
    for (int j = 0; j < 8; j++) {
      int r = t0 + j;
      int slot = (d >> 3) ^ (r & 7) ^ ((r >> 3) & 7);
      v[j] = tile[r * 64 + slot * 8 + (d & 7)];
    }
    *reinterpret_cast<u16x8*>(vt + ((size_t)(b * 16 + h) * 64 + d) * 2048 + tb * 64 + t0) = v;
  }
}

// ---------------- flash attention v4: split-KV chunks of <=8 tiles ----------------
// blockIdx.x = ((h*16)+qb)*4 + c ; blockIdx.y = b.  nchunk = ceil(T/8).
// nchunk==1: final normalized write (in-place, qkv Q-cols). Else: partial
// (o unnorm fp32 in register layout, m,l log2-domain) to workspace; k_combine merges.
__global__ __launch_bounds__(256) void k_attn(const u16* __restrict__ qkv,
                                              const u16* __restrict__ vt,
                                              u16* __restrict__ aout,
                                              float* __restrict__ partials) {
  const int xx = (int)blockIdx.x;
  const int h = xx >> 6, qb = (xx >> 2) & 15, c = xx & 3;
  const int kw = KBW[h];
  const int kend = min(2 * qb + 1, kw);
  const int T = kend + 1;
  const int nch = (T + 7) >> 3;
  if (c >= nch) return;
  const int t0 = c * 8;
  const int t1 = min(t0 + 8, T);

  __shared__ __align__(16) u16 Kl[2][64 * 64];   // [key][d], swizzled 16B slots
  __shared__ __align__(16) u16 Vl[2][64 * 64];   // [d][key], same swizzle
  const int tid = threadIdx.x, wave = tid >> 6, lane = tid & 63;
  const int l31 = lane & 31, half = lane >> 5;
  const int b = blockIdx.y;
  const int rb = b * 2048;
  const int hq = h * 64, hk = 1024 + h * 64;
  const int bh64 = (b * 16 + h) * 64;
  const int qB = qb * 128;
  const int q0w = qB + wave * 32;
  const int q = q0w + l31;

  // Q as B-fragment: col=q=l31, inner d = chunk*16 + half*8
  bf16x8 qf[4];
#pragma unroll
  for (int cc = 0; cc < 4; cc++)
    qf[cc] = *reinterpret_cast<const bf16x8*>(qkv + (size_t)(rb + q) * 3072 + hq + cc * 16 + half * 8);

  const float slope2 = exp2f(-0.5f * (float)(h + 1)) * 1.44269504f;  // nats->log2 folded
  const float c0 = 0.18033688f;                                       // 0.125*log2(e)

  float mrun = -1e30f, lrun = 0.f;
  f32x16 o0 = (f32x16)0.0f, o1 = (f32x16)0.0f;

  auto stage = [&](int kvr, int dst) {
#pragma unroll
    for (int i = 0; i < 2; i++) {
      int row = (i * 4 + wave) * 8 + (lane >> 3);
      int scol = ((lane & 7) ^ (row & 7)) << 3;
      gload16(qkv + (size_t)(rb + kvr + row) * 3072 + hk + scol, &Kl[dst][(i * 4 + wave) * 512]);
      gload16(vt + (size_t)(bh64 + row) * 2048 + kvr + scol,     &Vl[dst][(i * 4 + wave) * 512]);
    }
  };

  stage(t0 * 64, 0);
  __syncthreads();

  int bfi = 0;
  for (int kb = t0; kb < t1; ++kb, bfi ^= 1) {
    const int kvr = kb * 64;
    if (kb + 1 < t1) stage(kvr + 64, bfi ^ 1);   // issue next tile's loads early

    if (kvr <= q0w + 31) {   // wave-uniform: tile intersects this wave's causal range
      // ---- S^T = K * Q : s[t] covers k = t*32.., col=q=l31 ----
      f32x16 s[2];
#pragma unroll
      for (int t = 0; t < 2; t++) s[t] = (f32x16)0.0f;
      __builtin_amdgcn_s_setprio(1);
#pragma unroll
      for (int t = 0; t < 2; t++) {
        int r = t * 32 + l31;
#pragma unroll
        for (int cc = 0; cc < 4; cc++) {
          bf16x8 kf = *reinterpret_cast<const bf16x8*>(
              &Kl[bfi][r * 64 + (((cc * 2 + half) ^ (r & 7)) << 3)]);
          s[t] = mfma32(kf, qf[cc], s[t]);
        }
      }
      __builtin_amdgcn_s_setprio(0);

      // ---- scale + alibi (+ mask on diagonal tiles); row max ----
      const bool domask = (kvr + 63 > q0w);
      const int qrel = q - kvr - half * 4;
      const float qb0 = slope2 * (float)qrel;
      const float qb1 = qb0 - slope2 * 32.0f;
      float mt = -1e30f;
#pragma unroll
      for (int t = 0; t < 2; t++) {
        const float qbt = t ? qb1 : qb0;
        const int qmt = t ? (qrel - 32) : qrel;
#pragma unroll
        for (int r = 0; r < 16; r++) {
          const int krel = (r & 3) + 8 * (r >> 2);
          float val = fmaf(s[t][r], c0, fmaf(-slope2, (float)krel, qbt));
          if (domask) val = (krel <= qmt) ? val : -3.0e38f;
          s[t][r] = val;
          mt = fmaxf(mt, val);
        }
      }
      mt = fmaxf(mt, __shfl_xor(mt, 32));

      // defer-max: rescale only when max grew materially (rare: bias decays with kb)
      if (__any(mt - mrun > 8.0f)) {
        float mn = fmaxf(mrun, mt);
        float al = exp2f(mrun - mn);
        mrun = mn; lrun *= al;
#pragma unroll
        for (int r = 0; r < 16; r++) { o0[r] *= al; o1[r] *= al; }
      }

      float rs0 = 0.f, rs1 = 0.f;
#pragma unroll
      for (int t = 0; t < 2; t++)
#pragma unroll
        for (int r = 0; r < 16; r++) {
          float p = exp2f(s[t][r] - mrun);
          s[t][r] = p;
          if (t) rs1 += p; else rs0 += p;
        }
      float rs = rs0 + rs1;
      rs += __shfl_xor(rs, 32);
      lrun += rs;

      // ---- P -> bf16 fragments in-register (cvt_pk + permlane32_swap) ----
      bf16x8 pf[4];
#pragma unroll
      for (int t = 0; t < 2; t++)
#pragma unroll
        for (int hs = 0; hs < 2; hs++) {
          u32 A0 = packbf(s[t][8 * hs + 0], s[t][8 * hs + 1]);
          u32 B0 = packbf(s[t][8 * hs + 2], s[t][8 * hs + 3]);
          u32 C0 = packbf(s[t][8 * hs + 4], s[t][8 * hs + 5]);
          u32 D0 = packbf(s[t][8 * hs + 6], s[t][8 * hs + 7]);
          asm volatile("v_permlane32_swap_b32 %0, %1" : "+v"(A0), "+v"(C0));
          asm volatile("v_permlane32_swap_b32 %0, %1" : "+v"(B0), "+v"(D0));
          u32x4 fr; fr[0] = A0; fr[1] = B0; fr[2] = C0; fr[3] = D0;
          pf[t * 2 + hs] = __builtin_bit_cast(bf16x8, fr);
        }

      // ---- O^T += V^T * P^T : o[dblk] rows d, col=q=l31 ----
      __builtin_amdgcn_s_setprio(1);
#pragma unroll
      for (int dblk = 0; dblk < 2; dblk++) {
        int r = dblk * 32 + l31;
#pragma unroll
        for (int kc = 0; kc < 4; kc++) {
          bf16x8 vf = *reinterpret_cast<const bf16x8*>(
              &Vl[bfi][r * 64 + (((kc * 2 + half) ^ (r & 7)) << 3)]);
          if (dblk) o1 = mfma32(vf, pf[kc], o1);
          else      o0 = mfma32(vf, pf[kc], o0);
        }
      }
      __builtin_amdgcn_s_setprio(0);
    }
    __syncthreads();
  }

  if (nch == 1) {
    const float linv = 1.0f / lrun;
#pragma unroll
    for (int dblk = 0; dblk < 2; dblk++)
#pragma unroll
      for (int rg = 0; rg < 4; rg++) {
        int d0 = dblk * 32 + 8 * rg + 4 * half;
        u16x4 r4;
#pragma unroll
        for (int j = 0; j < 4; j++) {
          float v = (dblk ? o1[rg * 4 + j] : o0[rg * 4 + j]) * linv;
          r4[j] = f2bf(v);
        }
        *reinterpret_cast<u16x4*>(aout + (size_t)(rb + q) * 3072 + hq + d0) = r4;
      }
  } else {
    const int cbase = chunk_base(h, qb);
    float* pw = partials + (((size_t)b * TOTCH + cbase + c) * 4 + wave) * CHW;
    f32x4* po = reinterpret_cast<f32x4*>(pw + lane * 32);
#pragma unroll
    for (int k = 0; k < 4; k++) {
      f32x4 v0, v1;
#pragma unroll
      for (int j = 0; j < 4; j++) { v0[j] = o0[k * 4 + j]; v1[j] = o1[k * 4 + j]; }
      po[k] = v0;
      po[4 + k] = v1;
    }
    pw[2048 + lane] = mrun;
    pw[2112 + lane] = lrun;
  }
}

// ---------------- combine split-KV partials ----------------
// grid (256 = h*16+qb, 4 = b); merges <=4 chunks element-wise in the shared
// register layout, normalizes, writes bf16 in-place to qkv Q-cols.
__global__ __launch_bounds__(256) void k_combine(const float* __restrict__ partials,
                                                 u16* __restrict__ aout) {
  const int x = (int)blockIdx.x, b = blockIdx.y;
  const int h = x >> 4, qb = x & 15;
  const int kw = KBW[h];
  const int T = min(2 * qb + 1, kw) + 1;
  const int nch = (T + 7) >> 3;
  if (nch == 1) return;
  const int tid = threadIdx.x, wave = tid >> 6, lane = tid & 63;
  const int l31 = lane & 31, half = lane >> 5;
  const int cbase = chunk_base(h, qb);
  const float* pb = partials + (((size_t)b * TOTCH + cbase) * 4 + wave) * CHW;

  float ms = -3.0e38f;
  for (int cc = 0; cc < nch; cc++)
    ms = fmaxf(ms, pb[(size_t)cc * CHS + 2048 + lane]);

  f32x4 acc[8];
#pragma unroll
  for (int k = 0; k < 8; k++) acc[k] = (f32x4)0.0f;
  float lsum = 0.f;
  for (int cc = 0; cc < nch; cc++) {
    const float* pc = pb + (size_t)cc * CHS;
    float w = exp2f(pc[2048 + lane] - ms);
    lsum += pc[2112 + lane] * w;
    const f32x4* pv = reinterpret_cast<const f32x4*>(pc + lane * 32);
#pragma unroll
    for (int k = 0; k < 8; k++) acc[k] += pv[k] * w;
  }
  const float linv = 1.0f / lsum;

  const int rb = b * 2048, hq = h * 64;
  const int q = qb * 128 + wave * 32 + l31;
#pragma unroll
  for (int dblk = 0; dblk < 2; dblk++)
#pragma unroll
    for (int rg = 0; rg < 4; rg++) {
      int d0 = dblk * 32 + 8 * rg + 4 * half;
      u16x4 r4;
#pragma unroll
      for (int j = 0; j < 4; j++)
        r4[j] = f2bf(acc[dblk * 4 + rg][j] * linv);
      *reinterpret_cast<u16x4*>(aout + (size_t)(rb + q) * 3072 + hq + d0) = r4;
    }
}

extern "C" void kernel_launch(void* const* d_in, const int* in_sizes, int n_in,
                              void* d_out, int out_size, void* d_ws, size_t ws_size,
                              hipStream_t stream) {
  (void)in_sizes; (void)n_in; (void)out_size; (void)ws_size;
  const float* x  = (const float*)d_in[0];
  const float* Wq = (const float*)d_in[1];
  const float* Aq = (const float*)d_in[2];
  const float* Bq = (const float*)d_in[3];
  const float* Wk = (const float*)d_in[4];
  const float* Ak = (const float*)d_in[5];
  const float* Bk = (const float*)d_in[6];
  const float* Wv = (const float*)d_in[7];
  const float* Av = (const float*)d_in[8];
  const float* Bv = (const float*)d_in[9];
  const float* Wp = (const float*)d_in[10];

  char* ws = (char*)d_ws;
  u16* xb   = (u16*)(ws);                  // [8192][1024] bf16 (dead after gemm1)
  u16* wqkv = (u16*)(ws + 16777216);       // [3072][1024] bf16
  u16* wp   = (u16*)(ws + 23068672);       // [1024][1024] bf16
  u16* qkv  = (u16*)(ws + 25165824);       // [8192][3072] bf16
  u16* vt   = xb;                          // [4][16][64][2048] bf16, reuses xb
  float* partials = (float*)(ws + 75497472); // 4*296 chunks * 34816 B ~= 39.3MB
  float* out = (float*)d_out;

  k_cast_x<<<dim3(4096), dim3(256), 0, stream>>>(x, xb);
  k_fold_w<<<dim3(4096), dim3(256), 0, stream>>>(Wq, Aq, Bq, Wk, Ak, Bk, Wv, Av, Bv, Wp, wqkv, wp);
  k_gemm_bt<0><<<dim3(64, 24), dim3(256), 0, stream>>>(xb, wqkv, (void*)qkv, 1024, 3072, 1024);
  k_vt<<<dim3(32, 16, 4), dim3(256), 0, stream>>>(qkv, vt);
  // attention writes its output into qkv's Q-columns (in-place, stride 3072)
  k_attn<<<dim3(1024, 4), dim3(256), 0, stream>>>(qkv, vt, qkv, partials);
  k_combine<<<dim3(256, 4), dim3(256), 0, stream>>>(partials, qkv);
  k_gemm_bt<1><<<dim3(64, 8), dim3(256), 0, stream>>>(qkv, wp, (void*)out, 1024, 1024, 3072);
}

// Round 8
// 249.918 us; speedup vs baseline: 1.2293x; 1.2293x over previous
//
#include <hip/hip_runtime.h>

typedef unsigned short u16;
typedef unsigned int u32;
typedef u16  u16x8 __attribute__((ext_vector_type(8)));
typedef u16  u16x4 __attribute__((ext_vector_type(4)));
typedef u32  u32x4 __attribute__((ext_vector_type(4)));
typedef __bf16 bf16x2 __attribute__((ext_vector_type(2)));
typedef __bf16 bf16x8 __attribute__((ext_vector_type(8)));
typedef float f32x4 __attribute__((ext_vector_type(4)));
typedef float f32x16 __attribute__((ext_vector_type(16)));

// ALiBi prefix window (keys with slope_nat*j > 40 negligible): kb_w per head,
// kb_w = floor(40*2^((h+1)/2)) >> 6.
__constant__ int KBW[16]  = {0,1,1,2,3,5,7,10,14,20,28,40,56,80,113,160};

// fp32 -> bf16 round-to-nearest-even
static __device__ __forceinline__ u16 f2bf(float f) {
  unsigned int u = __float_as_uint(f);
  u += 0x7FFFu + ((u >> 16) & 1u);
  return (u16)(u >> 16);
}

static __device__ __forceinline__ u32 packbf(float a, float b) {
  bf16x2 t;
  t[0] = (__bf16)a;
  t[1] = (__bf16)b;
  return __builtin_bit_cast(u32, t);
}

static __device__ __forceinline__ f32x4 mfma16(bf16x8 a, bf16x8 b, f32x4 c) {
  return __builtin_amdgcn_mfma_f32_16x16x32_bf16(a, b, c, 0, 0, 0);
}
static __device__ __forceinline__ f32x16 mfma32(bf16x8 a, bf16x8 b, f32x16 c) {
  return __builtin_amdgcn_mfma_f32_32x32x16_bf16(a, b, c, 0, 0, 0);
}

static __device__ __forceinline__ void gload16(const void* g, void* lds) {
  __builtin_amdgcn_global_load_lds(
      (const __attribute__((address_space(1))) unsigned int*)g,
      (__attribute__((address_space(3))) unsigned int*)lds, 16, 0, 0);
}

// ---------------- cast x (fp32 -> bf16), 8 elems/thread ----------------
__global__ __launch_bounds__(256) void k_cast_x(const float* __restrict__ in,
                                                u16* __restrict__ out) {
  size_t i = (size_t)blockIdx.x * 256 + threadIdx.x;
  const float4* p = reinterpret_cast<const float4*>(in) + i * 2;
  float4 a = p[0], b = p[1];
  u16x8 r;
  r[0] = f2bf(a.x); r[1] = f2bf(a.y); r[2] = f2bf(a.z); r[3] = f2bf(a.w);
  r[4] = f2bf(b.x); r[5] = f2bf(b.y); r[6] = f2bf(b.z); r[7] = f2bf(b.w);
  *reinterpret_cast<u16x8*>(out + i * 8) = r;
}

// ---------------- fold LoRA into weights + cast to bf16 ----------------
__global__ __launch_bounds__(256) void k_fold_w(
    const float* __restrict__ Wq, const float* __restrict__ Aq, const float* __restrict__ Bq,
    const float* __restrict__ Wk, const float* __restrict__ Ak, const float* __restrict__ Bk,
    const float* __restrict__ Wv, const float* __restrict__ Av, const float* __restrict__ Bv,
    const float* __restrict__ Wp, u16* __restrict__ wqkv, u16* __restrict__ wp) {
  int n = blockIdx.x;
  int widx = n >> 10, nr = n & 1023;
  const float *W, *A, *Bm; u16* dst;
  if (widx == 0)      { W = Wq; A = Aq; Bm = Bq; dst = wqkv; }
  else if (widx == 1) { W = Wk; A = Ak; Bm = Bk; dst = wqkv + (1 << 20); }
  else if (widx == 2) { W = Wv; A = Av; Bm = Bv; dst = wqkv + (2 << 20); }
  else                { W = Wp; A = nullptr; Bm = nullptr; dst = wp; }
  int e0 = threadIdx.x * 4;
  float4 w = *reinterpret_cast<const float4*>(W + (size_t)nr * 1024 + e0);
  if (widx < 3) {
    float acx = 0.f, acy = 0.f, acz = 0.f, acw = 0.f;
#pragma unroll
    for (int r = 0; r < 8; r++) {
      float ar = A[nr * 8 + r];
      float4 bm = *reinterpret_cast<const float4*>(Bm + (size_t)r * 1024 + e0);
      acx += ar * bm.x; acy += ar * bm.y; acz += ar * bm.z; acw += ar * bm.w;
    }
    w.x += 2.0f * acx; w.y += 2.0f * acy; w.z += 2.0f * acz; w.w += 2.0f * acw;
  }
  u16x4 r4; r4[0] = f2bf(w.x); r4[1] = f2bf(w.y); r4[2] = f2bf(w.z); r4[3] = f2bf(w.w);
  *reinterpret_cast<u16x4*>(dst + (size_t)nr * 1024 + e0) = r4;
}

// ---------------- GEMM: C[M,N] = A[M,K(lda)] * Bw[N,K]^T ----------------
template<int OUTF32>
__global__ __launch_bounds__(256) void k_gemm_bt(const u16* __restrict__ A,
                                                 const u16* __restrict__ Bw,
                                                 void* __restrict__ C, int K, int N, int lda) {
  __shared__ __align__(16) u16 As[128 * 64];
  __shared__ __align__(16) u16 Bs[128 * 64];
  const int tid = threadIdx.x;
  const int wave = tid >> 6, lane = tid & 63;
  const int l15 = lane & 15, lg = lane >> 4;
  const int m0 = blockIdx.x * 128, n0 = blockIdx.y * 128;
  const int wr = wave >> 1, wc = wave & 1;

  f32x4 acc[4][4];
#pragma unroll
  for (int i = 0; i < 4; i++)
#pragma unroll
    for (int j = 0; j < 4; j++) acc[i][j] = (f32x4)0.0f;

  for (int k0 = 0; k0 < K; k0 += 64) {
#pragma unroll
    for (int i = 0; i < 4; i++) {
      int idx = i * 256 + tid;
      int row = idx >> 3, col = (idx & 7) << 3;
      gload16(A  + (size_t)(m0 + row) * lda + k0 + col, As + (i * 4 + wave) * 512);
      gload16(Bw + (size_t)(n0 + row) * K   + k0 + col, Bs + (i * 4 + wave) * 512);
    }
    __syncthreads();
#pragma unroll
    for (int c = 0; c < 2; c++) {
      bf16x8 af[4], bfr[4];
#pragma unroll
      for (int t = 0; t < 4; t++) {
        af[t]  = *reinterpret_cast<const bf16x8*>(As + (wr * 64 + t * 16 + l15) * 64 + c * 32 + lg * 8);
        bfr[t] = *reinterpret_cast<const bf16x8*>(Bs + (wc * 64 + t * 16 + l15) * 64 + c * 32 + lg * 8);
      }
#pragma unroll
      for (int mi = 0; mi < 4; mi++)
#pragma unroll
        for (int ni = 0; ni < 4; ni++)
          acc[mi][ni] = mfma16(af[mi], bfr[ni], acc[mi][ni]);
    }
    __syncthreads();
  }

  const int rbase = m0 + wr * 64, cbase = n0 + wc * 64;
#pragma unroll
  for (int mi = 0; mi < 4; mi++)
#pragma unroll
    for (int ni = 0; ni < 4; ni++)
#pragma unroll
      for (int j = 0; j < 4; j++) {
        int r  = rbase + mi * 16 + lg * 4 + j;
        int cc = cbase + ni * 16 + l15;
        if constexpr (OUTF32) {
          reinterpret_cast<float*>(C)[(size_t)r * N + cc] = acc[mi][ni][j];
        } else {
          reinterpret_cast<u16*>(C)[(size_t)r * N + cc] = f2bf(acc[mi][ni][j]);
        }
      }
}

// ---------------- V transpose: qkv V-section -> vt[b][h][d][t] ----------------
__global__ __launch_bounds__(256) void k_vt(const u16* __restrict__ qkv,
                                            u16* __restrict__ vt) {
  __shared__ __align__(16) u16 tile[64 * 64];
  const int tb = blockIdx.x, h = blockIdx.y, b = blockIdx.z;
  const int tid = threadIdx.x;
  const size_t rb = (size_t)b * 2048;
  const int hv = 2048 + h * 64;
#pragma unroll
  for (int p = 0; p < 2; p++) {
    int r = p * 32 + (tid >> 3);
    int c = (tid & 7) * 8;
    u16x8 v = *reinterpret_cast<const u16x8*>(qkv + (rb + tb * 64 + r) * 3072 + hv + c);
    int slot = (c >> 3) ^ (r & 7) ^ ((r >> 3) & 7);
    *reinterpret_cast<u16x8*>(tile + r * 64 + slot * 8) = v;
  }
  __syncthreads();
#pragma unroll
  for (int p = 0; p < 2; p++) {
    int d = p * 32 + (tid >> 3);
    int t0 = (tid & 7) * 8;
    u16x8 v;
#pragma unroll
    for (int j = 0; j < 8; j++) {
      int r = t0 + j;
      int slot = (d >> 3) ^ (r & 7) ^ ((r >> 3) & 7);
      v[j] = tile[r * 64 + slot * 8 + (d & 7)];
    }
    *reinterpret_cast<u16x8*>(vt + ((size_t)(b * 16 + h) * 64 + d) * 2048 + tb * 64 + t0) = v;
  }
}

// ---------------- flash attention v5: depth-2 pipeline, counted vmcnt ----------------
// 3 K/V buffers; one raw s_barrier per tile; vmcnt(4) mid-loop (tile kb landed,
// kb+1 in flight), vmcnt(0) only on the last tile. Heavy-first dispatch.
// QBLK=128 (4 waves x 32 q), KVBLK=64, 32x32x16 MFMA, swapped QK^T and PV,
// in-register softmax (cvt_pk + permlane32_swap), defer-max, ALiBi prefix window.
// Output written in-place into qkv's Q-columns (stride 3072).
__global__ __launch_bounds__(256) void k_attn(const u16* __restrict__ qkv,
                                              const u16* __restrict__ vt,
                                              u16* __restrict__ aout) {
  __shared__ __align__(16) u16 Kl[3][64 * 64];   // [key][d], swizzled 16B slots
  __shared__ __align__(16) u16 Vl[3][64 * 64];   // [d][key], same swizzle
  const int tid = threadIdx.x, wave = tid >> 6, lane = tid & 63;
  const int l31 = lane & 31, half = lane >> 5;
  const int qb = 15 - (int)blockIdx.x, h = 15 - (int)blockIdx.y, b = blockIdx.z;
  const int rb = b * 2048;
  const int hq = h * 64, hk = 1024 + h * 64;
  const int bh64 = (b * 16 + h) * 64;
  const int qB = qb * 128;
  const int q0w = qB + wave * 32;
  const int q = q0w + l31;

  // Q as B-fragment: col=q=l31, inner d = chunk*16 + half*8
  bf16x8 qf[4];
#pragma unroll
  for (int c = 0; c < 4; c++)
    qf[c] = *reinterpret_cast<const bf16x8*>(qkv + (size_t)(rb + q) * 3072 + hq + c * 16 + half * 8);

  const float slope2 = exp2f(-0.5f * (float)(h + 1)) * 1.44269504f;  // nats->log2 folded
  const float c0 = 0.18033688f;                                       // 0.125*log2(e)

  const int kend = min(2 * qb + 1, KBW[h]);                           // block-uniform

  float mrun = -1e30f, lrun = 0.f;
  f32x16 o0 = (f32x16)0.0f, o1 = (f32x16)0.0f;

  auto stage = [&](int kvr, int dst) {
#pragma unroll
    for (int i = 0; i < 2; i++) {
      int row = (i * 4 + wave) * 8 + (lane >> 3);
      int scol = ((lane & 7) ^ (row & 7)) << 3;
      gload16(qkv + (size_t)(rb + kvr + row) * 3072 + hk + scol, &Kl[dst][(i * 4 + wave) * 512]);
      gload16(vt + (size_t)(bh64 + row) * 2048 + kvr + scol,     &Vl[dst][(i * 4 + wave) * 512]);
    }
  };

  // prologue: prefetch depth 2 (tiles 0 and 1), 4 vmem ops per stage per wave
  stage(0, 0);
  if (kend >= 1) stage(64, 1);

  int bfi = 0;  // = kb % 3
  for (int kb = 0; kb <= kend; ++kb) {
    // tile kb's loads landed; keep kb+1's 4 loads in flight (never drain mid-loop)
    if (kb < kend) asm volatile("s_waitcnt vmcnt(4)" ::: "memory");
    else           asm volatile("s_waitcnt vmcnt(0)" ::: "memory");
    // certifies: all waves' kb loads landed AND all waves finished compute kb-1
    asm volatile("s_barrier" ::: "memory");
    // issue next prefetch into the buffer freed by compute kb-1
    if (kb + 2 <= kend) stage((kb + 2) * 64, (bfi + 2 >= 3) ? bfi - 1 : bfi + 2);

    const int kvr = kb * 64;
    if (kvr <= q0w + 31) {   // wave-uniform: tile intersects this wave's causal range
      // ---- S^T = K * Q : s[t] covers k = t*32.., col=q=l31 ----
      f32x16 s[2];
#pragma unroll
      for (int t = 0; t < 2; t++) s[t] = (f32x16)0.0f;
      __builtin_amdgcn_s_setprio(1);
#pragma unroll
      for (int t = 0; t < 2; t++) {
        int r = t * 32 + l31;
#pragma unroll
        for (int cc = 0; cc < 4; cc++) {
          bf16x8 kf = *reinterpret_cast<const bf16x8*>(
              &Kl[bfi][r * 64 + (((cc * 2 + half) ^ (r & 7)) << 3)]);
          s[t] = mfma32(kf, qf[cc], s[t]);
        }
      }
      __builtin_amdgcn_s_setprio(0);

      // ---- scale + alibi (+ mask on diagonal tiles); row max ----
      const bool domask = (kvr + 63 > q0w);
      const int qrel = q - kvr - half * 4;
      const float qb0 = slope2 * (float)qrel;
      const float qb1 = qb0 - slope2 * 32.0f;
      float mt = -1e30f;
#pragma unroll
      for (int t = 0; t < 2; t++) {
        const float qbt = t ? qb1 : qb0;
        const int qmt = t ? (qrel - 32) : qrel;
#pragma unroll
        for (int r = 0; r < 16; r++) {
          const int krel = (r & 3) + 8 * (r >> 2);
          float val = fmaf(s[t][r], c0, fmaf(-slope2, (float)krel, qbt));
          if (domask) val = (krel <= qmt) ? val : -3.0e38f;
          s[t][r] = val;
          mt = fmaxf(mt, val);
        }
      }
      mt = fmaxf(mt, __shfl_xor(mt, 32));

      // defer-max: rescale only when max grew materially (rare: bias decays with kb)
      if (__any(mt - mrun > 8.0f)) {
        float mn = fmaxf(mrun, mt);
        float al = exp2f(mrun - mn);
        mrun = mn; lrun *= al;
#pragma unroll
        for (int r = 0; r < 16; r++) { o0[r] *= al; o1[r] *= al; }
      }

      float rs0 = 0.f, rs1 = 0.f;
#pragma unroll
      for (int t = 0; t < 2; t++)
#pragma unroll
        for (int r = 0; r < 16; r++) {
          float p = exp2f(s[t][r] - mrun);
          s[t][r] = p;
          if (t) rs1 += p; else rs0 += p;
        }
      float rs = rs0 + rs1;
      rs += __shfl_xor(rs, 32);
      lrun += rs;

      // ---- P -> bf16 fragments in-register (cvt_pk + permlane32_swap) ----
      bf16x8 pf[4];
#pragma unroll
      for (int t = 0; t < 2; t++)
#pragma unroll
        for (int hs = 0; hs < 2; hs++) {
          u32 A0 = packbf(s[t][8 * hs + 0], s[t][8 * hs + 1]);
          u32 B0 = packbf(s[t][8 * hs + 2], s[t][8 * hs + 3]);
          u32 C0 = packbf(s[t][8 * hs + 4], s[t][8 * hs + 5]);
          u32 D0 = packbf(s[t][8 * hs + 6], s[t][8 * hs + 7]);
          asm volatile("v_permlane32_swap_b32 %0, %1" : "+v"(A0), "+v"(C0));
          asm volatile("v_permlane32_swap_b32 %0, %1" : "+v"(B0), "+v"(D0));
          u32x4 fr; fr[0] = A0; fr[1] = B0; fr[2] = C0; fr[3] = D0;
          pf[t * 2 + hs] = __builtin_bit_cast(bf16x8, fr);
        }

      // ---- O^T += V^T * P^T : o[dblk] rows d, col=q=l31 ----
      __builtin_amdgcn_s_setprio(1);
#pragma unroll
      for (int dblk = 0; dblk < 2; dblk++) {
        int r = dblk * 32 + l31;
#pragma unroll
        for (int kc = 0; kc < 4; kc++) {
          bf16x8 vf = *reinterpret_cast<const bf16x8*>(
              &Vl[bfi][r * 64 + (((kc * 2 + half) ^ (r & 7)) << 3)]);
          if (dblk) o1 = mfma32(vf, pf[kc], o1);
          else      o0 = mfma32(vf, pf[kc], o0);
        }
      }
      __builtin_amdgcn_s_setprio(0);
    }
    bfi = (bfi == 2) ? 0 : bfi + 1;
  }

  const float linv = 1.0f / lrun;
#pragma unroll
  for (int dblk = 0; dblk < 2; dblk++)
#pragma unroll
    for (int rg = 0; rg < 4; rg++) {
      int d0 = dblk * 32 + 8 * rg + 4 * half;
      u16x4 r4;
#pragma unroll
      for (int j = 0; j < 4; j++) {
        float v = (dblk ? o1[rg * 4 + j] : o0[rg * 4 + j]) * linv;
        r4[j] = f2bf(v);
      }
      *reinterpret_cast<u16x4*>(aout + (size_t)(rb + q) * 3072 + hq + d0) = r4;
    }
}

extern "C" void kernel_launch(void* const* d_in, const int* in_sizes, int n_in,
                              void* d_out, int out_size, void* d_ws, size_t ws_size,
                              hipStream_t stream) {
  (void)in_sizes; (void)n_in; (void)out_size; (void)ws_size;
  const float* x  = (const float*)d_in[0];
  const float* Wq = (const float*)d_in[1];
  const float* Aq = (const float*)d_in[2];
  const float* Bq = (const float*)d_in[3];
  const float* Wk = (const float*)d_in[4];
  const float* Ak = (const float*)d_in[5];
  const float* Bk = (const float*)d_in[6];
  const float* Wv = (const float*)d_in[7];
  const float* Av = (const float*)d_in[8];
  const float* Bv = (const float*)d_in[9];
  const float* Wp = (const float*)d_in[10];

  char* ws = (char*)d_ws;
  u16* xb   = (u16*)(ws);                  // [8192][1024] bf16 (dead after gemm1)
  u16* wqkv = (u16*)(ws + 16777216);       // [3072][1024] bf16
  u16* wp   = (u16*)(ws + 23068672);       // [1024][1024] bf16
  u16* qkv  = (u16*)(ws + 25165824);       // [8192][3072] bf16
  u16* vt   = xb;                          // [4][16][64][2048] bf16, reuses xb
  float* out = (float*)d_out;

  k_cast_x<<<dim3(4096), dim3(256), 0, stream>>>(x, xb);
  k_fold_w<<<dim3(4096), dim3(256), 0, stream>>>(Wq, Aq, Bq, Wk, Ak, Bk, Wv, Av, Bv, Wp, wqkv, wp);
  k_gemm_bt<0><<<dim3(64, 24), dim3(256), 0, stream>>>(xb, wqkv, (void*)qkv, 1024, 3072, 1024);
  k_vt<<<dim3(32, 16, 4), dim3(256), 0, stream>>>(qkv, vt);
  // attention writes its output into qkv's Q-columns (in-place, stride 3072)
  k_attn<<<dim3(16, 16, 4), dim3(256), 0, stream>>>(qkv, vt, qkv);
  k_gemm_bt<1><<<dim3(64, 8), dim3(256), 0, stream>>>(qkv, wp, (void*)out, 1024, 1024, 3072);
}

// Round 9
// 205.780 us; speedup vs baseline: 1.4930x; 1.2145x over previous
//
#include <hip/hip_runtime.h>

typedef unsigned short u16;
typedef unsigned int u32;
typedef u16  u16x8 __attribute__((ext_vector_type(8)));
typedef u16  u16x4 __attribute__((ext_vector_type(4)));
typedef u32  u32x4 __attribute__((ext_vector_type(4)));
typedef __bf16 bf16x2 __attribute__((ext_vector_type(2)));
typedef __bf16 bf16x8 __attribute__((ext_vector_type(8)));
typedef float f32x4 __attribute__((ext_vector_type(4)));
typedef float f32x16 __attribute__((ext_vector_type(16)));

// ALiBi prefix window (keys with slope_nat*j > 40 negligible): kb_w per head,
// kb_w = floor(40*2^((h+1)/2)) >> 6.
__constant__ int KBW[16]  = {0,1,1,2,3,5,7,10,14,20,28,40,56,80,113,160};

// (h,qb) pairs (byte = h*16+qb) sorted by tile count DESCENDING.
// Position p in the flat grid maps to rank {j,127-j,128+j,255-j} for p-chunk
// {0..63,64..127,128..191,192..255}: co-resident blocks (CU period 256 in
// linear ID) get complementary weights; heaviest blocks dispatch first (LPT).
__constant__ unsigned char RANKTBL[256] = {
  0xBF,0xCF,0xDF,0xEF,0xFF,
  0xBE,0xCE,0xDE,0xEE,0xFE,
  0xAE,0xAF,
  0xAD,0xBD,0xCD,0xDD,0xED,0xFD,
  0xAC,0xBC,0xCC,0xDC,0xEC,0xFC,
  0xAB,0xBB,0xCB,0xDB,0xEB,0xFB,
  0xAA,0xBA,0xCA,0xDA,0xEA,0xFA,
  0x9A,0x9B,0x9C,0x9D,0x9E,0x9F,
  0x99,0xA9,0xB9,0xC9,0xD9,0xE9,0xF9,
  0x98,0xA8,0xB8,0xC8,0xD8,0xE8,0xF8,
  0x97,0xA7,0xB7,0xC7,0xD7,0xE7,0xF7,
  0x87,0x88,0x89,0x8A,0x8B,0x8C,0x8D,0x8E,0x8F,
  0x86,0x96,0xA6,0xB6,0xC6,0xD6,0xE6,0xF6,
  0x85,0x95,0xA5,0xB5,0xC5,0xD5,0xE5,0xF5,
  0x75,0x76,0x77,0x78,0x79,0x7A,0x7B,0x7C,0x7D,0x7E,0x7F,
  0x74,0x84,0x94,0xA4,0xB4,0xC4,0xD4,0xE4,0xF4,
  0x63,0x64,0x65,0x66,0x67,0x68,0x69,0x6A,0x6B,0x6C,0x6D,0x6E,0x6F,
  0x73,0x83,0x93,0xA3,0xB3,0xC3,0xD3,0xE3,0xF3,
  0x52,0x53,0x54,0x55,0x56,0x57,0x58,0x59,0x5A,0x5B,0x5C,0x5D,0x5E,0x5F,
  0x62,0x72,0x82,0x92,0xA2,0xB2,0xC2,0xD2,0xE2,0xF2,
  0x41,0x42,0x43,0x44,0x45,0x46,0x47,0x48,0x49,0x4A,0x4B,0x4C,0x4D,0x4E,0x4F,
  0x51,0x61,0x71,0x81,0x91,0xA1,0xB1,0xC1,0xD1,0xE1,0xF1,
  0x31,0x32,0x33,0x34,0x35,0x36,0x37,0x38,0x39,0x3A,0x3B,0x3C,0x3D,0x3E,0x3F,
  0x10,0x11,0x12,0x13,0x14,0x15,0x16,0x17,0x18,0x19,0x1A,0x1B,0x1C,0x1D,0x1E,0x1F,
  0x20,0x21,0x22,0x23,0x24,0x25,0x26,0x27,0x28,0x29,0x2A,0x2B,0x2C,0x2D,0x2E,0x2F,
  0x30,0x40,0x50,0x60,0x70,0x80,0x90,0xA0,0xB0,0xC0,0xD0,0xE0,0xF0,
  0x00,0x01,0x02,0x03,0x04,0x05,0x06,0x07,0x08,0x09,0x0A,0x0B,0x0C,0x0D,0x0E,0x0F
};

// fp32 -> bf16 round-to-nearest-even
static __device__ __forceinline__ u16 f2bf(float f) {
  unsigned int u = __float_as_uint(f);
  u += 0x7FFFu + ((u >> 16) & 1u);
  return (u16)(u >> 16);
}

static __device__ __forceinline__ u32 packbf(float a, float b) {
  bf16x2 t;
  t[0] = (__bf16)a;
  t[1] = (__bf16)b;
  return __builtin_bit_cast(u32, t);
}

static __device__ __forceinline__ f32x4 mfma16(bf16x8 a, bf16x8 b, f32x4 c) {
  return __builtin_amdgcn_mfma_f32_16x16x32_bf16(a, b, c, 0, 0, 0);
}
static __device__ __forceinline__ f32x16 mfma32(bf16x8 a, bf16x8 b, f32x16 c) {
  return __builtin_amdgcn_mfma_f32_32x32x16_bf16(a, b, c, 0, 0, 0);
}

static __device__ __forceinline__ void gload16(const void* g, void* lds) {
  __builtin_amdgcn_global_load_lds(
      (const __attribute__((address_space(1))) unsigned int*)g,
      (__attribute__((address_space(3))) unsigned int*)lds, 16, 0, 0);
}

// ---------------- cast x (fp32 -> bf16), 8 elems/thread ----------------
__global__ __launch_bounds__(256) void k_cast_x(const float* __restrict__ in,
                                                u16* __restrict__ out) {
  size_t i = (size_t)blockIdx.x * 256 + threadIdx.x;
  const float4* p = reinterpret_cast<const float4*>(in) + i * 2;
  float4 a = p[0], b = p[1];
  u16x8 r;
  r[0] = f2bf(a.x); r[1] = f2bf(a.y); r[2] = f2bf(a.z); r[3] = f2bf(a.w);
  r[4] = f2bf(b.x); r[5] = f2bf(b.y); r[6] = f2bf(b.z); r[7] = f2bf(b.w);
  *reinterpret_cast<u16x8*>(out + i * 8) = r;
}

// ---------------- fold LoRA into weights + cast to bf16 ----------------
__global__ __launch_bounds__(256) void k_fold_w(
    const float* __restrict__ Wq, const float* __restrict__ Aq, const float* __restrict__ Bq,
    const float* __restrict__ Wk, const float* __restrict__ Ak, const float* __restrict__ Bk,
    const float* __restrict__ Wv, const float* __restrict__ Av, const float* __restrict__ Bv,
    const float* __restrict__ Wp, u16* __restrict__ wqkv, u16* __restrict__ wp) {
  int n = blockIdx.x;
  int widx = n >> 10, nr = n & 1023;
  const float *W, *A, *Bm; u16* dst;
  if (widx == 0)      { W = Wq; A = Aq; Bm = Bq; dst = wqkv; }
  else if (widx == 1) { W = Wk; A = Ak; Bm = Bk; dst = wqkv + (1 << 20); }
  else if (widx == 2) { W = Wv; A = Av; Bm = Bv; dst = wqkv + (2 << 20); }
  else                { W = Wp; A = nullptr; Bm = nullptr; dst = wp; }
  int e0 = threadIdx.x * 4;
  float4 w = *reinterpret_cast<const float4*>(W + (size_t)nr * 1024 + e0);
  if (widx < 3) {
    float acx = 0.f, acy = 0.f, acz = 0.f, acw = 0.f;
#pragma unroll
    for (int r = 0; r < 8; r++) {
      float ar = A[nr * 8 + r];
      float4 bm = *reinterpret_cast<const float4*>(Bm + (size_t)r * 1024 + e0);
      acx += ar * bm.x; acy += ar * bm.y; acz += ar * bm.z; acw += ar * bm.w;
    }
    w.x += 2.0f * acx; w.y += 2.0f * acy; w.z += 2.0f * acz; w.w += 2.0f * acw;
  }
  u16x4 r4; r4[0] = f2bf(w.x); r4[1] = f2bf(w.y); r4[2] = f2bf(w.z); r4[3] = f2bf(w.w);
  *reinterpret_cast<u16x4*>(dst + (size_t)nr * 1024 + e0) = r4;
}

// ---------------- GEMM: C[M,N] = A[M,K(lda)] * Bw[N,K]^T ----------------
template<int OUTF32>
__global__ __launch_bounds__(256) void k_gemm_bt(const u16* __restrict__ A,
                                                 const u16* __restrict__ Bw,
                                                 void* __restrict__ C, int K, int N, int lda) {
  __shared__ __align__(16) u16 As[128 * 64];
  __shared__ __align__(16) u16 Bs[128 * 64];
  const int tid = threadIdx.x;
  const int wave = tid >> 6, lane = tid & 63;
  const int l15 = lane & 15, lg = lane >> 4;
  const int m0 = blockIdx.x * 128, n0 = blockIdx.y * 128;
  const int wr = wave >> 1, wc = wave & 1;

  f32x4 acc[4][4];
#pragma unroll
  for (int i = 0; i < 4; i++)
#pragma unroll
    for (int j = 0; j < 4; j++) acc[i][j] = (f32x4)0.0f;

  for (int k0 = 0; k0 < K; k0 += 64) {
#pragma unroll
    for (int i = 0; i < 4; i++) {
      int idx = i * 256 + tid;
      int row = idx >> 3, col = (idx & 7) << 3;
      gload16(A  + (size_t)(m0 + row) * lda + k0 + col, As + (i * 4 + wave) * 512);
      gload16(Bw + (size_t)(n0 + row) * K   + k0 + col, Bs + (i * 4 + wave) * 512);
    }
    __syncthreads();
#pragma unroll
    for (int c = 0; c < 2; c++) {
      bf16x8 af[4], bfr[4];
#pragma unroll
      for (int t = 0; t < 4; t++) {
        af[t]  = *reinterpret_cast<const bf16x8*>(As + (wr * 64 + t * 16 + l15) * 64 + c * 32 + lg * 8);
        bfr[t] = *reinterpret_cast<const bf16x8*>(Bs + (wc * 64 + t * 16 + l15) * 64 + c * 32 + lg * 8);
      }
#pragma unroll
      for (int mi = 0; mi < 4; mi++)
#pragma unroll
        for (int ni = 0; ni < 4; ni++)
          acc[mi][ni] = mfma16(af[mi], bfr[ni], acc[mi][ni]);
    }
    __syncthreads();
  }

  const int rbase = m0 + wr * 64, cbase = n0 + wc * 64;
#pragma unroll
  for (int mi = 0; mi < 4; mi++)
#pragma unroll
    for (int ni = 0; ni < 4; ni++)
#pragma unroll
      for (int j = 0; j < 4; j++) {
        int r  = rbase + mi * 16 + lg * 4 + j;
        int cc = cbase + ni * 16 + l15;
        if constexpr (OUTF32) {
          reinterpret_cast<float*>(C)[(size_t)r * N + cc] = acc[mi][ni][j];
        } else {
          reinterpret_cast<u16*>(C)[(size_t)r * N + cc] = f2bf(acc[mi][ni][j]);
        }
      }
}

// ---------------- V transpose: qkv V-section -> vt[b][h][d][t] ----------------
__global__ __launch_bounds__(256) void k_vt(const u16* __restrict__ qkv,
                                            u16* __restrict__ vt) {
  __shared__ __align__(16) u16 tile[64 * 64];
  const int tb = blockIdx.x, h = blockIdx.y, b = blockIdx.z;
  const int tid = threadIdx.x;
  const size_t rb = (size_t)b * 2048;
  const int hv = 2048 + h * 64;
#pragma unroll
  for (int p = 0; p < 2; p++) {
    int r = p * 32 + (tid >> 3);
    int c = (tid & 7) * 8;
    u16x8 v = *reinterpret_cast<const u16x8*>(qkv + (rb + tb * 64 + r) * 3072 + hv + c);
    int slot = (c >> 3) ^ (r & 7) ^ ((r >> 3) & 7);
    *reinterpret_cast<u16x8*>(tile + r * 64 + slot * 8) = v;
  }
  __syncthreads();
#pragma unroll
  for (int p = 0; p < 2; p++) {
    int d = p * 32 + (tid >> 3);
    int t0 = (tid & 7) * 8;
    u16x8 v;
#pragma unroll
    for (int j = 0; j < 8; j++) {
      int r = t0 + j;
      int slot = (d >> 3) ^ (r & 7) ^ ((r >> 3) & 7);
      v[j] = tile[r * 64 + slot * 8 + (d & 7)];
    }
    *reinterpret_cast<u16x8*>(vt + ((size_t)(b * 16 + h) * 64 + d) * 2048 + tb * 64 + t0) = v;
  }
}

// ---------------- flash attention v6: LPT-balanced flat grid ----------------
// Flat grid 1024: b = i&3, (h,qb) via RANKTBL so co-resident blocks have
// complementary weights and heavy blocks dispatch first. 2 LDS buffers
// (32KB -> 5 blocks/CU, 20 waves/CU: TLP packs the VALU pipe).
// QBLK=128 (4 waves x 32 q), KVBLK=64, 32x32x16 MFMA, swapped QK^T and PV,
// in-register softmax (cvt_pk + permlane32_swap), defer-max, ALiBi prefix window.
// Output written in-place into qkv's Q-columns (stride 3072).
__global__ __launch_bounds__(256) void k_attn(const u16* __restrict__ qkv,
                                              const u16* __restrict__ vt,
                                              u16* __restrict__ aout) {
  __shared__ __align__(16) u16 Kl[2][64 * 64];   // [key][d], swizzled 16B slots
  __shared__ __align__(16) u16 Vl[2][64 * 64];   // [d][key], same swizzle
  const int tid = threadIdx.x, wave = tid >> 6, lane = tid & 63;
  const int l31 = lane & 31, half = lane >> 5;
  const int i = (int)blockIdx.x;
  const int b = i & 3, p = i >> 2;
  const int k4 = p >> 6, j4 = p & 63;
  const int ridx = (k4 == 0) ? j4 : (k4 == 1) ? 127 - j4 : (k4 == 2) ? 128 + j4 : 255 - j4;
  const int hqv = RANKTBL[ridx];
  const int h = hqv >> 4, qb = hqv & 15;
  const int rb = b * 2048;
  const int hq = h * 64, hk = 1024 + h * 64;
  const int bh64 = (b * 16 + h) * 64;
  const int qB = qb * 128;
  const int q0w = qB + wave * 32;
  const int q = q0w + l31;

  // Q as B-fragment: col=q=l31, inner d = chunk*16 + half*8
  bf16x8 qf[4];
#pragma unroll
  for (int c = 0; c < 4; c++)
    qf[c] = *reinterpret_cast<const bf16x8*>(qkv + (size_t)(rb + q) * 3072 + hq + c * 16 + half * 8);

  const float slope2 = exp2f(-0.5f * (float)(h + 1)) * 1.44269504f;  // nats->log2 folded
  const float c0 = 0.18033688f;                                       // 0.125*log2(e)

  const int kend = min(2 * qb + 1, KBW[h]);                           // block-uniform

  float mrun = -1e30f, lrun = 0.f;
  f32x16 o0 = (f32x16)0.0f, o1 = (f32x16)0.0f;

  auto stage = [&](int kvr, int dst) {
#pragma unroll
    for (int i2 = 0; i2 < 2; i2++) {
      int row = (i2 * 4 + wave) * 8 + (lane >> 3);
      int scol = ((lane & 7) ^ (row & 7)) << 3;
      gload16(qkv + (size_t)(rb + kvr + row) * 3072 + hk + scol, &Kl[dst][(i2 * 4 + wave) * 512]);
      gload16(vt + (size_t)(bh64 + row) * 2048 + kvr + scol,     &Vl[dst][(i2 * 4 + wave) * 512]);
    }
  };

  stage(0, 0);   // prologue: oldest tile into buffer 0
  __syncthreads();

  int bfi = 0;
  for (int kb = 0; kb <= kend; ++kb, bfi ^= 1) {
    const int kvr = kb * 64;
    if (kb < kend) stage(kvr + 64, bfi ^ 1);   // issue next tile's loads early

    if (kvr <= q0w + 31) {   // wave-uniform: tile intersects this wave's causal range
      // ---- S^T = K * Q : s[t] covers k = t*32.., col=q=l31 ----
      f32x16 s[2];
#pragma unroll
      for (int t = 0; t < 2; t++) s[t] = (f32x16)0.0f;
      __builtin_amdgcn_s_setprio(1);
#pragma unroll
      for (int t = 0; t < 2; t++) {
        int r = t * 32 + l31;
#pragma unroll
        for (int cc = 0; cc < 4; cc++) {
          bf16x8 kf = *reinterpret_cast<const bf16x8*>(
              &Kl[bfi][r * 64 + (((cc * 2 + half) ^ (r & 7)) << 3)]);
          s[t] = mfma32(kf, qf[cc], s[t]);
        }
      }
      __builtin_amdgcn_s_setprio(0);

      // ---- scale + alibi (+ mask on diagonal tiles); row max ----
      const bool domask = (kvr + 63 > q0w);
      const int qrel = q - kvr - half * 4;
      const float qb0 = slope2 * (float)qrel;
      const float qb1 = qb0 - slope2 * 32.0f;
      float mt = -1e30f;
#pragma unroll
      for (int t = 0; t < 2; t++) {
        const float qbt = t ? qb1 : qb0;
        const int qmt = t ? (qrel - 32) : qrel;
#pragma unroll
        for (int r = 0; r < 16; r++) {
          const int krel = (r & 3) + 8 * (r >> 2);
          float val = fmaf(s[t][r], c0, fmaf(-slope2, (float)krel, qbt));
          if (domask) val = (krel <= qmt) ? val : -3.0e38f;
          s[t][r] = val;
          mt = fmaxf(mt, val);
        }
      }
      mt = fmaxf(mt, __shfl_xor(mt, 32));

      // defer-max: rescale only when max grew materially (rare: bias decays with kb)
      if (__any(mt - mrun > 8.0f)) {
        float mn = fmaxf(mrun, mt);
        float al = exp2f(mrun - mn);
        mrun = mn; lrun *= al;
#pragma unroll
        for (int r = 0; r < 16; r++) { o0[r] *= al; o1[r] *= al; }
      }

      float rs0 = 0.f, rs1 = 0.f;
#pragma unroll
      for (int t = 0; t < 2; t++)
#pragma unroll
        for (int r = 0; r < 16; r++) {
          float pp = exp2f(s[t][r] - mrun);
          s[t][r] = pp;
          if (t) rs1 += pp; else rs0 += pp;
        }
      float rs = rs0 + rs1;
      rs += __shfl_xor(rs, 32);
      lrun += rs;

      // ---- P -> bf16 fragments in-register (cvt_pk + permlane32_swap) ----
      bf16x8 pf[4];
#pragma unroll
      for (int t = 0; t < 2; t++)
#pragma unroll
        for (int hs = 0; hs < 2; hs++) {
          u32 A0 = packbf(s[t][8 * hs + 0], s[t][8 * hs + 1]);
          u32 B0 = packbf(s[t][8 * hs + 2], s[t][8 * hs + 3]);
          u32 C0 = packbf(s[t][8 * hs + 4], s[t][8 * hs + 5]);
          u32 D0 = packbf(s[t][8 * hs + 6], s[t][8 * hs + 7]);
          asm volatile("v_permlane32_swap_b32 %0, %1" : "+v"(A0), "+v"(C0));
          asm volatile("v_permlane32_swap_b32 %0, %1" : "+v"(B0), "+v"(D0));
          u32x4 fr; fr[0] = A0; fr[1] = B0; fr[2] = C0; fr[3] = D0;
          pf[t * 2 + hs] = __builtin_bit_cast(bf16x8, fr);
        }

      // ---- O^T += V^T * P^T : o[dblk] rows d, col=q=l31 ----
      __builtin_amdgcn_s_setprio(1);
#pragma unroll
      for (int dblk = 0; dblk < 2; dblk++) {
        int r = dblk * 32 + l31;
#pragma unroll
        for (int kc = 0; kc < 4; kc++) {
          bf16x8 vf = *reinterpret_cast<const bf16x8*>(
              &Vl[bfi][r * 64 + (((kc * 2 + half) ^ (r & 7)) << 3)]);
          if (dblk) o1 = mfma32(vf, pf[kc], o1);
          else      o0 = mfma32(vf, pf[kc], o0);
        }
      }
      __builtin_amdgcn_s_setprio(0);
    }
    __syncthreads();
  }

  const float linv = 1.0f / lrun;
#pragma unroll
  for (int dblk = 0; dblk < 2; dblk++)
#pragma unroll
    for (int rg = 0; rg < 4; rg++) {
      int d0 = dblk * 32 + 8 * rg + 4 * half;
      u16x4 r4;
#pragma unroll
      for (int j = 0; j < 4; j++) {
        float v = (dblk ? o1[rg * 4 + j] : o0[rg * 4 + j]) * linv;
        r4[j] = f2bf(v);
      }
      *reinterpret_cast<u16x4*>(aout + (size_t)(rb + q) * 3072 + hq + d0) = r4;
    }
}

extern "C" void kernel_launch(void* const* d_in, const int* in_sizes, int n_in,
                              void* d_out, int out_size, void* d_ws, size_t ws_size,
                              hipStream_t stream) {
  (void)in_sizes; (void)n_in; (void)out_size; (void)ws_size;
  const float* x  = (const float*)d_in[0];
  const float* Wq = (const float*)d_in[1];
  const float* Aq = (const float*)d_in[2];
  const float* Bq = (const float*)d_in[3];
  const float* Wk = (const float*)d_in[4];
  const float* Ak = (const float*)d_in[5];
  const float* Bk = (const float*)d_in[6];
  const float* Wv = (const float*)d_in[7];
  const float* Av = (const float*)d_in[8];
  const float* Bv = (const float*)d_in[9];
  const float* Wp = (const float*)d_in[10];

  char* ws = (char*)d_ws;
  u16* xb   = (u16*)(ws);                  // [8192][1024] bf16 (dead after gemm1)
  u16* wqkv = (u16*)(ws + 16777216);       // [3072][1024] bf16
  u16* wp   = (u16*)(ws + 23068672);       // [1024][1024] bf16
  u16* qkv  = (u16*)(ws + 25165824);       // [8192][3072] bf16
  u16* vt   = xb;                          // [4][16][64][2048] bf16, reuses xb
  float* out = (float*)d_out;

  k_cast_x<<<dim3(4096), dim3(256), 0, stream>>>(x, xb);
  k_fold_w<<<dim3(4096), dim3(256), 0, stream>>>(Wq, Aq, Bq, Wk, Ak, Bk, Wv, Av, Bv, Wp, wqkv, wp);
  k_gemm_bt<0><<<dim3(64, 24), dim3(256), 0, stream>>>(xb, wqkv, (void*)qkv, 1024, 3072, 1024);
  k_vt<<<dim3(32, 16, 4), dim3(256), 0, stream>>>(qkv, vt);
  // attention writes its output into qkv's Q-columns (in-place, stride 3072)
  k_attn<<<dim3(1024), dim3(256), 0, stream>>>(qkv, vt, qkv);
  k_gemm_bt<1><<<dim3(64, 8), dim3(256), 0, stream>>>(qkv, wp, (void*)out, 1024, 1024, 3072);
}

// Round 10
// 201.750 us; speedup vs baseline: 1.5228x; 1.0200x over previous
//
#include <hip/hip_runtime.h>

typedef unsigned short u16;
typedef unsigned int u32;
typedef u16  u16x8 __attribute__((ext_vector_type(8)));
typedef u16  u16x4 __attribute__((ext_vector_type(4)));
typedef u32  u32x4 __attribute__((ext_vector_type(4)));
typedef __bf16 bf16x2 __attribute__((ext_vector_type(2)));
typedef __bf16 bf16x8 __attribute__((ext_vector_type(8)));
typedef float f32x4 __attribute__((ext_vector_type(4)));
typedef float f32x16 __attribute__((ext_vector_type(16)));

// ALiBi prefix window (keys with slope_nat*j > 40 negligible): kb_w per head.
__constant__ int KBW[16]  = {0,1,1,2,3,5,7,10,14,20,28,40,56,80,113,160};

// (h,qb) pairs (byte = h*16+qb) sorted by tile count DESCENDING (LPT schedule).
__constant__ unsigned char RANKTBL[256] = {
  0xBF,0xCF,0xDF,0xEF,0xFF,
  0xBE,0xCE,0xDE,0xEE,0xFE,
  0xAE,0xAF,
  0xAD,0xBD,0xCD,0xDD,0xED,0xFD,
  0xAC,0xBC,0xCC,0xDC,0xEC,0xFC,
  0xAB,0xBB,0xCB,0xDB,0xEB,0xFB,
  0xAA,0xBA,0xCA,0xDA,0xEA,0xFA,
  0x9A,0x9B,0x9C,0x9D,0x9E,0x9F,
  0x99,0xA9,0xB9,0xC9,0xD9,0xE9,0xF9,
  0x98,0xA8,0xB8,0xC8,0xD8,0xE8,0xF8,
  0x97,0xA7,0xB7,0xC7,0xD7,0xE7,0xF7,
  0x87,0x88,0x89,0x8A,0x8B,0x8C,0x8D,0x8E,0x8F,
  0x86,0x96,0xA6,0xB6,0xC6,0xD6,0xE6,0xF6,
  0x85,0x95,0xA5,0xB5,0xC5,0xD5,0xE5,0xF5,
  0x75,0x76,0x77,0x78,0x79,0x7A,0x7B,0x7C,0x7D,0x7E,0x7F,
  0x74,0x84,0x94,0xA4,0xB4,0xC4,0xD4,0xE4,0xF4,
  0x63,0x64,0x65,0x66,0x67,0x68,0x69,0x6A,0x6B,0x6C,0x6D,0x6E,0x6F,
  0x73,0x83,0x93,0xA3,0xB3,0xC3,0xD3,0xE3,0xF3,
  0x52,0x53,0x54,0x55,0x56,0x57,0x58,0x59,0x5A,0x5B,0x5C,0x5D,0x5E,0x5F,
  0x62,0x72,0x82,0x92,0xA2,0xB2,0xC2,0xD2,0xE2,0xF2,
  0x41,0x42,0x43,0x44,0x45,0x46,0x47,0x48,0x49,0x4A,0x4B,0x4C,0x4D,0x4E,0x4F,
  0x51,0x61,0x71,0x81,0x91,0xA1,0xB1,0xC1,0xD1,0xE1,0xF1,
  0x31,0x32,0x33,0x34,0x35,0x36,0x37,0x38,0x39,0x3A,0x3B,0x3C,0x3D,0x3E,0x3F,
  0x10,0x11,0x12,0x13,0x14,0x15,0x16,0x17,0x18,0x19,0x1A,0x1B,0x1C,0x1D,0x1E,0x1F,
  0x20,0x21,0x22,0x23,0x24,0x25,0x26,0x27,0x28,0x29,0x2A,0x2B,0x2C,0x2D,0x2E,0x2F,
  0x30,0x40,0x50,0x60,0x70,0x80,0x90,0xA0,0xB0,0xC0,0xD0,0xE0,0xF0,
  0x00,0x01,0x02,0x03,0x04,0x05,0x06,0x07,0x08,0x09,0x0A,0x0B,0x0C,0x0D,0x0E,0x0F
};

// fp32 -> bf16 round-to-nearest-even
static __device__ __forceinline__ u16 f2bf(float f) {
  unsigned int u = __float_as_uint(f);
  u += 0x7FFFu + ((u >> 16) & 1u);
  return (u16)(u >> 16);
}

static __device__ __forceinline__ u32 packbf(float a, float b) {
  bf16x2 t;
  t[0] = (__bf16)a;
  t[1] = (__bf16)b;
  return __builtin_bit_cast(u32, t);
}

static __device__ __forceinline__ f32x4 mfma16(bf16x8 a, bf16x8 b, f32x4 c) {
  return __builtin_amdgcn_mfma_f32_16x16x32_bf16(a, b, c, 0, 0, 0);
}
static __device__ __forceinline__ f32x16 mfma32(bf16x8 a, bf16x8 b, f32x16 c) {
  return __builtin_amdgcn_mfma_f32_32x32x16_bf16(a, b, c, 0, 0, 0);
}

static __device__ __forceinline__ void gload16(const void* g, void* lds) {
  __builtin_amdgcn_global_load_lds(
      (const __attribute__((address_space(1))) unsigned int*)g,
      (__attribute__((address_space(3))) unsigned int*)lds, 16, 0, 0);
}

// ---------------- cast x (fp32 -> bf16), 8 elems/thread ----------------
__global__ __launch_bounds__(256) void k_cast_x(const float* __restrict__ in,
                                                u16* __restrict__ out) {
  size_t i = (size_t)blockIdx.x * 256 + threadIdx.x;
  const float4* p = reinterpret_cast<const float4*>(in) + i * 2;
  float4 a = p[0], b = p[1];
  u16x8 r;
  r[0] = f2bf(a.x); r[1] = f2bf(a.y); r[2] = f2bf(a.z); r[3] = f2bf(a.w);
  r[4] = f2bf(b.x); r[5] = f2bf(b.y); r[6] = f2bf(b.z); r[7] = f2bf(b.w);
  *reinterpret_cast<u16x8*>(out + i * 8) = r;
}

// ---------------- fold LoRA into weights + cast to bf16 ----------------
__global__ __launch_bounds__(256) void k_fold_w(
    const float* __restrict__ Wq, const float* __restrict__ Aq, const float* __restrict__ Bq,
    const float* __restrict__ Wk, const float* __restrict__ Ak, const float* __restrict__ Bk,
    const float* __restrict__ Wv, const float* __restrict__ Av, const float* __restrict__ Bv,
    const float* __restrict__ Wp, u16* __restrict__ wqkv, u16* __restrict__ wp) {
  int n = blockIdx.x;
  int widx = n >> 10, nr = n & 1023;
  const float *W, *A, *Bm; u16* dst;
  if (widx == 0)      { W = Wq; A = Aq; Bm = Bq; dst = wqkv; }
  else if (widx == 1) { W = Wk; A = Ak; Bm = Bk; dst = wqkv + (1 << 20); }
  else if (widx == 2) { W = Wv; A = Av; Bm = Bv; dst = wqkv + (2 << 20); }
  else                { W = Wp; A = nullptr; Bm = nullptr; dst = wp; }
  int e0 = threadIdx.x * 4;
  float4 w = *reinterpret_cast<const float4*>(W + (size_t)nr * 1024 + e0);
  if (widx < 3) {
    float acx = 0.f, acy = 0.f, acz = 0.f, acw = 0.f;
#pragma unroll
    for (int r = 0; r < 8; r++) {
      float ar = A[nr * 8 + r];
      float4 bm = *reinterpret_cast<const float4*>(Bm + (size_t)r * 1024 + e0);
      acx += ar * bm.x; acy += ar * bm.y; acz += ar * bm.z; acw += ar * bm.w;
    }
    w.x += 2.0f * acx; w.y += 2.0f * acy; w.z += 2.0f * acz; w.w += 2.0f * acw;
  }
  u16x4 r4; r4[0] = f2bf(w.x); r4[1] = f2bf(w.y); r4[2] = f2bf(w.z); r4[3] = f2bf(w.w);
  *reinterpret_cast<u16x4*>(dst + (size_t)nr * 1024 + e0) = r4;
}

// ---------------- GEMM v2: 8-phase schedule (T2+T3+T4+T5) ----------------
// C[M,N] = A[M,K(lda)] * Bw[N,K]^T.  128x256 tile, BK=64, 8 waves (2Mx4N),
// per-wave 64x64 out.  LDS 96KB: As[2][2kk][128][32], Bs[2][2kk][256][32],
// XOR-swizzled (u16 idx: e ^= ((e>>8)&1)<<4, involution) on BOTH the
// pre-swizzled global_load_lds source and the ds_read address.
// Per K-tile: 4 phases {ds_read subtile | stage | bar | lgkm(0) | 8 MFMA | bar};
// stage B at ph3 (B reads done ph2), A at ph4; counted vmcnt(6) at ph4/ph8 only.
template<int OUTF32>
__global__ __launch_bounds__(512) void k_gemm8(const u16* __restrict__ Ag,
                                               const u16* __restrict__ Bg,
                                               void* __restrict__ C,
                                               int K, int N, int lda, int gx) {
  __shared__ __align__(16) u16 As[2][8192];    // 32KB
  __shared__ __align__(16) u16 Bs[2][16384];   // 64KB
  const int tid = threadIdx.x;
  const int wid = tid >> 6, lane = tid & 63;
  const int l15 = lane & 15, lg = lane >> 4;
  const int wr = wid >> 2, wc = wid & 3;
  // bijective XCD swizzle (nwg % 8 == 0 for all our grids)
  const int nwg = gridDim.x, cpx = nwg >> 3;
  const int bid = (int)blockIdx.x;
  const int sid = (bid & 7) * cpx + (bid >> 3);
  const int m0 = (sid % gx) * 128, n0 = (sid / gx) * 256;

  const int swz = ((l15 >> 3) & 1) << 4;             // read-side XOR on bf16-col bit 4
  const int ln2 = lane >> 2;                         // staging row-within-16
  const int scol = ((lane & 3) ^ ((lane >> 5) << 1)) << 3;  // pre-swizzled src col

  f32x4 acc[4][4];
#pragma unroll
  for (int i = 0; i < 4; i++)
#pragma unroll
    for (int j = 0; j < 4; j++) acc[i][j] = (f32x4)0.0f;

  auto stageA = [&](int d, int t) {   // 2 gloads/thread
#pragma unroll
    for (int i = 0; i < 2; i++)
      gload16(Ag + (size_t)(m0 + wid * 16 + ln2) * lda + t * 64 + i * 32 + scol,
              &As[d][(i * 512 + wid * 64) * 8]);
  };
  auto stageB = [&](int d, int t) {   // 4 gloads/thread
#pragma unroll
    for (int i = 0; i < 4; i++)
      gload16(Bg + (size_t)(n0 + (i & 1) * 128 + wid * 16 + ln2) * K + t * 64 + (i >> 1) * 32 + scol,
              &Bs[d][(i * 512 + wid * 64) * 8]);
  };
  auto ldsA = [&](int d, int m, int kk) {
    int rr = wr * 64 + m * 16 + l15;
    return *reinterpret_cast<const bf16x8*>(&As[d][kk * 4096 + rr * 32 + (lg * 8 ^ swz)]);
  };
  auto ldsB = [&](int d, int n, int kk) {
    int rr = wc * 64 + n * 16 + l15;
    return *reinterpret_cast<const bf16x8*>(&Bs[d][kk * 8192 + rr * 32 + (lg * 8 ^ swz)]);
  };

  bf16x8 fa[4][2], fb[4][2];
  auto quad = [&](int mh, int nh) {
    __builtin_amdgcn_s_setprio(1);
#pragma unroll
    for (int m = 0; m < 2; m++)
#pragma unroll
      for (int n = 0; n < 2; n++)
#pragma unroll
        for (int kk = 0; kk < 2; kk++)
          acc[mh * 2 + m][nh * 2 + n] =
              mfma16(fa[mh * 2 + m][kk], fb[nh * 2 + n][kk], acc[mh * 2 + m][nh * 2 + n]);
    __builtin_amdgcn_s_setprio(0);
  };

#define MIDBAR do { asm volatile("s_barrier" ::: "memory"); \
                    asm volatile("s_waitcnt lgkmcnt(0)" ::: "memory"); } while (0)
#define ENDBAR asm volatile("s_barrier" ::: "memory")

  // prologue: tiles 0,1 into buf0,buf1; drain; barrier
  stageB(0, 0); stageA(0, 0); stageB(1, 1); stageA(1, 1);
  asm volatile("s_waitcnt vmcnt(0)" ::: "memory");
  asm volatile("s_barrier" ::: "memory");

  const int niter = K >> 7;                 // 2 K-tiles per iteration
  for (int it = 0; it < niter; ++it) {
    const bool st = (it + 1 < niter);
    const int T2 = 2 * it + 2;
#pragma unroll
    for (int d = 0; d < 2; ++d) {           // d=0: tile 2it (ph1-4); d=1: tile 2it+1 (ph5-8)
      // ph1/ph5: read A m0-1 + B n0-1, MFMA quad(0,0)
#pragma unroll
      for (int m = 0; m < 2; m++)
#pragma unroll
        for (int kk = 0; kk < 2; kk++) fa[m][kk] = ldsA(d, m, kk);
#pragma unroll
      for (int n = 0; n < 2; n++)
#pragma unroll
        for (int kk = 0; kk < 2; kk++) fb[n][kk] = ldsB(d, n, kk);
      MIDBAR; quad(0, 0); ENDBAR;
      // ph2/ph6: read B n2-3, MFMA quad(0,1)
#pragma unroll
      for (int n = 2; n < 4; n++)
#pragma unroll
        for (int kk = 0; kk < 2; kk++) fb[n][kk] = ldsB(d, n, kk);
      MIDBAR; quad(0, 1); ENDBAR;
      // ph3/ph7: read A m2-3, stage B(T2+d) into buf d (B reads of buf d done ph2)
#pragma unroll
      for (int m = 2; m < 4; m++)
#pragma unroll
        for (int kk = 0; kk < 2; kk++) fa[m][kk] = ldsA(d, m, kk);
      if (st) stageB(d, T2 + d);
      MIDBAR; quad(1, 1); ENDBAR;
      // ph4/ph8: stage A(T2+d) (A reads of buf d done ph3); counted vmcnt
      if (st) stageA(d, T2 + d);
      MIDBAR; quad(1, 0);
      if (st) asm volatile("s_waitcnt vmcnt(6)" ::: "memory");
      else    asm volatile("s_waitcnt vmcnt(0)" ::: "memory");
      ENDBAR;
    }
  }
#undef MIDBAR
#undef ENDBAR

  const int rbase = m0 + wr * 64, cbase = n0 + wc * 64;
#pragma unroll
  for (int m = 0; m < 4; m++)
#pragma unroll
    for (int n = 0; n < 4; n++)
#pragma unroll
      for (int j = 0; j < 4; j++) {
        int r  = rbase + m * 16 + lg * 4 + j;
        int cc = cbase + n * 16 + l15;
        if constexpr (OUTF32) {
          reinterpret_cast<float*>(C)[(size_t)r * N + cc] = acc[m][n][j];
        } else {
          reinterpret_cast<u16*>(C)[(size_t)r * N + cc] = f2bf(acc[m][n][j]);
        }
      }
}

// ---------------- V transpose: qkv V-section -> vt[b][h][d][t] ----------------
__global__ __launch_bounds__(256) void k_vt(const u16* __restrict__ qkv,
                                            u16* __restrict__ vt) {
  __shared__ __align__(16) u16 tile[64 * 64];
  const int tb = blockIdx.x, h = blockIdx.y, b = blockIdx.z;
  const int tid = threadIdx.x;
  const size_t rb = (size_t)b * 2048;
  const int hv = 2048 + h * 64;
#pragma unroll
  for (int p = 0; p < 2; p++) {
    int r = p * 32 + (tid >> 3);
    int c = (tid & 7) * 8;
    u16x8 v = *reinterpret_cast<const u16x8*>(qkv + (rb + tb * 64 + r) * 3072 + hv + c);
    int slot = (c >> 3) ^ (r & 7) ^ ((r >> 3) & 7);
    *reinterpret_cast<u16x8*>(tile + r * 64 + slot * 8) = v;
  }
  __syncthreads();
#pragma unroll
  for (int p = 0; p < 2; p++) {
    int d = p * 32 + (tid >> 3);
    int t0 = (tid & 7) * 8;
    u16x8 v;
#pragma unroll
    for (int j = 0; j < 8; j++) {
      int r = t0 + j;
      int slot = (d >> 3) ^ (r & 7) ^ ((r >> 3) & 7);
      v[j] = tile[r * 64 + slot * 8 + (d & 7)];
    }
    *reinterpret_cast<u16x8*>(vt + ((size_t)(b * 16 + h) * 64 + d) * 2048 + tb * 64 + t0) = v;
  }
}

// ---------------- flash attention v6: LPT-balanced flat grid ----------------
__global__ __launch_bounds__(256) void k_attn(const u16* __restrict__ qkv,
                                              const u16* __restrict__ vt,
                                              u16* __restrict__ aout) {
  __shared__ __align__(16) u16 Kl[2][64 * 64];   // [key][d], swizzled 16B slots
  __shared__ __align__(16) u16 Vl[2][64 * 64];   // [d][key], same swizzle
  const int tid = threadIdx.x, wave = tid >> 6, lane = tid & 63;
  const int l31 = lane & 31, half = lane >> 5;
  const int i = (int)blockIdx.x;
  const int b = i & 3, p = i >> 2;
  const int k4 = p >> 6, j4 = p & 63;
  const int ridx = (k4 == 0) ? j4 : (k4 == 1) ? 127 - j4 : (k4 == 2) ? 128 + j4 : 255 - j4;
  const int hqv = RANKTBL[ridx];
  const int h = hqv >> 4, qb = hqv & 15;
  const int rb = b * 2048;
  const int hq = h * 64, hk = 1024 + h * 64;
  const int bh64 = (b * 16 + h) * 64;
  const int qB = qb * 128;
  const int q0w = qB + wave * 32;
  const int q = q0w + l31;

  bf16x8 qf[4];
#pragma unroll
  for (int c = 0; c < 4; c++)
    qf[c] = *reinterpret_cast<const bf16x8*>(qkv + (size_t)(rb + q) * 3072 + hq + c * 16 + half * 8);

  const float slope2 = exp2f(-0.5f * (float)(h + 1)) * 1.44269504f;
  const float c0 = 0.18033688f;

  const int kend = min(2 * qb + 1, KBW[h]);

  float mrun = -1e30f, lrun = 0.f;
  f32x16 o0 = (f32x16)0.0f, o1 = (f32x16)0.0f;

  auto stage = [&](int kvr, int dst) {
#pragma unroll
    for (int i2 = 0; i2 < 2; i2++) {
      int row = (i2 * 4 + wave) * 8 + (lane >> 3);
      int scol = ((lane & 7) ^ (row & 7)) << 3;
      gload16(qkv + (size_t)(rb + kvr + row) * 3072 + hk + scol, &Kl[dst][(i2 * 4 + wave) * 512]);
      gload16(vt + (size_t)(bh64 + row) * 2048 + kvr + scol,     &Vl[dst][(i2 * 4 + wave) * 512]);
    }
  };

  stage(0, 0);
  __syncthreads();

  int bfi = 0;
  for (int kb = 0; kb <= kend; ++kb, bfi ^= 1) {
    const int kvr = kb * 64;
    if (kb < kend) stage(kvr + 64, bfi ^ 1);

    if (kvr <= q0w + 31) {
      f32x16 s[2];
#pragma unroll
      for (int t = 0; t < 2; t++) s[t] = (f32x16)0.0f;
      __builtin_amdgcn_s_setprio(1);
#pragma unroll
      for (int t = 0; t < 2; t++) {
        int r = t * 32 + l31;
#pragma unroll
        for (int cc = 0; cc < 4; cc++) {
          bf16x8 kf = *reinterpret_cast<const bf16x8*>(
              &Kl[bfi][r * 64 + (((cc * 2 + half) ^ (r & 7)) << 3)]);
          s[t] = mfma32(kf, qf[cc], s[t]);
        }
      }
      __builtin_amdgcn_s_setprio(0);

      const bool domask = (kvr + 63 > q0w);
      const int qrel = q - kvr - half * 4;
      const float qb0 = slope2 * (float)qrel;
      const float qb1 = qb0 - slope2 * 32.0f;
      float mt = -1e30f;
#pragma unroll
      for (int t = 0; t < 2; t++) {
        const float qbt = t ? qb1 : qb0;
        const int qmt = t ? (qrel - 32) : qrel;
#pragma unroll
        for (int r = 0; r < 16; r++) {
          const int krel = (r & 3) + 8 * (r >> 2);
          float val = fmaf(s[t][r], c0, fmaf(-slope2, (float)krel, qbt));
          if (domask) val = (krel <= qmt) ? val : -3.0e38f;
          s[t][r] = val;
          mt = fmaxf(mt, val);
        }
      }
      mt = fmaxf(mt, __shfl_xor(mt, 32));

      if (__any(mt - mrun > 8.0f)) {
        float mn = fmaxf(mrun, mt);
        float al = exp2f(mrun - mn);
        mrun = mn; lrun *= al;
#pragma unroll
        for (int r = 0; r < 16; r++) { o0[r] *= al; o1[r] *= al; }
      }

      float rs0 = 0.f, rs1 = 0.f;
#pragma unroll
      for (int t = 0; t < 2; t++)
#pragma unroll
        for (int r = 0; r < 16; r++) {
          float pp = exp2f(s[t][r] - mrun);
          s[t][r] = pp;
          if (t) rs1 += pp; else rs0 += pp;
        }
      float rs = rs0 + rs1;
      rs += __shfl_xor(rs, 32);
      lrun += rs;

      bf16x8 pf[4];
#pragma unroll
      for (int t = 0; t < 2; t++)
#pragma unroll
        for (int hs = 0; hs < 2; hs++) {
          u32 A0 = packbf(s[t][8 * hs + 0], s[t][8 * hs + 1]);
          u32 B0 = packbf(s[t][8 * hs + 2], s[t][8 * hs + 3]);
          u32 C0 = packbf(s[t][8 * hs + 4], s[t][8 * hs + 5]);
          u32 D0 = packbf(s[t][8 * hs + 6], s[t][8 * hs + 7]);
          asm volatile("v_permlane32_swap_b32 %0, %1" : "+v"(A0), "+v"(C0));
          asm volatile("v_permlane32_swap_b32 %0, %1" : "+v"(B0), "+v"(D0));
          u32x4 fr; fr[0] = A0; fr[1] = B0; fr[2] = C0; fr[3] = D0;
          pf[t * 2 + hs] = __builtin_bit_cast(bf16x8, fr);
        }

      __builtin_amdgcn_s_setprio(1);
#pragma unroll
      for (int dblk = 0; dblk < 2; dblk++) {
        int r = dblk * 32 + l31;
#pragma unroll
        for (int kc = 0; kc < 4; kc++) {
          bf16x8 vf = *reinterpret_cast<const bf16x8*>(
              &Vl[bfi][r * 64 + (((kc * 2 + half) ^ (r & 7)) << 3)]);
          if (dblk) o1 = mfma32(vf, pf[kc], o1);
          else      o0 = mfma32(vf, pf[kc], o0);
        }
      }
      __builtin_amdgcn_s_setprio(0);
    }
    __syncthreads();
  }

  const float linv = 1.0f / lrun;
#pragma unroll
  for (int dblk = 0; dblk < 2; dblk++)
#pragma unroll
    for (int rg = 0; rg < 4; rg++) {
      int d0 = dblk * 32 + 8 * rg + 4 * half;
      u16x4 r4;
#pragma unroll
      for (int j = 0; j < 4; j++) {
        float v = (dblk ? o1[rg * 4 + j] : o0[rg * 4 + j]) * linv;
        r4[j] = f2bf(v);
      }
      *reinterpret_cast<u16x4*>(aout + (size_t)(rb + q) * 3072 + hq + d0) = r4;
    }
}

extern "C" void kernel_launch(void* const* d_in, const int* in_sizes, int n_in,
                              void* d_out, int out_size, void* d_ws, size_t ws_size,
                              hipStream_t stream) {
  (void)in_sizes; (void)n_in; (void)out_size; (void)ws_size;
  const float* x  = (const float*)d_in[0];
  const float* Wq = (const float*)d_in[1];
  const float* Aq = (const float*)d_in[2];
  const float* Bq = (const float*)d_in[3];
  const float* Wk = (const float*)d_in[4];
  const float* Ak = (const float*)d_in[5];
  const float* Bk = (const float*)d_in[6];
  const float* Wv = (const float*)d_in[7];
  const float* Av = (const float*)d_in[8];
  const float* Bv = (const float*)d_in[9];
  const float* Wp = (const float*)d_in[10];

  char* ws = (char*)d_ws;
  u16* xb   = (u16*)(ws);                  // [8192][1024] bf16 (dead after gemm1)
  u16* wqkv = (u16*)(ws + 16777216);       // [3072][1024] bf16
  u16* wp   = (u16*)(ws + 23068672);       // [1024][1024] bf16
  u16* qkv  = (u16*)(ws + 25165824);       // [8192][3072] bf16
  u16* vt   = xb;                          // [4][16][64][2048] bf16, reuses xb
  float* out = (float*)d_out;

  k_cast_x<<<dim3(4096), dim3(256), 0, stream>>>(x, xb);
  k_fold_w<<<dim3(4096), dim3(256), 0, stream>>>(Wq, Aq, Bq, Wk, Ak, Bk, Wv, Av, Bv, Wp, wqkv, wp);
  // QKV GEMM: M=8192 N=3072 K=1024 -> grid 64x12 = 768 blocks (3/CU exact)
  k_gemm8<0><<<dim3(768), dim3(512), 0, stream>>>(xb, wqkv, (void*)qkv, 1024, 3072, 1024, 64);
  k_vt<<<dim3(32, 16, 4), dim3(256), 0, stream>>>(qkv, vt);
  // attention writes its output into qkv's Q-columns (in-place, stride 3072)
  k_attn<<<dim3(1024), dim3(256), 0, stream>>>(qkv, vt, qkv);
  // output GEMM: M=8192 N=1024 K=1024 -> grid 64x4 = 256 blocks (1/CU exact)
  k_gemm8<1><<<dim3(256), dim3(512), 0, stream>>>(qkv, wp, (void*)out, 1024, 1024, 3072, 64);
}

// Round 11
// 184.083 us; speedup vs baseline: 1.6690x; 1.0960x over previous
//
#include <hip/hip_runtime.h>

typedef unsigned short u16;
typedef unsigned int u32;
typedef u16  u16x8 __attribute__((ext_vector_type(8)));
typedef u16  u16x4 __attribute__((ext_vector_type(4)));
typedef u32  u32x4 __attribute__((ext_vector_type(4)));
typedef __bf16 bf16x2 __attribute__((ext_vector_type(2)));
typedef __bf16 bf16x8 __attribute__((ext_vector_type(8)));
typedef float f32x4 __attribute__((ext_vector_type(4)));
typedef float f32x16 __attribute__((ext_vector_type(16)));

// ALiBi prefix window (keys with slope_nat*j > 40 negligible): kb_w per head.
__constant__ int KBW[16]  = {0,1,1,2,3,5,7,10,14,20,28,40,56,80,113,160};

// (h,qb) pairs (byte = h*16+qb) sorted by tile count DESCENDING (LPT schedule).
__constant__ unsigned char RANKTBL[256] = {
  0xBF,0xCF,0xDF,0xEF,0xFF,
  0xBE,0xCE,0xDE,0xEE,0xFE,
  0xAE,0xAF,
  0xAD,0xBD,0xCD,0xDD,0xED,0xFD,
  0xAC,0xBC,0xCC,0xDC,0xEC,0xFC,
  0xAB,0xBB,0xCB,0xDB,0xEB,0xFB,
  0xAA,0xBA,0xCA,0xDA,0xEA,0xFA,
  0x9A,0x9B,0x9C,0x9D,0x9E,0x9F,
  0x99,0xA9,0xB9,0xC9,0xD9,0xE9,0xF9,
  0x98,0xA8,0xB8,0xC8,0xD8,0xE8,0xF8,
  0x97,0xA7,0xB7,0xC7,0xD7,0xE7,0xF7,
  0x87,0x88,0x89,0x8A,0x8B,0x8C,0x8D,0x8E,0x8F,
  0x86,0x96,0xA6,0xB6,0xC6,0xD6,0xE6,0xF6,
  0x85,0x95,0xA5,0xB5,0xC5,0xD5,0xE5,0xF5,
  0x75,0x76,0x77,0x78,0x79,0x7A,0x7B,0x7C,0x7D,0x7E,0x7F,
  0x74,0x84,0x94,0xA4,0xB4,0xC4,0xD4,0xE4,0xF4,
  0x63,0x64,0x65,0x66,0x67,0x68,0x69,0x6A,0x6B,0x6C,0x6D,0x6E,0x6F,
  0x73,0x83,0x93,0xA3,0xB3,0xC3,0xD3,0xE3,0xF3,
  0x52,0x53,0x54,0x55,0x56,0x57,0x58,0x59,0x5A,0x5B,0x5C,0x5D,0x5E,0x5F,
  0x62,0x72,0x82,0x92,0xA2,0xB2,0xC2,0xD2,0xE2,0xF2,
  0x41,0x42,0x43,0x44,0x45,0x46,0x47,0x48,0x49,0x4A,0x4B,0x4C,0x4D,0x4E,0x4F,
  0x51,0x61,0x71,0x81,0x91,0xA1,0xB1,0xC1,0xD1,0xE1,0xF1,
  0x31,0x32,0x33,0x34,0x35,0x36,0x37,0x38,0x39,0x3A,0x3B,0x3C,0x3D,0x3E,0x3F,
  0x10,0x11,0x12,0x13,0x14,0x15,0x16,0x17,0x18,0x19,0x1A,0x1B,0x1C,0x1D,0x1E,0x1F,
  0x20,0x21,0x22,0x23,0x24,0x25,0x26,0x27,0x28,0x29,0x2A,0x2B,0x2C,0x2D,0x2E,0x2F,
  0x30,0x40,0x50,0x60,0x70,0x80,0x90,0xA0,0xB0,0xC0,0xD0,0xE0,0xF0,
  0x00,0x01,0x02,0x03,0x04,0x05,0x06,0x07,0x08,0x09,0x0A,0x0B,0x0C,0x0D,0x0E,0x0F
};

// fp32 -> bf16 round-to-nearest-even
static __device__ __forceinline__ u16 f2bf(float f) {
  unsigned int u = __float_as_uint(f);
  u += 0x7FFFu + ((u >> 16) & 1u);
  return (u16)(u >> 16);
}

static __device__ __forceinline__ u32 packbf(float a, float b) {
  bf16x2 t;
  t[0] = (__bf16)a;
  t[1] = (__bf16)b;
  return __builtin_bit_cast(u32, t);
}

static __device__ __forceinline__ f32x4 mfma16(bf16x8 a, bf16x8 b, f32x4 c) {
  return __builtin_amdgcn_mfma_f32_16x16x32_bf16(a, b, c, 0, 0, 0);
}
static __device__ __forceinline__ f32x16 mfma32(bf16x8 a, bf16x8 b, f32x16 c) {
  return __builtin_amdgcn_mfma_f32_32x32x16_bf16(a, b, c, 0, 0, 0);
}

static __device__ __forceinline__ void gload16(const void* g, void* lds) {
  __builtin_amdgcn_global_load_lds(
      (const __attribute__((address_space(1))) unsigned int*)g,
      (__attribute__((address_space(3))) unsigned int*)lds, 16, 0, 0);
}

// ---------------- cast x (fp32 -> bf16), 8 elems/thread ----------------
__global__ __launch_bounds__(256) void k_cast_x(const float* __restrict__ in,
                                                u16* __restrict__ out) {
  size_t i = (size_t)blockIdx.x * 256 + threadIdx.x;
  const float4* p = reinterpret_cast<const float4*>(in) + i * 2;
  float4 a = p[0], b = p[1];
  u16x8 r;
  r[0] = f2bf(a.x); r[1] = f2bf(a.y); r[2] = f2bf(a.z); r[3] = f2bf(a.w);
  r[4] = f2bf(b.x); r[5] = f2bf(b.y); r[6] = f2bf(b.z); r[7] = f2bf(b.w);
  *reinterpret_cast<u16x8*>(out + i * 8) = r;
}

// ---------------- fold LoRA into weights + cast to bf16 ----------------
__global__ __launch_bounds__(256) void k_fold_w(
    const float* __restrict__ Wq, const float* __restrict__ Aq, const float* __restrict__ Bq,
    const float* __restrict__ Wk, const float* __restrict__ Ak, const float* __restrict__ Bk,
    const float* __restrict__ Wv, const float* __restrict__ Av, const float* __restrict__ Bv,
    const float* __restrict__ Wp, u16* __restrict__ wqkv, u16* __restrict__ wp) {
  int n = blockIdx.x;
  int widx = n >> 10, nr = n & 1023;
  const float *W, *A, *Bm; u16* dst;
  if (widx == 0)      { W = Wq; A = Aq; Bm = Bq; dst = wqkv; }
  else if (widx == 1) { W = Wk; A = Ak; Bm = Bk; dst = wqkv + (1 << 20); }
  else if (widx == 2) { W = Wv; A = Av; Bm = Bv; dst = wqkv + (2 << 20); }
  else                { W = Wp; A = nullptr; Bm = nullptr; dst = wp; }
  int e0 = threadIdx.x * 4;
  float4 w = *reinterpret_cast<const float4*>(W + (size_t)nr * 1024 + e0);
  if (widx < 3) {
    float acx = 0.f, acy = 0.f, acz = 0.f, acw = 0.f;
#pragma unroll
    for (int r = 0; r < 8; r++) {
      float ar = A[nr * 8 + r];
      float4 bm = *reinterpret_cast<const float4*>(Bm + (size_t)r * 1024 + e0);
      acx += ar * bm.x; acy += ar * bm.y; acz += ar * bm.z; acw += ar * bm.w;
    }
    w.x += 2.0f * acx; w.y += 2.0f * acy; w.z += 2.0f * acz; w.w += 2.0f * acw;
  }
  u16x4 r4; r4[0] = f2bf(w.x); r4[1] = f2bf(w.y); r4[2] = f2bf(w.z); r4[3] = f2bf(w.w);
  *reinterpret_cast<u16x4*>(dst + (size_t)nr * 1024 + e0) = r4;
}

// ---------------- GEMM v3: 8-phase schedule, FULL 3-bit XOR swizzle ----------------
// C[M,N] = A[M,K(lda)] * Bw[N,K]^T.  128x256 tile, BK=64, 8 waves (2Mx4N),
// per-wave 64x64 out.  LDS: As[2][128][64], Bs[2][256][64] u16, row-major.
// Swizzle: 16B slot s of row r holds global slot s^(r&7)  (conflict-free:
// any 8-lane service group reading rows r..r+7 at one slot hits 8 distinct slots).
// Per K-tile: 4 phases {ds_read subtile | stage | bar | lgkm(0) | 8 MFMA | bar};
// stage B at ph3 (B reads done ph2), A at ph4; counted vmcnt(6) at ph4/ph8 only.
template<int OUTF32>
__global__ __launch_bounds__(512) void k_gemm8(const u16* __restrict__ Ag,
                                               const u16* __restrict__ Bg,
                                               void* __restrict__ C,
                                               int K, int N, int lda, int gx) {
  __shared__ __align__(16) u16 As[2][8192];    // [2][128][64]  32KB
  __shared__ __align__(16) u16 Bs[2][16384];   // [2][256][64]  64KB
  const int tid = threadIdx.x;
  const int wid = tid >> 6, lane = tid & 63;
  const int l15 = lane & 15, lg = lane >> 4;
  const int wr = wid >> 2, wc = wid & 3;
  // bijective XCD swizzle (nwg % 8 == 0 for all our grids)
  const int nwg = gridDim.x, cpx = nwg >> 3;
  const int bid = (int)blockIdx.x;
  const int sid = (bid & 7) * cpx + (bid >> 3);
  const int m0 = (sid % gx) * 128, n0 = (sid / gx) * 256;

  const int lrow = lane >> 3;                        // row-within-8 for staging
  const int lslot = lane & 7;                        // 16B slot for staging

  f32x4 acc[4][4];
#pragma unroll
  for (int i = 0; i < 4; i++)
#pragma unroll
    for (int j = 0; j < 4; j++) acc[i][j] = (f32x4)0.0f;

  auto stageA = [&](int d, int t) {   // 2 rounds of 64 rows
#pragma unroll
    for (int i = 0; i < 2; i++) {
      int row = i * 64 + wid * 8 + lrow;
      int sc = (lslot ^ (row & 7)) << 3;             // pre-swizzled source col (u16)
      gload16(Ag + (size_t)(m0 + row) * lda + t * 64 + sc,
              &As[d][(i * 64 + wid * 8) * 64]);
    }
  };
  auto stageB = [&](int d, int t) {   // 4 rounds of 64 rows
#pragma unroll
    for (int i = 0; i < 4; i++) {
      int row = i * 64 + wid * 8 + lrow;
      int sc = (lslot ^ (row & 7)) << 3;
      gload16(Bg + (size_t)(n0 + row) * K + t * 64 + sc,
              &Bs[d][(i * 64 + wid * 8) * 64]);
    }
  };
  auto ldsA = [&](int d, int m, int kk) {
    int rr = wr * 64 + m * 16 + l15;
    return *reinterpret_cast<const bf16x8*>(&As[d][rr * 64 + (((kk * 4 + lg) ^ (rr & 7)) << 3)]);
  };
  auto ldsB = [&](int d, int n, int kk) {
    int rr = wc * 64 + n * 16 + l15;
    return *reinterpret_cast<const bf16x8*>(&Bs[d][rr * 64 + (((kk * 4 + lg) ^ (rr & 7)) << 3)]);
  };

  bf16x8 fa[4][2], fb[4][2];
  auto quad = [&](int mh, int nh) {
    __builtin_amdgcn_s_setprio(1);
#pragma unroll
    for (int m = 0; m < 2; m++)
#pragma unroll
      for (int n = 0; n < 2; n++)
#pragma unroll
        for (int kk = 0; kk < 2; kk++)
          acc[mh * 2 + m][nh * 2 + n] =
              mfma16(fa[mh * 2 + m][kk], fb[nh * 2 + n][kk], acc[mh * 2 + m][nh * 2 + n]);
    __builtin_amdgcn_s_setprio(0);
  };

#define MIDBAR do { asm volatile("s_barrier" ::: "memory"); \
                    asm volatile("s_waitcnt lgkmcnt(0)" ::: "memory"); } while (0)
#define ENDBAR asm volatile("s_barrier" ::: "memory")

  // prologue: tiles 0,1 into buf0,buf1; drain; barrier
  stageB(0, 0); stageA(0, 0); stageB(1, 1); stageA(1, 1);
  asm volatile("s_waitcnt vmcnt(0)" ::: "memory");
  asm volatile("s_barrier" ::: "memory");

  const int niter = K >> 7;                 // 2 K-tiles per iteration
  for (int it = 0; it < niter; ++it) {
    const bool st = (it + 1 < niter);
    const int T2 = 2 * it + 2;
#pragma unroll
    for (int d = 0; d < 2; ++d) {           // d=0: tile 2it (ph1-4); d=1: tile 2it+1 (ph5-8)
      // ph1/ph5: read A m0-1 + B n0-1, MFMA quad(0,0)
#pragma unroll
      for (int m = 0; m < 2; m++)
#pragma unroll
        for (int kk = 0; kk < 2; kk++) fa[m][kk] = ldsA(d, m, kk);
#pragma unroll
      for (int n = 0; n < 2; n++)
#pragma unroll
        for (int kk = 0; kk < 2; kk++) fb[n][kk] = ldsB(d, n, kk);
      MIDBAR; quad(0, 0); ENDBAR;
      // ph2/ph6: read B n2-3, MFMA quad(0,1)
#pragma unroll
      for (int n = 2; n < 4; n++)
#pragma unroll
        for (int kk = 0; kk < 2; kk++) fb[n][kk] = ldsB(d, n, kk);
      MIDBAR; quad(0, 1); ENDBAR;
      // ph3/ph7: read A m2-3, stage B(T2+d) into buf d (B reads of buf d done ph2)
#pragma unroll
      for (int m = 2; m < 4; m++)
#pragma unroll
        for (int kk = 0; kk < 2; kk++) fa[m][kk] = ldsA(d, m, kk);
      if (st) stageB(d, T2 + d);
      MIDBAR; quad(1, 1); ENDBAR;
      // ph4/ph8: stage A(T2+d) (A reads of buf d done ph3); counted vmcnt
      if (st) stageA(d, T2 + d);
      MIDBAR; quad(1, 0);
      if (st) asm volatile("s_waitcnt vmcnt(6)" ::: "memory");
      else    asm volatile("s_waitcnt vmcnt(0)" ::: "memory");
      ENDBAR;
    }
  }
#undef MIDBAR
#undef ENDBAR

  const int rbase = m0 + wr * 64, cbase = n0 + wc * 64;
#pragma unroll
  for (int m = 0; m < 4; m++)
#pragma unroll
    for (int n = 0; n < 4; n++)
#pragma unroll
      for (int j = 0; j < 4; j++) {
        int r  = rbase + m * 16 + lg * 4 + j;
        int cc = cbase + n * 16 + l15;
        if constexpr (OUTF32) {
          reinterpret_cast<float*>(C)[(size_t)r * N + cc] = acc[m][n][j];
        } else {
          reinterpret_cast<u16*>(C)[(size_t)r * N + cc] = f2bf(acc[m][n][j]);
        }
      }
}

// ---------------- V transpose: qkv V-section -> vt[b][h][d][t] ----------------
__global__ __launch_bounds__(256) void k_vt(const u16* __restrict__ qkv,
                                            u16* __restrict__ vt) {
  __shared__ __align__(16) u16 tile[64 * 64];
  const int tb = blockIdx.x, h = blockIdx.y, b = blockIdx.z;
  const int tid = threadIdx.x;
  const size_t rb = (size_t)b * 2048;
  const int hv = 2048 + h * 64;
#pragma unroll
  for (int p = 0; p < 2; p++) {
    int r = p * 32 + (tid >> 3);
    int c = (tid & 7) * 8;
    u16x8 v = *reinterpret_cast<const u16x8*>(qkv + (rb + tb * 64 + r) * 3072 + hv + c);
    int slot = (c >> 3) ^ (r & 7) ^ ((r >> 3) & 7);
    *reinterpret_cast<u16x8*>(tile + r * 64 + slot * 8) = v;
  }
  __syncthreads();
#pragma unroll
  for (int p = 0; p < 2; p++) {
    int d = p * 32 + (tid >> 3);
    int t0 = (tid & 7) * 8;
    u16x8 v;
#pragma unroll
    for (int j = 0; j < 8; j++) {
      int r = t0 + j;
      int slot = (d >> 3) ^ (r & 7) ^ ((r >> 3) & 7);
      v[j] = tile[r * 64 + slot * 8 + (d & 7)];
    }
    *reinterpret_cast<u16x8*>(vt + ((size_t)(b * 16 + h) * 64 + d) * 2048 + tb * 64 + t0) = v;
  }
}

// ---------------- flash attention v7: mask-split + max3 ----------------
__global__ __launch_bounds__(256) void k_attn(const u16* __restrict__ qkv,
                                              const u16* __restrict__ vt,
                                              u16* __restrict__ aout) {
  __shared__ __align__(16) u16 Kl[2][64 * 64];   // [key][d], swizzled 16B slots
  __shared__ __align__(16) u16 Vl[2][64 * 64];   // [d][key], same swizzle
  const int tid = threadIdx.x, wave = tid >> 6, lane = tid & 63;
  const int l31 = lane & 31, half = lane >> 5;
  const int i = (int)blockIdx.x;
  const int b = i & 3, p = i >> 2;
  const int k4 = p >> 6, j4 = p & 63;
  const int ridx = (k4 == 0) ? j4 : (k4 == 1) ? 127 - j4 : (k4 == 2) ? 128 + j4 : 255 - j4;
  const int hqv = RANKTBL[ridx];
  const int h = hqv >> 4, qb = hqv & 15;
  const int rb = b * 2048;
  const int hq = h * 64, hk = 1024 + h * 64;
  const int bh64 = (b * 16 + h) * 64;
  const int qB = qb * 128;
  const int q0w = qB + wave * 32;
  const int q = q0w + l31;

  bf16x8 qf[4];
#pragma unroll
  for (int c = 0; c < 4; c++)
    qf[c] = *reinterpret_cast<const bf16x8*>(qkv + (size_t)(rb + q) * 3072 + hq + c * 16 + half * 8);

  const float slope2 = exp2f(-0.5f * (float)(h + 1)) * 1.44269504f;
  const float c0 = 0.18033688f;

  const int kend = min(2 * qb + 1, KBW[h]);

  float mrun = -1e30f, lrun = 0.f;
  f32x16 o0 = (f32x16)0.0f, o1 = (f32x16)0.0f;

  auto stage = [&](int kvr, int dst) {
#pragma unroll
    for (int i2 = 0; i2 < 2; i2++) {
      int row = (i2 * 4 + wave) * 8 + (lane >> 3);
      int scol = ((lane & 7) ^ (row & 7)) << 3;
      gload16(qkv + (size_t)(rb + kvr + row) * 3072 + hk + scol, &Kl[dst][(i2 * 4 + wave) * 512]);
      gload16(vt + (size_t)(bh64 + row) * 2048 + kvr + scol,     &Vl[dst][(i2 * 4 + wave) * 512]);
    }
  };

  stage(0, 0);
  __syncthreads();

  int bfi = 0;
  for (int kb = 0; kb <= kend; ++kb, bfi ^= 1) {
    const int kvr = kb * 64;
    if (kb < kend) stage(kvr + 64, bfi ^ 1);

    if (kvr <= q0w + 31) {
      f32x16 s[2];
#pragma unroll
      for (int t = 0; t < 2; t++) s[t] = (f32x16)0.0f;
      __builtin_amdgcn_s_setprio(1);
#pragma unroll
      for (int t = 0; t < 2; t++) {
        int r = t * 32 + l31;
#pragma unroll
        for (int cc = 0; cc < 4; cc++) {
          bf16x8 kf = *reinterpret_cast<const bf16x8*>(
              &Kl[bfi][r * 64 + (((cc * 2 + half) ^ (r & 7)) << 3)]);
          s[t] = mfma32(kf, qf[cc], s[t]);
        }
      }
      __builtin_amdgcn_s_setprio(0);

      const bool domask = (kvr + 63 > q0w);   // wave-uniform
      const int qrel = q - kvr - half * 4;
      const float qb0 = slope2 * (float)qrel;
      const float qb1 = qb0 - slope2 * 32.0f;
      float mt = -1e30f;
      if (domask) {
#pragma unroll
        for (int t = 0; t < 2; t++) {
          const float qbt = t ? qb1 : qb0;
          const int qmt = t ? (qrel - 32) : qrel;
#pragma unroll
          for (int r = 0; r < 16; r++) {
            const int krel = (r & 3) + 8 * (r >> 2);
            float val = fmaf(s[t][r], c0, fmaf(-slope2, (float)krel, qbt));
            val = (krel <= qmt) ? val : -3.0e38f;
            s[t][r] = val;
            mt = fmaxf(mt, val);
          }
        }
      } else {
#pragma unroll
        for (int t = 0; t < 2; t++) {
          const float qbt = t ? qb1 : qb0;
#pragma unroll
          for (int r = 0; r < 16; r += 2) {
            const int k0 = (r & 3) + 8 * (r >> 2);
            const int k1 = ((r + 1) & 3) + 8 * ((r + 1) >> 2);
            float v0 = fmaf(s[t][r],     c0, fmaf(-slope2, (float)k0, qbt));
            float v1 = fmaf(s[t][r + 1], c0, fmaf(-slope2, (float)k1, qbt));
            s[t][r] = v0; s[t][r + 1] = v1;
            mt = fmaxf(mt, fmaxf(v0, v1));   // max3-fusable
          }
        }
      }
      mt = fmaxf(mt, __shfl_xor(mt, 32));

      if (__any(mt - mrun > 8.0f)) {
        float mn = fmaxf(mrun, mt);
        float al = exp2f(mrun - mn);
        mrun = mn; lrun *= al;
#pragma unroll
        for (int r = 0; r < 16; r++) { o0[r] *= al; o1[r] *= al; }
      }

      float rs0 = 0.f, rs1 = 0.f;
#pragma unroll
      for (int t = 0; t < 2; t++)
#pragma unroll
        for (int r = 0; r < 16; r++) {
          float pp = exp2f(s[t][r] - mrun);
          s[t][r] = pp;
          if (t) rs1 += pp; else rs0 += pp;
        }
      float rs = rs0 + rs1;
      rs += __shfl_xor(rs, 32);
      lrun += rs;

      bf16x8 pf[4];
#pragma unroll
      for (int t = 0; t < 2; t++)
#pragma unroll
        for (int hs = 0; hs < 2; hs++) {
          u32 A0 = packbf(s[t][8 * hs + 0], s[t][8 * hs + 1]);
          u32 B0 = packbf(s[t][8 * hs + 2], s[t][8 * hs + 3]);
          u32 C0 = packbf(s[t][8 * hs + 4], s[t][8 * hs + 5]);
          u32 D0 = packbf(s[t][8 * hs + 6], s[t][8 * hs + 7]);
          asm volatile("v_permlane32_swap_b32 %0, %1" : "+v"(A0), "+v"(C0));
          asm volatile("v_permlane32_swap_b32 %0, %1" : "+v"(B0), "+v"(D0));
          u32x4 fr; fr[0] = A0; fr[1] = B0; fr[2] = C0; fr[3] = D0;
          pf[t * 2 + hs] = __builtin_bit_cast(bf16x8, fr);
        }

      __builtin_amdgcn_s_setprio(1);
#pragma unroll
      for (int dblk = 0; dblk < 2; dblk++) {
        int r = dblk * 32 + l31;
#pragma unroll
        for (int kc = 0; kc < 4; kc++) {
          bf16x8 vf = *reinterpret_cast<const bf16x8*>(
              &Vl[bfi][r * 64 + (((kc * 2 + half) ^ (r & 7)) << 3)]);
          if (dblk) o1 = mfma32(vf, pf[kc], o1);
          else      o0 = mfma32(vf, pf[kc], o0);
        }
      }
      __builtin_amdgcn_s_setprio(0);
    }
    __syncthreads();
  }

  const float linv = 1.0f / lrun;
#pragma unroll
  for (int dblk = 0; dblk < 2; dblk++)
#pragma unroll
    for (int rg = 0; rg < 4; rg++) {
      int d0 = dblk * 32 + 8 * rg + 4 * half;
      u16x4 r4;
#pragma unroll
      for (int j = 0; j < 4; j++) {
        float v = (dblk ? o1[rg * 4 + j] : o0[rg * 4 + j]) * linv;
        r4[j] = f2bf(v);
      }
      *reinterpret_cast<u16x4*>(aout + (size_t)(rb + q) * 3072 + hq + d0) = r4;
    }
}

extern "C" void kernel_launch(void* const* d_in, const int* in_sizes, int n_in,
                              void* d_out, int out_size, void* d_ws, size_t ws_size,
                              hipStream_t stream) {
  (void)in_sizes; (void)n_in; (void)out_size; (void)ws_size;
  const float* x  = (const float*)d_in[0];
  const float* Wq = (const float*)d_in[1];
  const float* Aq = (const float*)d_in[2];
  const float* Bq = (const float*)d_in[3];
  const float* Wk = (const float*)d_in[4];
  const float* Ak = (const float*)d_in[5];
  const float* Bk = (const float*)d_in[6];
  const float* Wv = (const float*)d_in[7];
  const float* Av = (const float*)d_in[8];
  const float* Bv = (const float*)d_in[9];
  const float* Wp = (const float*)d_in[10];

  char* ws = (char*)d_ws;
  u16* xb   = (u16*)(ws);                  // [8192][1024] bf16 (dead after gemm1)
  u16* wqkv = (u16*)(ws + 16777216);       // [3072][1024] bf16
  u16* wp   = (u16*)(ws + 23068672);       // [1024][1024] bf16
  u16* qkv  = (u16*)(ws + 25165824);       // [8192][3072] bf16
  u16* vt   = xb;                          // [4][16][64][2048] bf16, reuses xb
  float* out = (float*)d_out;

  k_cast_x<<<dim3(4096), dim3(256), 0, stream>>>(x, xb);
  k_fold_w<<<dim3(4096), dim3(256), 0, stream>>>(Wq, Aq, Bq, Wk, Ak, Bk, Wv, Av, Bv, Wp, wqkv, wp);
  // QKV GEMM: M=8192 N=3072 K=1024 -> grid 64x12 = 768 blocks (3/CU exact)
  k_gemm8<0><<<dim3(768), dim3(512), 0, stream>>>(xb, wqkv, (void*)qkv, 1024, 3072, 1024, 64);
  k_vt<<<dim3(32, 16, 4), dim3(256), 0, stream>>>(qkv, vt);
  // attention writes its output into qkv's Q-columns (in-place, stride 3072)
  k_attn<<<dim3(1024), dim3(256), 0, stream>>>(qkv, vt, qkv);
  // output GEMM: M=8192 N=1024 K=1024 -> grid 64x4 = 256 blocks (1/CU exact)
  k_gemm8<1><<<dim3(256), dim3(512), 0, stream>>>(qkv, wp, (void*)out, 1024, 1024, 3072, 64);
}

// Round 12
// 182.621 us; speedup vs baseline: 1.6823x; 1.0080x over previous
//
#include <hip/hip_runtime.h>

typedef unsigned short u16;
typedef unsigned int u32;
typedef u16  u16x8 __attribute__((ext_vector_type(8)));
typedef u16  u16x4 __attribute__((ext_vector_type(4)));
typedef u32  u32x4 __attribute__((ext_vector_type(4)));
typedef __bf16 bf16x2 __attribute__((ext_vector_type(2)));
typedef __bf16 bf16x8 __attribute__((ext_vector_type(8)));
typedef float f32x4 __attribute__((ext_vector_type(4)));
typedef float f32x16 __attribute__((ext_vector_type(16)));

// ALiBi prefix window (keys with slope_nat*j > 40 negligible): kb_w per head.
__constant__ int KBW[16]  = {0,1,1,2,3,5,7,10,14,20,28,40,56,80,113,160};

// (h,qb) pairs (byte = h*16+qb) sorted by tile count DESCENDING (LPT schedule).
__constant__ unsigned char RANKTBL[256] = {
  0xBF,0xCF,0xDF,0xEF,0xFF,
  0xBE,0xCE,0xDE,0xEE,0xFE,
  0xAE,0xAF,
  0xAD,0xBD,0xCD,0xDD,0xED,0xFD,
  0xAC,0xBC,0xCC,0xDC,0xEC,0xFC,
  0xAB,0xBB,0xCB,0xDB,0xEB,0xFB,
  0xAA,0xBA,0xCA,0xDA,0xEA,0xFA,
  0x9A,0x9B,0x9C,0x9D,0x9E,0x9F,
  0x99,0xA9,0xB9,0xC9,0xD9,0xE9,0xF9,
  0x98,0xA8,0xB8,0xC8,0xD8,0xE8,0xF8,
  0x97,0xA7,0xB7,0xC7,0xD7,0xE7,0xF7,
  0x87,0x88,0x89,0x8A,0x8B,0x8C,0x8D,0x8E,0x8F,
  0x86,0x96,0xA6,0xB6,0xC6,0xD6,0xE6,0xF6,
  0x85,0x95,0xA5,0xB5,0xC5,0xD5,0xE5,0xF5,
  0x75,0x76,0x77,0x78,0x79,0x7A,0x7B,0x7C,0x7D,0x7E,0x7F,
  0x74,0x84,0x94,0xA4,0xB4,0xC4,0xD4,0xE4,0xF4,
  0x63,0x64,0x65,0x66,0x67,0x68,0x69,0x6A,0x6B,0x6C,0x6D,0x6E,0x6F,
  0x73,0x83,0x93,0xA3,0xB3,0xC3,0xD3,0xE3,0xF3,
  0x52,0x53,0x54,0x55,0x56,0x57,0x58,0x59,0x5A,0x5B,0x5C,0x5D,0x5E,0x5F,
  0x62,0x72,0x82,0x92,0xA2,0xB2,0xC2,0xD2,0xE2,0xF2,
  0x41,0x42,0x43,0x44,0x45,0x46,0x47,0x48,0x49,0x4A,0x4B,0x4C,0x4D,0x4E,0x4F,
  0x51,0x61,0x71,0x81,0x91,0xA1,0xB1,0xC1,0xD1,0xE1,0xF1,
  0x31,0x32,0x33,0x34,0x35,0x36,0x37,0x38,0x39,0x3A,0x3B,0x3C,0x3D,0x3E,0x3F,
  0x10,0x11,0x12,0x13,0x14,0x15,0x16,0x17,0x18,0x19,0x1A,0x1B,0x1C,0x1D,0x1E,0x1F,
  0x20,0x21,0x22,0x23,0x24,0x25,0x26,0x27,0x28,0x29,0x2A,0x2B,0x2C,0x2D,0x2E,0x2F,
  0x30,0x40,0x50,0x60,0x70,0x80,0x90,0xA0,0xB0,0xC0,0xD0,0xE0,0xF0,
  0x00,0x01,0x02,0x03,0x04,0x05,0x06,0x07,0x08,0x09,0x0A,0x0B,0x0C,0x0D,0x0E,0x0F
};

// fp32 -> bf16 round-to-nearest-even
static __device__ __forceinline__ u16 f2bf(float f) {
  unsigned int u = __float_as_uint(f);
  u += 0x7FFFu + ((u >> 16) & 1u);
  return (u16)(u >> 16);
}

static __device__ __forceinline__ u32 packbf(float a, float b) {
  bf16x2 t;
  t[0] = (__bf16)a;
  t[1] = (__bf16)b;
  return __builtin_bit_cast(u32, t);
}

static __device__ __forceinline__ f32x4 mfma16(bf16x8 a, bf16x8 b, f32x4 c) {
  return __builtin_amdgcn_mfma_f32_16x16x32_bf16(a, b, c, 0, 0, 0);
}
static __device__ __forceinline__ f32x16 mfma32(bf16x8 a, bf16x8 b, f32x16 c) {
  return __builtin_amdgcn_mfma_f32_32x32x16_bf16(a, b, c, 0, 0, 0);
}

static __device__ __forceinline__ void gload16(const void* g, void* lds) {
  __builtin_amdgcn_global_load_lds(
      (const __attribute__((address_space(1))) unsigned int*)g,
      (__attribute__((address_space(3))) unsigned int*)lds, 16, 0, 0);
}

// ---------------- cast x (fp32 -> bf16), 8 elems/thread ----------------
__global__ __launch_bounds__(256) void k_cast_x(const float* __restrict__ in,
                                                u16* __restrict__ out) {
  size_t i = (size_t)blockIdx.x * 256 + threadIdx.x;
  const float4* p = reinterpret_cast<const float4*>(in) + i * 2;
  float4 a = p[0], b = p[1];
  u16x8 r;
  r[0] = f2bf(a.x); r[1] = f2bf(a.y); r[2] = f2bf(a.z); r[3] = f2bf(a.w);
  r[4] = f2bf(b.x); r[5] = f2bf(b.y); r[6] = f2bf(b.z); r[7] = f2bf(b.w);
  *reinterpret_cast<u16x8*>(out + i * 8) = r;
}

// ---------------- fold LoRA into weights + cast to bf16 ----------------
__global__ __launch_bounds__(256) void k_fold_w(
    const float* __restrict__ Wq, const float* __restrict__ Aq, const float* __restrict__ Bq,
    const float* __restrict__ Wk, const float* __restrict__ Ak, const float* __restrict__ Bk,
    const float* __restrict__ Wv, const float* __restrict__ Av, const float* __restrict__ Bv,
    const float* __restrict__ Wp, u16* __restrict__ wqkv, u16* __restrict__ wp) {
  int n = blockIdx.x;
  int widx = n >> 10, nr = n & 1023;
  const float *W, *A, *Bm; u16* dst;
  if (widx == 0)      { W = Wq; A = Aq; Bm = Bq; dst = wqkv; }
  else if (widx == 1) { W = Wk; A = Ak; Bm = Bk; dst = wqkv + (1 << 20); }
  else if (widx == 2) { W = Wv; A = Av; Bm = Bv; dst = wqkv + (2 << 20); }
  else                { W = Wp; A = nullptr; Bm = nullptr; dst = wp; }
  int e0 = threadIdx.x * 4;
  float4 w = *reinterpret_cast<const float4*>(W + (size_t)nr * 1024 + e0);
  if (widx < 3) {
    float acx = 0.f, acy = 0.f, acz = 0.f, acw = 0.f;
#pragma unroll
    for (int r = 0; r < 8; r++) {
      float ar = A[nr * 8 + r];
      float4 bm = *reinterpret_cast<const float4*>(Bm + (size_t)r * 1024 + e0);
      acx += ar * bm.x; acy += ar * bm.y; acz += ar * bm.z; acw += ar * bm.w;
    }
    w.x += 2.0f * acx; w.y += 2.0f * acy; w.z += 2.0f * acz; w.w += 2.0f * acw;
  }
  u16x4 r4; r4[0] = f2bf(w.x); r4[1] = f2bf(w.y); r4[2] = f2bf(w.z); r4[3] = f2bf(w.w);
  *reinterpret_cast<u16x4*>(dst + (size_t)nr * 1024 + e0) = r4;
}

// ---------------- GEMM v4: 2-phase/K-tile, 16 MFMA/phase ----------------
// C[M,N] = A[M,K(lda)] * Bw[N,K]^T.  128x256 tile, BK=64, 8 waves (2Mx4N),
// per-wave 64x64 out.  LDS: As[2][128][64], Bs[2][256][64] u16, full 3-bit
// XOR swizzle (slot s of row r holds global slot s^(r&7); conflict-free).
// Per K-tile t (buf d=t&1):
//  phA: ds_read A m0-3 (8) + B n0-1 (4); issue B(t+1 -> buf d^1); bar;
//       lgkm(0); 16 MFMA (m0-3 x n0-1); bar
//  phB: ds_read B n2-3 (4); issue A(t+2 -> buf d); bar; lgkm(0);
//       16 MFMA (m0-3 x n2-3); vmcnt(2); bar
// Windows verified: A-region of buf d register-resident after phA's
// lgkm+bar; B-region of buf d^1 free since phB(t-1). vmcnt(2) keeps only
// the newest stage-A in flight -> B(t+1)/A(t+1) landed before phA(t+1).
template<int OUTF32>
__global__ __launch_bounds__(512) void k_gemm8(const u16* __restrict__ Ag,
                                               const u16* __restrict__ Bg,
                                               void* __restrict__ C,
                                               int K, int N, int lda, int gx) {
  __shared__ __align__(16) u16 As[2][8192];    // [2][128][64]  32KB
  __shared__ __align__(16) u16 Bs[2][16384];   // [2][256][64]  64KB
  const int tid = threadIdx.x;
  const int wid = tid >> 6, lane = tid & 63;
  const int l15 = lane & 15, lg = lane >> 4;
  const int wr = wid >> 2, wc = wid & 3;
  // bijective XCD swizzle (nwg % 8 == 0 for all our grids)
  const int nwg = gridDim.x, cpx = nwg >> 3;
  const int bid = (int)blockIdx.x;
  const int sid = (bid & 7) * cpx + (bid >> 3);
  const int m0 = (sid % gx) * 128, n0 = (sid / gx) * 256;

  const int lrow = lane >> 3;                        // row-within-8 for staging
  const int lslot = lane & 7;                        // 16B slot for staging

  f32x4 acc[4][4];
#pragma unroll
  for (int i = 0; i < 4; i++)
#pragma unroll
    for (int j = 0; j < 4; j++) acc[i][j] = (f32x4)0.0f;

  auto stageA = [&](int d, int t) {   // 2 gloads/thread
#pragma unroll
    for (int i = 0; i < 2; i++) {
      int row = i * 64 + wid * 8 + lrow;
      int sc = (lslot ^ (row & 7)) << 3;             // pre-swizzled source col (u16)
      gload16(Ag + (size_t)(m0 + row) * lda + t * 64 + sc,
              &As[d][(i * 64 + wid * 8) * 64]);
    }
  };
  auto stageB = [&](int d, int t) {   // 4 gloads/thread
#pragma unroll
    for (int i = 0; i < 4; i++) {
      int row = i * 64 + wid * 8 + lrow;
      int sc = (lslot ^ (row & 7)) << 3;
      gload16(Bg + (size_t)(n0 + row) * K + t * 64 + sc,
              &Bs[d][(i * 64 + wid * 8) * 64]);
    }
  };
  auto ldsA = [&](int d, int m, int kk) {
    int rr = wr * 64 + m * 16 + l15;
    return *reinterpret_cast<const bf16x8*>(&As[d][rr * 64 + (((kk * 4 + lg) ^ (rr & 7)) << 3)]);
  };
  auto ldsB = [&](int d, int n, int kk) {
    int rr = wc * 64 + n * 16 + l15;
    return *reinterpret_cast<const bf16x8*>(&Bs[d][rr * 64 + (((kk * 4 + lg) ^ (rr & 7)) << 3)]);
  };

#define MIDBAR do { asm volatile("s_barrier" ::: "memory"); \
                    asm volatile("s_waitcnt lgkmcnt(0)" ::: "memory"); } while (0)
#define ENDBAR asm volatile("s_barrier" ::: "memory")

  // prologue: B(0),A(0) into buf0, A(1) into buf1; wait B0+A0, keep A1 in flight
  stageB(0, 0); stageA(0, 0); stageA(1, 1);
  asm volatile("s_waitcnt vmcnt(2)" ::: "memory");
  asm volatile("s_barrier" ::: "memory");

  bf16x8 fa[4][2], fb[2][2];
  const int nt = K >> 6;                  // K-tiles
  for (int t = 0; t < nt; ++t) {
    const int d = t & 1;
    // ---- phA: all A-frags + B n0-1; stage next B into other buffer ----
#pragma unroll
    for (int m = 0; m < 4; m++)
#pragma unroll
      for (int kk = 0; kk < 2; kk++) fa[m][kk] = ldsA(d, m, kk);
#pragma unroll
    for (int n = 0; n < 2; n++)
#pragma unroll
      for (int kk = 0; kk < 2; kk++) fb[n][kk] = ldsB(d, n, kk);
    if (t + 1 < nt) stageB(d ^ 1, t + 1);
    MIDBAR;
    __builtin_amdgcn_s_setprio(1);
#pragma unroll
    for (int m = 0; m < 4; m++)
#pragma unroll
      for (int n = 0; n < 2; n++)
#pragma unroll
        for (int kk = 0; kk < 2; kk++)
          acc[m][n] = mfma16(fa[m][kk], fb[n][kk], acc[m][n]);
    __builtin_amdgcn_s_setprio(0);
    ENDBAR;
    // ---- phB: B n2-3; stage next-next A into this buffer ----
#pragma unroll
    for (int n = 0; n < 2; n++)
#pragma unroll
      for (int kk = 0; kk < 2; kk++) fb[n][kk] = ldsB(d, n + 2, kk);
    if (t + 2 < nt) stageA(d, t + 2);
    MIDBAR;
    __builtin_amdgcn_s_setprio(1);
#pragma unroll
    for (int m = 0; m < 4; m++)
#pragma unroll
      for (int n = 0; n < 2; n++)
#pragma unroll
        for (int kk = 0; kk < 2; kk++)
          acc[m][n + 2] = mfma16(fa[m][kk], fb[n][kk], acc[m][n + 2]);
    __builtin_amdgcn_s_setprio(0);
    if (t + 2 < nt) asm volatile("s_waitcnt vmcnt(2)" ::: "memory");
    else            asm volatile("s_waitcnt vmcnt(0)" ::: "memory");
    ENDBAR;
  }
#undef MIDBAR
#undef ENDBAR

  const int rbase = m0 + wr * 64, cbase = n0 + wc * 64;
#pragma unroll
  for (int m = 0; m < 4; m++)
#pragma unroll
    for (int n = 0; n < 4; n++)
#pragma unroll
      for (int j = 0; j < 4; j++) {
        int r  = rbase + m * 16 + lg * 4 + j;
        int cc = cbase + n * 16 + l15;
        if constexpr (OUTF32) {
          reinterpret_cast<float*>(C)[(size_t)r * N + cc] = acc[m][n][j];
        } else {
          reinterpret_cast<u16*>(C)[(size_t)r * N + cc] = f2bf(acc[m][n][j]);
        }
      }
}

// ---------------- V transpose: qkv V-section -> vt[b][h][d][t] ----------------
__global__ __launch_bounds__(256) void k_vt(const u16* __restrict__ qkv,
                                            u16* __restrict__ vt) {
  __shared__ __align__(16) u16 tile[64 * 64];
  const int tb = blockIdx.x, h = blockIdx.y, b = blockIdx.z;
  const int tid = threadIdx.x;
  const size_t rb = (size_t)b * 2048;
  const int hv = 2048 + h * 64;
#pragma unroll
  for (int p = 0; p < 2; p++) {
    int r = p * 32 + (tid >> 3);
    int c = (tid & 7) * 8;
    u16x8 v = *reinterpret_cast<const u16x8*>(qkv + (rb + tb * 64 + r) * 3072 + hv + c);
    int slot = (c >> 3) ^ (r & 7) ^ ((r >> 3) & 7);
    *reinterpret_cast<u16x8*>(tile + r * 64 + slot * 8) = v;
  }
  __syncthreads();
#pragma unroll
  for (int p = 0; p < 2; p++) {
    int d = p * 32 + (tid >> 3);
    int t0 = (tid & 7) * 8;
    u16x8 v;
#pragma unroll
    for (int j = 0; j < 8; j++) {
      int r = t0 + j;
      int slot = (d >> 3) ^ (r & 7) ^ ((r >> 3) & 7);
      v[j] = tile[r * 64 + slot * 8 + (d & 7)];
    }
    *reinterpret_cast<u16x8*>(vt + ((size_t)(b * 16 + h) * 64 + d) * 2048 + tb * 64 + t0) = v;
  }
}

// ---------------- flash attention v7: mask-split + max3 ----------------
__global__ __launch_bounds__(256) void k_attn(const u16* __restrict__ qkv,
                                              const u16* __restrict__ vt,
                                              u16* __restrict__ aout) {
  __shared__ __align__(16) u16 Kl[2][64 * 64];   // [key][d], swizzled 16B slots
  __shared__ __align__(16) u16 Vl[2][64 * 64];   // [d][key], same swizzle
  const int tid = threadIdx.x, wave = tid >> 6, lane = tid & 63;
  const int l31 = lane & 31, half = lane >> 5;
  const int i = (int)blockIdx.x;
  const int b = i & 3, p = i >> 2;
  const int k4 = p >> 6, j4 = p & 63;
  const int ridx = (k4 == 0) ? j4 : (k4 == 1) ? 127 - j4 : (k4 == 2) ? 128 + j4 : 255 - j4;
  const int hqv = RANKTBL[ridx];
  const int h = hqv >> 4, qb = hqv & 15;
  const int rb = b * 2048;
  const int hq = h * 64, hk = 1024 + h * 64;
  const int bh64 = (b * 16 + h) * 64;
  const int qB = qb * 128;
  const int q0w = qB + wave * 32;
  const int q = q0w + l31;

  bf16x8 qf[4];
#pragma unroll
  for (int c = 0; c < 4; c++)
    qf[c] = *reinterpret_cast<const bf16x8*>(qkv + (size_t)(rb + q) * 3072 + hq + c * 16 + half * 8);

  const float slope2 = exp2f(-0.5f * (float)(h + 1)) * 1.44269504f;
  const float c0 = 0.18033688f;

  const int kend = min(2 * qb + 1, KBW[h]);

  float mrun = -1e30f, lrun = 0.f;
  f32x16 o0 = (f32x16)0.0f, o1 = (f32x16)0.0f;

  auto stage = [&](int kvr, int dst) {
#pragma unroll
    for (int i2 = 0; i2 < 2; i2++) {
      int row = (i2 * 4 + wave) * 8 + (lane >> 3);
      int scol = ((lane & 7) ^ (row & 7)) << 3;
      gload16(qkv + (size_t)(rb + kvr + row) * 3072 + hk + scol, &Kl[dst][(i2 * 4 + wave) * 512]);
      gload16(vt + (size_t)(bh64 + row) * 2048 + kvr + scol,     &Vl[dst][(i2 * 4 + wave) * 512]);
    }
  };

  stage(0, 0);
  __syncthreads();

  int bfi = 0;
  for (int kb = 0; kb <= kend; ++kb, bfi ^= 1) {
    const int kvr = kb * 64;
    if (kb < kend) stage(kvr + 64, bfi ^ 1);

    if (kvr <= q0w + 31) {
      f32x16 s[2];
#pragma unroll
      for (int t = 0; t < 2; t++) s[t] = (f32x16)0.0f;
      __builtin_amdgcn_s_setprio(1);
#pragma unroll
      for (int t = 0; t < 2; t++) {
        int r = t * 32 + l31;
#pragma unroll
        for (int cc = 0; cc < 4; cc++) {
          bf16x8 kf = *reinterpret_cast<const bf16x8*>(
              &Kl[bfi][r * 64 + (((cc * 2 + half) ^ (r & 7)) << 3)]);
          s[t] = mfma32(kf, qf[cc], s[t]);
        }
      }
      __builtin_amdgcn_s_setprio(0);

      const bool domask = (kvr + 63 > q0w);   // wave-uniform
      const int qrel = q - kvr - half * 4;
      const float qb0 = slope2 * (float)qrel;
      const float qb1 = qb0 - slope2 * 32.0f;
      float mt = -1e30f;
      if (domask) {
#pragma unroll
        for (int t = 0; t < 2; t++) {
          const float qbt = t ? qb1 : qb0;
          const int qmt = t ? (qrel - 32) : qrel;
#pragma unroll
          for (int r = 0; r < 16; r++) {
            const int krel = (r & 3) + 8 * (r >> 2);
            float val = fmaf(s[t][r], c0, fmaf(-slope2, (float)krel, qbt));
            val = (krel <= qmt) ? val : -3.0e38f;
            s[t][r] = val;
            mt = fmaxf(mt, val);
          }
        }
      } else {
#pragma unroll
        for (int t = 0; t < 2; t++) {
          const float qbt = t ? qb1 : qb0;
#pragma unroll
          for (int r = 0; r < 16; r += 2) {
            const int k0 = (r & 3) + 8 * (r >> 2);
            const int k1 = ((r + 1) & 3) + 8 * ((r + 1) >> 2);
            float v0 = fmaf(s[t][r],     c0, fmaf(-slope2, (float)k0, qbt));
            float v1 = fmaf(s[t][r + 1], c0, fmaf(-slope2, (float)k1, qbt));
            s[t][r] = v0; s[t][r + 1] = v1;
            mt = fmaxf(mt, fmaxf(v0, v1));   // max3-fusable
          }
        }
      }
      mt = fmaxf(mt, __shfl_xor(mt, 32));

      if (__any(mt - mrun > 8.0f)) {
        float mn = fmaxf(mrun, mt);
        float al = exp2f(mrun - mn);
        mrun = mn; lrun *= al;
#pragma unroll
        for (int r = 0; r < 16; r++) { o0[r] *= al; o1[r] *= al; }
      }

      float rs0 = 0.f, rs1 = 0.f;
#pragma unroll
      for (int t = 0; t < 2; t++)
#pragma unroll
        for (int r = 0; r < 16; r++) {
          float pp = exp2f(s[t][r] - mrun);
          s[t][r] = pp;
          if (t) rs1 += pp; else rs0 += pp;
        }
      float rs = rs0 + rs1;
      rs += __shfl_xor(rs, 32);
      lrun += rs;

      bf16x8 pf[4];
#pragma unroll
      for (int t = 0; t < 2; t++)
#pragma unroll
        for (int hs = 0; hs < 2; hs++) {
          u32 A0 = packbf(s[t][8 * hs + 0], s[t][8 * hs + 1]);
          u32 B0 = packbf(s[t][8 * hs + 2], s[t][8 * hs + 3]);
          u32 C0 = packbf(s[t][8 * hs + 4], s[t][8 * hs + 5]);
          u32 D0 = packbf(s[t][8 * hs + 6], s[t][8 * hs + 7]);
          asm volatile("v_permlane32_swap_b32 %0, %1" : "+v"(A0), "+v"(C0));
          asm volatile("v_permlane32_swap_b32 %0, %1" : "+v"(B0), "+v"(D0));
          u32x4 fr; fr[0] = A0; fr[1] = B0; fr[2] = C0; fr[3] = D0;
          pf[t * 2 + hs] = __builtin_bit_cast(bf16x8, fr);
        }

      __builtin_amdgcn_s_setprio(1);
#pragma unroll
      for (int dblk = 0; dblk < 2; dblk++) {
        int r = dblk * 32 + l31;
#pragma unroll
        for (int kc = 0; kc < 4; kc++) {
          bf16x8 vf = *reinterpret_cast<const bf16x8*>(
              &Vl[bfi][r * 64 + (((kc * 2 + half) ^ (r & 7)) << 3)]);
          if (dblk) o1 = mfma32(vf, pf[kc], o1);
          else      o0 = mfma32(vf, pf[kc], o0);
        }
      }
      __builtin_amdgcn_s_setprio(0);
    }
    __syncthreads();
  }

  const float linv = 1.0f / lrun;
#pragma unroll
  for (int dblk = 0; dblk < 2; dblk++)
#pragma unroll
    for (int rg = 0; rg < 4; rg++) {
      int d0 = dblk * 32 + 8 * rg + 4 * half;
      u16x4 r4;
#pragma unroll
      for (int j = 0; j < 4; j++) {
        float v = (dblk ? o1[rg * 4 + j] : o0[rg * 4 + j]) * linv;
        r4[j] = f2bf(v);
      }
      *reinterpret_cast<u16x4*>(aout + (size_t)(rb + q) * 3072 + hq + d0) = r4;
    }
}

extern "C" void kernel_launch(void* const* d_in, const int* in_sizes, int n_in,
                              void* d_out, int out_size, void* d_ws, size_t ws_size,
                              hipStream_t stream) {
  (void)in_sizes; (void)n_in; (void)out_size; (void)ws_size;
  const float* x  = (const float*)d_in[0];
  const float* Wq = (const float*)d_in[1];
  const float* Aq = (const float*)d_in[2];
  const float* Bq = (const float*)d_in[3];
  const float* Wk = (const float*)d_in[4];
  const float* Ak = (const float*)d_in[5];
  const float* Bk = (const float*)d_in[6];
  const float* Wv = (const float*)d_in[7];
  const float* Av = (const float*)d_in[8];
  const float* Bv = (const float*)d_in[9];
  const float* Wp = (const float*)d_in[10];

  char* ws = (char*)d_ws;
  u16* xb   = (u16*)(ws);                  // [8192][1024] bf16 (dead after gemm1)
  u16* wqkv = (u16*)(ws + 16777216);       // [3072][1024] bf16
  u16* wp   = (u16*)(ws + 23068672);       // [1024][1024] bf16
  u16* qkv  = (u16*)(ws + 25165824);       // [8192][3072] bf16
  u16* vt   = xb;                          // [4][16][64][2048] bf16, reuses xb
  float* out = (float*)d_out;

  k_cast_x<<<dim3(4096), dim3(256), 0, stream>>>(x, xb);
  k_fold_w<<<dim3(4096), dim3(256), 0, stream>>>(Wq, Aq, Bq, Wk, Ak, Bk, Wv, Av, Bv, Wp, wqkv, wp);
  // QKV GEMM: M=8192 N=3072 K=1024 -> grid 64x12 = 768 blocks (3/CU exact)
  k_gemm8<0><<<dim3(768), dim3(512), 0, stream>>>(xb, wqkv, (void*)qkv, 1024, 3072, 1024, 64);
  k_vt<<<dim3(32, 16, 4), dim3(256), 0, stream>>>(qkv, vt);
  // attention writes its output into qkv's Q-columns (in-place, stride 3072)
  k_attn<<<dim3(1024), dim3(256), 0, stream>>>(qkv, vt, qkv);
  // output GEMM: M=8192 N=1024 K=1024 -> grid 64x4 = 256 blocks (1/CU exact)
  k_gemm8<1><<<dim3(256), dim3(512), 0, stream>>>(qkv, wp, (void*)out, 1024, 1024, 3072, 64);
}

// Round 13
// 180.704 us; speedup vs baseline: 1.7002x; 1.0106x over previous
//
#include <hip/hip_runtime.h>

typedef unsigned short u16;
typedef unsigned int u32;
typedef u16  u16x8 __attribute__((ext_vector_type(8)));
typedef u16  u16x4 __attribute__((ext_vector_type(4)));
typedef u32  u32x4 __attribute__((ext_vector_type(4)));
typedef __bf16 bf16x2 __attribute__((ext_vector_type(2)));
typedef __bf16 bf16x8 __attribute__((ext_vector_type(8)));
typedef float f32x4 __attribute__((ext_vector_type(4)));
typedef float f32x16 __attribute__((ext_vector_type(16)));

// ALiBi prefix window (keys with slope_nat*j > 40 negligible): kb_w per head.
__constant__ int KBW[16]  = {0,1,1,2,3,5,7,10,14,20,28,40,56,80,113,160};

// (h,qb) pairs (byte = h*16+qb) sorted by tile count DESCENDING (LPT schedule).
__constant__ unsigned char RANKTBL[256] = {
  0xBF,0xCF,0xDF,0xEF,0xFF,
  0xBE,0xCE,0xDE,0xEE,0xFE,
  0xAE,0xAF,
  0xAD,0xBD,0xCD,0xDD,0xED,0xFD,
  0xAC,0xBC,0xCC,0xDC,0xEC,0xFC,
  0xAB,0xBB,0xCB,0xDB,0xEB,0xFB,
  0xAA,0xBA,0xCA,0xDA,0xEA,0xFA,
  0x9A,0x9B,0x9C,0x9D,0x9E,0x9F,
  0x99,0xA9,0xB9,0xC9,0xD9,0xE9,0xF9,
  0x98,0xA8,0xB8,0xC8,0xD8,0xE8,0xF8,
  0x97,0xA7,0xB7,0xC7,0xD7,0xE7,0xF7,
  0x87,0x88,0x89,0x8A,0x8B,0x8C,0x8D,0x8E,0x8F,
  0x86,0x96,0xA6,0xB6,0xC6,0xD6,0xE6,0xF6,
  0x85,0x95,0xA5,0xB5,0xC5,0xD5,0xE5,0xF5,
  0x75,0x76,0x77,0x78,0x79,0x7A,0x7B,0x7C,0x7D,0x7E,0x7F,
  0x74,0x84,0x94,0xA4,0xB4,0xC4,0xD4,0xE4,0xF4,
  0x63,0x64,0x65,0x66,0x67,0x68,0x69,0x6A,0x6B,0x6C,0x6D,0x6E,0x6F,
  0x73,0x83,0x93,0xA3,0xB3,0xC3,0xD3,0xE3,0xF3,
  0x52,0x53,0x54,0x55,0x56,0x57,0x58,0x59,0x5A,0x5B,0x5C,0x5D,0x5E,0x5F,
  0x62,0x72,0x82,0x92,0xA2,0xB2,0xC2,0xD2,0xE2,0xF2,
  0x41,0x42,0x43,0x44,0x45,0x46,0x47,0x48,0x49,0x4A,0x4B,0x4C,0x4D,0x4E,0x4F,
  0x51,0x61,0x71,0x81,0x91,0xA1,0xB1,0xC1,0xD1,0xE1,0xF1,
  0x31,0x32,0x33,0x34,0x35,0x36,0x37,0x38,0x39,0x3A,0x3B,0x3C,0x3D,0x3E,0x3F,
  0x10,0x11,0x12,0x13,0x14,0x15,0x16,0x17,0x18,0x19,0x1A,0x1B,0x1C,0x1D,0x1E,0x1F,
  0x20,0x21,0x22,0x23,0x24,0x25,0x26,0x27,0x28,0x29,0x2A,0x2B,0x2C,0x2D,0x2E,0x2F,
  0x30,0x40,0x50,0x60,0x70,0x80,0x90,0xA0,0xB0,0xC0,0xD0,0xE0,0xF0,
  0x00,0x01,0x02,0x03,0x04,0x05,0x06,0x07,0x08,0x09,0x0A,0x0B,0x0C,0x0D,0x0E,0x0F
};

// fp32 -> bf16 round-to-nearest-even
static __device__ __forceinline__ u16 f2bf(float f) {
  unsigned int u = __float_as_uint(f);
  u += 0x7FFFu + ((u >> 16) & 1u);
  return (u16)(u >> 16);
}

static __device__ __forceinline__ u32 packbf(float a, float b) {
  bf16x2 t;
  t[0] = (__bf16)a;
  t[1] = (__bf16)b;
  return __builtin_bit_cast(u32, t);
}

static __device__ __forceinline__ f32x4 mfma16(bf16x8 a, bf16x8 b, f32x4 c) {
  return __builtin_amdgcn_mfma_f32_16x16x32_bf16(a, b, c, 0, 0, 0);
}
static __device__ __forceinline__ f32x16 mfma32(bf16x8 a, bf16x8 b, f32x16 c) {
  return __builtin_amdgcn_mfma_f32_32x32x16_bf16(a, b, c, 0, 0, 0);
}

static __device__ __forceinline__ void gload16(const void* g, void* lds) {
  __builtin_amdgcn_global_load_lds(
      (const __attribute__((address_space(1))) unsigned int*)g,
      (__attribute__((address_space(3))) unsigned int*)lds, 16, 0, 0);
}

// ---------------- cast x (fp32 -> bf16), 8 elems/thread ----------------
__global__ __launch_bounds__(256) void k_cast_x(const float* __restrict__ in,
                                                u16* __restrict__ out) {
  size_t i = (size_t)blockIdx.x * 256 + threadIdx.x;
  const float4* p = reinterpret_cast<const float4*>(in) + i * 2;
  float4 a = p[0], b = p[1];
  u16x8 r;
  r[0] = f2bf(a.x); r[1] = f2bf(a.y); r[2] = f2bf(a.z); r[3] = f2bf(a.w);
  r[4] = f2bf(b.x); r[5] = f2bf(b.y); r[6] = f2bf(b.z); r[7] = f2bf(b.w);
  *reinterpret_cast<u16x8*>(out + i * 8) = r;
}

// ---------------- fold LoRA into weights + cast to bf16 ----------------
__global__ __launch_bounds__(256) void k_fold_w(
    const float* __restrict__ Wq, const float* __restrict__ Aq, const float* __restrict__ Bq,
    const float* __restrict__ Wk, const float* __restrict__ Ak, const float* __restrict__ Bk,
    const float* __restrict__ Wv, const float* __restrict__ Av, const float* __restrict__ Bv,
    const float* __restrict__ Wp, u16* __restrict__ wqkv, u16* __restrict__ wp) {
  int n = blockIdx.x;
  int widx = n >> 10, nr = n & 1023;
  const float *W, *A, *Bm; u16* dst;
  if (widx == 0)      { W = Wq; A = Aq; Bm = Bq; dst = wqkv; }
  else if (widx == 1) { W = Wk; A = Ak; Bm = Bk; dst = wqkv + (1 << 20); }
  else if (widx == 2) { W = Wv; A = Av; Bm = Bv; dst = wqkv + (2 << 20); }
  else                { W = Wp; A = nullptr; Bm = nullptr; dst = wp; }
  int e0 = threadIdx.x * 4;
  float4 w = *reinterpret_cast<const float4*>(W + (size_t)nr * 1024 + e0);
  if (widx < 3) {
    float acx = 0.f, acy = 0.f, acz = 0.f, acw = 0.f;
#pragma unroll
    for (int r = 0; r < 8; r++) {
      float ar = A[nr * 8 + r];
      float4 bm = *reinterpret_cast<const float4*>(Bm + (size_t)r * 1024 + e0);
      acx += ar * bm.x; acy += ar * bm.y; acz += ar * bm.z; acw += ar * bm.w;
    }
    w.x += 2.0f * acx; w.y += 2.0f * acy; w.z += 2.0f * acz; w.w += 2.0f * acw;
  }
  u16x4 r4; r4[0] = f2bf(w.x); r4[1] = f2bf(w.y); r4[2] = f2bf(w.z); r4[3] = f2bf(w.w);
  *reinterpret_cast<u16x4*>(dst + (size_t)nr * 1024 + e0) = r4;
}

// ---------------- GEMM v5: m201-geometry 256x256, wave=128x64 ----------------
// C[M,N] = A[M,K(lda)] * Bw[N,K]^T.  BK=64, 8 waves (2Mx4N), acc[8][4].
// LDS 128KB: As[2][256][64], Bs[2][256][64], full 3-bit XOR swizzle.
// Per K-tile t (buf d=t&1), quadrant rotation (reads {12,4,8,0} vs 16 MFMA):
//  P1: ds fa(m0-3)8 + fbA(n0-1)4; stage 2A(t+1->d^1); bar; lgkm0; 16 MFMA; bar
//  P2: ds fbB(n2-3)4;             stage 2A(t+1);      bar; lgkm0; 16 MFMA; bar
//  P3: ds fa(m4-7)8;              stage 4B(t+1);      bar; lgkm0; 16 MFMA
//      + 16 MFMA (m4-7 x n0-1, all-register reuse);   vmcnt(0); bar
// Stage overwrite windows: buf d^1 A last read P3(t-1), B last read P2(t-1),
// both >=2 barriers before the overwrites. vmcnt(0)@P3: youngest loads are
// >=1 phase old (B panels L2-resident) -> little exposed latency.
template<int OUTF32>
__global__ __launch_bounds__(512) void k_gemm256(const u16* __restrict__ Ag,
                                                 const u16* __restrict__ Bg,
                                                 void* __restrict__ C,
                                                 int K, int N, int lda, int gx) {
  __shared__ __align__(16) u16 As[2][16384];   // [2][256][64]  64KB
  __shared__ __align__(16) u16 Bs[2][16384];   // [2][256][64]  64KB
  const int tid = threadIdx.x;
  const int wid = tid >> 6, lane = tid & 63;
  const int l15 = lane & 15, lg = lane >> 4;
  const int wr = wid >> 2, wc = wid & 3;
  // bijective XCD swizzle (nwg % 8 == 0: 384 and 128)
  const int nwg = gridDim.x, cpx = nwg >> 3;
  const int bid = (int)blockIdx.x;
  const int sid = (bid & 7) * cpx + (bid >> 3);
  const int m0 = (sid % gx) * 256, n0 = (sid / gx) * 256;

  const int lrow = lane >> 3;          // row-within-8 for staging
  const int lslot = lane & 7;          // 16B slot for staging

  f32x4 acc[8][4];
#pragma unroll
  for (int i = 0; i < 8; i++)
#pragma unroll
    for (int j = 0; j < 4; j++) acc[i][j] = (f32x4)0.0f;

  // stage one 64-row round: wave wid covers rows [i*64+wid*8, +8)
  auto stA = [&](int d, int t, int i) {
    int row = i * 64 + wid * 8 + lrow;
    int sc = (lslot ^ (row & 7)) << 3;
    gload16(Ag + (size_t)(m0 + row) * lda + t * 64 + sc, &As[d][(i * 64 + wid * 8) * 64]);
  };
  auto stB = [&](int d, int t, int i) {
    int row = i * 64 + wid * 8 + lrow;
    int sc = (lslot ^ (row & 7)) << 3;
    gload16(Bg + (size_t)(n0 + row) * K + t * 64 + sc, &Bs[d][(i * 64 + wid * 8) * 64]);
  };
  auto ldsA = [&](int d, int m, int kk) {   // m in 0..7 within wave's 128-row strip
    int rr = wr * 128 + m * 16 + l15;
    return *reinterpret_cast<const bf16x8*>(&As[d][rr * 64 + (((kk * 4 + lg) ^ (rr & 7)) << 3)]);
  };
  auto ldsB = [&](int d, int n, int kk) {   // n in 0..3 within wave's 64-row strip
    int rr = wc * 64 + n * 16 + l15;
    return *reinterpret_cast<const bf16x8*>(&Bs[d][rr * 64 + (((kk * 4 + lg) ^ (rr & 7)) << 3)]);
  };

#define MIDBAR do { asm volatile("s_barrier" ::: "memory"); \
                    asm volatile("s_waitcnt lgkmcnt(0)" ::: "memory"); } while (0)
#define ENDBAR asm volatile("s_barrier" ::: "memory")

  // prologue: tile 0 fully into buf 0
  stA(0, 0, 0); stA(0, 0, 1); stA(0, 0, 2); stA(0, 0, 3);
  stB(0, 0, 0); stB(0, 0, 1); stB(0, 0, 2); stB(0, 0, 3);
  asm volatile("s_waitcnt vmcnt(0)" ::: "memory");
  asm volatile("s_barrier" ::: "memory");

  bf16x8 fa[4][2], fbA[2][2], fbB[2][2];
  const int nt = K >> 6;
  for (int t = 0; t < nt; ++t) {
    const int d = t & 1;
    const bool st = (t + 1 < nt);
    // ---- P1: fa(m0-3) + fbA(n0-1); stage A rounds 0-1 ----
#pragma unroll
    for (int m = 0; m < 4; m++)
#pragma unroll
      for (int kk = 0; kk < 2; kk++) fa[m][kk] = ldsA(d, m, kk);
#pragma unroll
    for (int n = 0; n < 2; n++)
#pragma unroll
      for (int kk = 0; kk < 2; kk++) fbA[n][kk] = ldsB(d, n, kk);
    if (st) { stA(d ^ 1, t + 1, 0); stA(d ^ 1, t + 1, 1); }
    MIDBAR;
    __builtin_amdgcn_s_setprio(1);
#pragma unroll
    for (int m = 0; m < 4; m++)
#pragma unroll
      for (int n = 0; n < 2; n++)
#pragma unroll
        for (int kk = 0; kk < 2; kk++)
          acc[m][n] = mfma16(fa[m][kk], fbA[n][kk], acc[m][n]);
    __builtin_amdgcn_s_setprio(0);
    ENDBAR;
    // ---- P2: fbB(n2-3); stage A rounds 2-3 ----
#pragma unroll
    for (int n = 0; n < 2; n++)
#pragma unroll
      for (int kk = 0; kk < 2; kk++) fbB[n][kk] = ldsB(d, n + 2, kk);
    if (st) { stA(d ^ 1, t + 1, 2); stA(d ^ 1, t + 1, 3); }
    MIDBAR;
    __builtin_amdgcn_s_setprio(1);
#pragma unroll
    for (int m = 0; m < 4; m++)
#pragma unroll
      for (int n = 0; n < 2; n++)
#pragma unroll
        for (int kk = 0; kk < 2; kk++)
          acc[m][n + 2] = mfma16(fa[m][kk], fbB[n][kk], acc[m][n + 2]);
    __builtin_amdgcn_s_setprio(0);
    ENDBAR;
    // ---- P3: fa(m4-7); stage B rounds 0-3; 32 MFMA (n2-3 then n0-1 reuse) ----
#pragma unroll
    for (int m = 0; m < 4; m++)
#pragma unroll
      for (int kk = 0; kk < 2; kk++) fa[m][kk] = ldsA(d, m + 4, kk);
    if (st) { stB(d ^ 1, t + 1, 0); stB(d ^ 1, t + 1, 1); stB(d ^ 1, t + 1, 2); stB(d ^ 1, t + 1, 3); }
    MIDBAR;
    __builtin_amdgcn_s_setprio(1);
#pragma unroll
    for (int m = 0; m < 4; m++)
#pragma unroll
      for (int n = 0; n < 2; n++)
#pragma unroll
        for (int kk = 0; kk < 2; kk++)
          acc[m + 4][n + 2] = mfma16(fa[m][kk], fbB[n][kk], acc[m + 4][n + 2]);
#pragma unroll
    for (int m = 0; m < 4; m++)
#pragma unroll
      for (int n = 0; n < 2; n++)
#pragma unroll
        for (int kk = 0; kk < 2; kk++)
          acc[m + 4][n] = mfma16(fa[m][kk], fbA[n][kk], acc[m + 4][n]);
    __builtin_amdgcn_s_setprio(0);
    asm volatile("s_waitcnt vmcnt(0)" ::: "memory");
    ENDBAR;
  }
#undef MIDBAR
#undef ENDBAR

  const int rbase = m0 + wr * 128, cbase = n0 + wc * 64;
#pragma unroll
  for (int m = 0; m < 8; m++)
#pragma unroll
    for (int n = 0; n < 4; n++)
#pragma unroll
      for (int j = 0; j < 4; j++) {
        int r  = rbase + m * 16 + lg * 4 + j;
        int cc = cbase + n * 16 + l15;
        if constexpr (OUTF32) {
          reinterpret_cast<float*>(C)[(size_t)r * N + cc] = acc[m][n][j];
        } else {
          reinterpret_cast<u16*>(C)[(size_t)r * N + cc] = f2bf(acc[m][n][j]);
        }
      }
}

// ---------------- GEMM v4 (kept for gemm2): 2-phase/K-tile, 128x256 ----------------
template<int OUTF32>
__global__ __launch_bounds__(512) void k_gemm8(const u16* __restrict__ Ag,
                                               const u16* __restrict__ Bg,
                                               void* __restrict__ C,
                                               int K, int N, int lda, int gx) {
  __shared__ __align__(16) u16 As[2][8192];    // [2][128][64]  32KB
  __shared__ __align__(16) u16 Bs[2][16384];   // [2][256][64]  64KB
  const int tid = threadIdx.x;
  const int wid = tid >> 6, lane = tid & 63;
  const int l15 = lane & 15, lg = lane >> 4;
  const int wr = wid >> 2, wc = wid & 3;
  const int nwg = gridDim.x, cpx = nwg >> 3;
  const int bid = (int)blockIdx.x;
  const int sid = (bid & 7) * cpx + (bid >> 3);
  const int m0 = (sid % gx) * 128, n0 = (sid / gx) * 256;

  const int lrow = lane >> 3;
  const int lslot = lane & 7;

  f32x4 acc[4][4];
#pragma unroll
  for (int i = 0; i < 4; i++)
#pragma unroll
    for (int j = 0; j < 4; j++) acc[i][j] = (f32x4)0.0f;

  auto stageA = [&](int d, int t) {
#pragma unroll
    for (int i = 0; i < 2; i++) {
      int row = i * 64 + wid * 8 + lrow;
      int sc = (lslot ^ (row & 7)) << 3;
      gload16(Ag + (size_t)(m0 + row) * lda + t * 64 + sc,
              &As[d][(i * 64 + wid * 8) * 64]);
    }
  };
  auto stageB = [&](int d, int t) {
#pragma unroll
    for (int i = 0; i < 4; i++) {
      int row = i * 64 + wid * 8 + lrow;
      int sc = (lslot ^ (row & 7)) << 3;
      gload16(Bg + (size_t)(n0 + row) * K + t * 64 + sc,
              &Bs[d][(i * 64 + wid * 8) * 64]);
    }
  };
  auto ldsA = [&](int d, int m, int kk) {
    int rr = wr * 64 + m * 16 + l15;
    return *reinterpret_cast<const bf16x8*>(&As[d][rr * 64 + (((kk * 4 + lg) ^ (rr & 7)) << 3)]);
  };
  auto ldsB = [&](int d, int n, int kk) {
    int rr = wc * 64 + n * 16 + l15;
    return *reinterpret_cast<const bf16x8*>(&Bs[d][rr * 64 + (((kk * 4 + lg) ^ (rr & 7)) << 3)]);
  };

#define MIDBAR do { asm volatile("s_barrier" ::: "memory"); \
                    asm volatile("s_waitcnt lgkmcnt(0)" ::: "memory"); } while (0)
#define ENDBAR asm volatile("s_barrier" ::: "memory")

  stageB(0, 0); stageA(0, 0); stageA(1, 1);
  asm volatile("s_waitcnt vmcnt(2)" ::: "memory");
  asm volatile("s_barrier" ::: "memory");

  bf16x8 fa[4][2], fb[2][2];
  const int nt = K >> 6;
  for (int t = 0; t < nt; ++t) {
    const int d = t & 1;
#pragma unroll
    for (int m = 0; m < 4; m++)
#pragma unroll
      for (int kk = 0; kk < 2; kk++) fa[m][kk] = ldsA(d, m, kk);
#pragma unroll
    for (int n = 0; n < 2; n++)
#pragma unroll
      for (int kk = 0; kk < 2; kk++) fb[n][kk] = ldsB(d, n, kk);
    if (t + 1 < nt) stageB(d ^ 1, t + 1);
    MIDBAR;
    __builtin_amdgcn_s_setprio(1);
#pragma unroll
    for (int m = 0; m < 4; m++)
#pragma unroll
      for (int n = 0; n < 2; n++)
#pragma unroll
        for (int kk = 0; kk < 2; kk++)
          acc[m][n] = mfma16(fa[m][kk], fb[n][kk], acc[m][n]);
    __builtin_amdgcn_s_setprio(0);
    ENDBAR;
#pragma unroll
    for (int n = 0; n < 2; n++)
#pragma unroll
      for (int kk = 0; kk < 2; kk++) fb[n][kk] = ldsB(d, n + 2, kk);
    if (t + 2 < nt) stageA(d, t + 2);
    MIDBAR;
    __builtin_amdgcn_s_setprio(1);
#pragma unroll
    for (int m = 0; m < 4; m++)
#pragma unroll
      for (int n = 0; n < 2; n++)
#pragma unroll
        for (int kk = 0; kk < 2; kk++)
          acc[m][n + 2] = mfma16(fa[m][kk], fb[n][kk], acc[m][n + 2]);
    __builtin_amdgcn_s_setprio(0);
    if (t + 2 < nt) asm volatile("s_waitcnt vmcnt(2)" ::: "memory");
    else            asm volatile("s_waitcnt vmcnt(0)" ::: "memory");
    ENDBAR;
  }
#undef MIDBAR
#undef ENDBAR

  const int rbase = m0 + wr * 64, cbase = n0 + wc * 64;
#pragma unroll
  for (int m = 0; m < 4; m++)
#pragma unroll
    for (int n = 0; n < 4; n++)
#pragma unroll
      for (int j = 0; j < 4; j++) {
        int r  = rbase + m * 16 + lg * 4 + j;
        int cc = cbase + n * 16 + l15;
        if constexpr (OUTF32) {
          reinterpret_cast<float*>(C)[(size_t)r * N + cc] = acc[m][n][j];
        } else {
          reinterpret_cast<u16*>(C)[(size_t)r * N + cc] = f2bf(acc[m][n][j]);
        }
      }
}

// ---------------- V transpose: qkv V-section -> vt[b][h][d][t] ----------------
__global__ __launch_bounds__(256) void k_vt(const u16* __restrict__ qkv,
                                            u16* __restrict__ vt) {
  __shared__ __align__(16) u16 tile[64 * 64];
  const int tb = blockIdx.x, h = blockIdx.y, b = blockIdx.z;
  const int tid = threadIdx.x;
  const size_t rb = (size_t)b * 2048;
  const int hv = 2048 + h * 64;
#pragma unroll
  for (int p = 0; p < 2; p++) {
    int r = p * 32 + (tid >> 3);
    int c = (tid & 7) * 8;
    u16x8 v = *reinterpret_cast<const u16x8*>(qkv + (rb + tb * 64 + r) * 3072 + hv + c);
    int slot = (c >> 3) ^ (r & 7) ^ ((r >> 3) & 7);
    *reinterpret_cast<u16x8*>(tile + r * 64 + slot * 8) = v;
  }
  __syncthreads();
#pragma unroll
  for (int p = 0; p < 2; p++) {
    int d = p * 32 + (tid >> 3);
    int t0 = (tid & 7) * 8;
    u16x8 v;
#pragma unroll
    for (int j = 0; j < 8; j++) {
      int r = t0 + j;
      int slot = (d >> 3) ^ (r & 7) ^ ((r >> 3) & 7);
      v[j] = tile[r * 64 + slot * 8 + (d & 7)];
    }
    *reinterpret_cast<u16x8*>(vt + ((size_t)(b * 16 + h) * 64 + d) * 2048 + tb * 64 + t0) = v;
  }
}

// ---------------- flash attention v7: mask-split + max3 ----------------
__global__ __launch_bounds__(256) void k_attn(const u16* __restrict__ qkv,
                                              const u16* __restrict__ vt,
                                              u16* __restrict__ aout) {
  __shared__ __align__(16) u16 Kl[2][64 * 64];   // [key][d], swizzled 16B slots
  __shared__ __align__(16) u16 Vl[2][64 * 64];   // [d][key], same swizzle
  const int tid = threadIdx.x, wave = tid >> 6, lane = tid & 63;
  const int l31 = lane & 31, half = lane >> 5;
  const int i = (int)blockIdx.x;
  const int b = i & 3, p = i >> 2;
  const int k4 = p >> 6, j4 = p & 63;
  const int ridx = (k4 == 0) ? j4 : (k4 == 1) ? 127 - j4 : (k4 == 2) ? 128 + j4 : 255 - j4;
  const int hqv = RANKTBL[ridx];
  const int h = hqv >> 4, qb = hqv & 15;
  const int rb = b * 2048;
  const int hq = h * 64, hk = 1024 + h * 64;
  const int bh64 = (b * 16 + h) * 64;
  const int qB = qb * 128;
  const int q0w = qB + wave * 32;
  const int q = q0w + l31;

  bf16x8 qf[4];
#pragma unroll
  for (int c = 0; c < 4; c++)
    qf[c] = *reinterpret_cast<const bf16x8*>(qkv + (size_t)(rb + q) * 3072 + hq + c * 16 + half * 8);

  const float slope2 = exp2f(-0.5f * (float)(h + 1)) * 1.44269504f;
  const float c0 = 0.18033688f;

  const int kend = min(2 * qb + 1, KBW[h]);

  float mrun = -1e30f, lrun = 0.f;
  f32x16 o0 = (f32x16)0.0f, o1 = (f32x16)0.0f;

  auto stage = [&](int kvr, int dst) {
#pragma unroll
    for (int i2 = 0; i2 < 2; i2++) {
      int row = (i2 * 4 + wave) * 8 + (lane >> 3);
      int scol = ((lane & 7) ^ (row & 7)) << 3;
      gload16(qkv + (size_t)(rb + kvr + row) * 3072 + hk + scol, &Kl[dst][(i2 * 4 + wave) * 512]);
      gload16(vt + (size_t)(bh64 + row) * 2048 + kvr + scol,     &Vl[dst][(i2 * 4 + wave) * 512]);
    }
  };

  stage(0, 0);
  __syncthreads();

  int bfi = 0;
  for (int kb = 0; kb <= kend; ++kb, bfi ^= 1) {
    const int kvr = kb * 64;
    if (kb < kend) stage(kvr + 64, bfi ^ 1);

    if (kvr <= q0w + 31) {
      f32x16 s[2];
#pragma unroll
      for (int t = 0; t < 2; t++) s[t] = (f32x16)0.0f;
      __builtin_amdgcn_s_setprio(1);
#pragma unroll
      for (int t = 0; t < 2; t++) {
        int r = t * 32 + l31;
#pragma unroll
        for (int cc = 0; cc < 4; cc++) {
          bf16x8 kf = *reinterpret_cast<const bf16x8*>(
              &Kl[bfi][r * 64 + (((cc * 2 + half) ^ (r & 7)) << 3)]);
          s[t] = mfma32(kf, qf[cc], s[t]);
        }
      }
      __builtin_amdgcn_s_setprio(0);

      const bool domask = (kvr + 63 > q0w);   // wave-uniform
      const int qrel = q - kvr - half * 4;
      const float qb0 = slope2 * (float)qrel;
      const float qb1 = qb0 - slope2 * 32.0f;
      float mt = -1e30f;
      if (domask) {
#pragma unroll
        for (int t = 0; t < 2; t++) {
          const float qbt = t ? qb1 : qb0;
          const int qmt = t ? (qrel - 32) : qrel;
#pragma unroll
          for (int r = 0; r < 16; r++) {
            const int krel = (r & 3) + 8 * (r >> 2);
            float val = fmaf(s[t][r], c0, fmaf(-slope2, (float)krel, qbt));
            val = (krel <= qmt) ? val : -3.0e38f;
            s[t][r] = val;
            mt = fmaxf(mt, val);
          }
        }
      } else {
#pragma unroll
        for (int t = 0; t < 2; t++) {
          const float qbt = t ? qb1 : qb0;
#pragma unroll
          for (int r = 0; r < 16; r += 2) {
            const int k0 = (r & 3) + 8 * (r >> 2);
            const int k1 = ((r + 1) & 3) + 8 * ((r + 1) >> 2);
            float v0 = fmaf(s[t][r],     c0, fmaf(-slope2, (float)k0, qbt));
            float v1 = fmaf(s[t][r + 1], c0, fmaf(-slope2, (float)k1, qbt));
            s[t][r] = v0; s[t][r + 1] = v1;
            mt = fmaxf(mt, fmaxf(v0, v1));   // max3-fusable
          }
        }
      }
      mt = fmaxf(mt, __shfl_xor(mt, 32));

      if (__any(mt - mrun > 8.0f)) {
        float mn = fmaxf(mrun, mt);
        float al = exp2f(mrun - mn);
        mrun = mn; lrun *= al;
#pragma unroll
        for (int r = 0; r < 16; r++) { o0[r] *= al; o1[r] *= al; }
      }

      float rs0 = 0.f, rs1 = 0.f;
#pragma unroll
      for (int t = 0; t < 2; t++)
#pragma unroll
        for (int r = 0; r < 16; r++) {
          float pp = exp2f(s[t][r] - mrun);
          s[t][r] = pp;
          if (t) rs1 += pp; else rs0 += pp;
        }
      float rs = rs0 + rs1;
      rs += __shfl_xor(rs, 32);
      lrun += rs;

      bf16x8 pf[4];
#pragma unroll
      for (int t = 0; t < 2; t++)
#pragma unroll
        for (int hs = 0; hs < 2; hs++) {
          u32 A0 = packbf(s[t][8 * hs + 0], s[t][8 * hs + 1]);
          u32 B0 = packbf(s[t][8 * hs + 2], s[t][8 * hs + 3]);
          u32 C0 = packbf(s[t][8 * hs + 4], s[t][8 * hs + 5]);
          u32 D0 = packbf(s[t][8 * hs + 6], s[t][8 * hs + 7]);
          asm volatile("v_permlane32_swap_b32 %0, %1" : "+v"(A0), "+v"(C0));
          asm volatile("v_permlane32_swap_b32 %0, %1" : "+v"(B0), "+v"(D0));
          u32x4 fr; fr[0] = A0; fr[1] = B0; fr[2] = C0; fr[3] = D0;
          pf[t * 2 + hs] = __builtin_bit_cast(bf16x8, fr);
        }

      __builtin_amdgcn_s_setprio(1);
#pragma unroll
      for (int dblk = 0; dblk < 2; dblk++) {
        int r = dblk * 32 + l31;
#pragma unroll
        for (int kc = 0; kc < 4; kc++) {
          bf16x8 vf = *reinterpret_cast<const bf16x8*>(
              &Vl[bfi][r * 64 + (((kc * 2 + half) ^ (r & 7)) << 3)]);
          if (dblk) o1 = mfma32(vf, pf[kc], o1);
          else      o0 = mfma32(vf, pf[kc], o0);
        }
      }
      __builtin_amdgcn_s_setprio(0);
    }
    __syncthreads();
  }

  const float linv = 1.0f / lrun;
#pragma unroll
  for (int dblk = 0; dblk < 2; dblk++)
#pragma unroll
    for (int rg = 0; rg < 4; rg++) {
      int d0 = dblk * 32 + 8 * rg + 4 * half;
      u16x4 r4;
#pragma unroll
      for (int j = 0; j < 4; j++) {
        float v = (dblk ? o1[rg * 4 + j] : o0[rg * 4 + j]) * linv;
        r4[j] = f2bf(v);
      }
      *reinterpret_cast<u16x4*>(aout + (size_t)(rb + q) * 3072 + hq + d0) = r4;
    }
}

extern "C" void kernel_launch(void* const* d_in, const int* in_sizes, int n_in,
                              void* d_out, int out_size, void* d_ws, size_t ws_size,
                              hipStream_t stream) {
  (void)in_sizes; (void)n_in; (void)out_size; (void)ws_size;
  const float* x  = (const float*)d_in[0];
  const float* Wq = (const float*)d_in[1];
  const float* Aq = (const float*)d_in[2];
  const float* Bq = (const float*)d_in[3];
  const float* Wk = (const float*)d_in[4];
  const float* Ak = (const float*)d_in[5];
  const float* Bk = (const float*)d_in[6];
  const float* Wv = (const float*)d_in[7];
  const float* Av = (const float*)d_in[8];
  const float* Bv = (const float*)d_in[9];
  const float* Wp = (const float*)d_in[10];

  char* ws = (char*)d_ws;
  u16* xb   = (u16*)(ws);                  // [8192][1024] bf16 (dead after gemm1)
  u16* wqkv = (u16*)(ws + 16777216);       // [3072][1024] bf16
  u16* wp   = (u16*)(ws + 23068672);       // [1024][1024] bf16
  u16* qkv  = (u16*)(ws + 25165824);       // [8192][3072] bf16
  u16* vt   = xb;                          // [4][16][64][2048] bf16, reuses xb
  float* out = (float*)d_out;

  k_cast_x<<<dim3(4096), dim3(256), 0, stream>>>(x, xb);
  k_fold_w<<<dim3(4096), dim3(256), 0, stream>>>(Wq, Aq, Bq, Wk, Ak, Bk, Wv, Av, Bv, Wp, wqkv, wp);
  // QKV GEMM: M=8192 N=3072 K=1024 -> grid 32x12 = 384 blocks (256^2 tile)
  k_gemm256<0><<<dim3(384), dim3(512), 0, stream>>>(xb, wqkv, (void*)qkv, 1024, 3072, 1024, 32);
  k_vt<<<dim3(32, 16, 4), dim3(256), 0, stream>>>(qkv, vt);
  // attention writes its output into qkv's Q-columns (in-place, stride 3072)
  k_attn<<<dim3(1024), dim3(256), 0, stream>>>(qkv, vt, qkv);
  // output GEMM: M=8192 N=1024 K=1024 -> grid 64x4 = 256 blocks (1/CU exact)
  k_gemm8<1><<<dim3(256), dim3(512), 0, stream>>>(qkv, wp, (void*)out, 1024, 1024, 3072, 64);
}

// Round 14
// 178.519 us; speedup vs baseline: 1.7210x; 1.0122x over previous
//
#include <hip/hip_runtime.h>

typedef unsigned short u16;
typedef unsigned int u32;
typedef u16  u16x8 __attribute__((ext_vector_type(8)));
typedef u16  u16x4 __attribute__((ext_vector_type(4)));
typedef u32  u32x4 __attribute__((ext_vector_type(4)));
typedef __bf16 bf16x2 __attribute__((ext_vector_type(2)));
typedef __bf16 bf16x8 __attribute__((ext_vector_type(8)));
typedef float f32x4 __attribute__((ext_vector_type(4)));
typedef float f32x16 __attribute__((ext_vector_type(16)));

// ALiBi prefix window (keys with slope_nat*j > 40 negligible): kb_w per head.
__constant__ int KBW[16]  = {0,1,1,2,3,5,7,10,14,20,28,40,56,80,113,160};

// (h,qb) pairs (byte = h*16+qb) sorted by tile count DESCENDING (LPT schedule).
__constant__ unsigned char RANKTBL[256] = {
  0xBF,0xCF,0xDF,0xEF,0xFF,
  0xBE,0xCE,0xDE,0xEE,0xFE,
  0xAE,0xAF,
  0xAD,0xBD,0xCD,0xDD,0xED,0xFD,
  0xAC,0xBC,0xCC,0xDC,0xEC,0xFC,
  0xAB,0xBB,0xCB,0xDB,0xEB,0xFB,
  0xAA,0xBA,0xCA,0xDA,0xEA,0xFA,
  0x9A,0x9B,0x9C,0x9D,0x9E,0x9F,
  0x99,0xA9,0xB9,0xC9,0xD9,0xE9,0xF9,
  0x98,0xA8,0xB8,0xC8,0xD8,0xE8,0xF8,
  0x97,0xA7,0xB7,0xC7,0xD7,0xE7,0xF7,
  0x87,0x88,0x89,0x8A,0x8B,0x8C,0x8D,0x8E,0x8F,
  0x86,0x96,0xA6,0xB6,0xC6,0xD6,0xE6,0xF6,
  0x85,0x95,0xA5,0xB5,0xC5,0xD5,0xE5,0xF5,
  0x75,0x76,0x77,0x78,0x79,0x7A,0x7B,0x7C,0x7D,0x7E,0x7F,
  0x74,0x84,0x94,0xA4,0xB4,0xC4,0xD4,0xE4,0xF4,
  0x63,0x64,0x65,0x66,0x67,0x68,0x69,0x6A,0x6B,0x6C,0x6D,0x6E,0x6F,
  0x73,0x83,0x93,0xA3,0xB3,0xC3,0xD3,0xE3,0xF3,
  0x52,0x53,0x54,0x55,0x56,0x57,0x58,0x59,0x5A,0x5B,0x5C,0x5D,0x5E,0x5F,
  0x62,0x72,0x82,0x92,0xA2,0xB2,0xC2,0xD2,0xE2,0xF2,
  0x41,0x42,0x43,0x44,0x45,0x46,0x47,0x48,0x49,0x4A,0x4B,0x4C,0x4D,0x4E,0x4F,
  0x51,0x61,0x71,0x81,0x91,0xA1,0xB1,0xC1,0xD1,0xE1,0xF1,
  0x31,0x32,0x33,0x34,0x35,0x36,0x37,0x38,0x39,0x3A,0x3B,0x3C,0x3D,0x3E,0x3F,
  0x10,0x11,0x12,0x13,0x14,0x15,0x16,0x17,0x18,0x19,0x1A,0x1B,0x1C,0x1D,0x1E,0x1F,
  0x20,0x21,0x22,0x23,0x24,0x25,0x26,0x27,0x28,0x29,0x2A,0x2B,0x2C,0x2D,0x2E,0x2F,
  0x30,0x40,0x50,0x60,0x70,0x80,0x90,0xA0,0xB0,0xC0,0xD0,0xE0,0xF0,
  0x00,0x01,0x02,0x03,0x04,0x05,0x06,0x07,0x08,0x09,0x0A,0x0B,0x0C,0x0D,0x0E,0x0F
};

// fp32 -> bf16 round-to-nearest-even
static __device__ __forceinline__ u16 f2bf(float f) {
  unsigned int u = __float_as_uint(f);
  u += 0x7FFFu + ((u >> 16) & 1u);
  return (u16)(u >> 16);
}

static __device__ __forceinline__ u32 packbf(float a, float b) {
  bf16x2 t;
  t[0] = (__bf16)a;
  t[1] = (__bf16)b;
  return __builtin_bit_cast(u32, t);
}

static __device__ __forceinline__ f32x4 mfma16(bf16x8 a, bf16x8 b, f32x4 c) {
  return __builtin_amdgcn_mfma_f32_16x16x32_bf16(a, b, c, 0, 0, 0);
}
static __device__ __forceinline__ f32x16 mfma32(bf16x8 a, bf16x8 b, f32x16 c) {
  return __builtin_amdgcn_mfma_f32_32x32x16_bf16(a, b, c, 0, 0, 0);
}

static __device__ __forceinline__ void gload16(const void* g, void* lds) {
  __builtin_amdgcn_global_load_lds(
      (const __attribute__((address_space(1))) unsigned int*)g,
      (__attribute__((address_space(3))) unsigned int*)lds, 16, 0, 0);
}

// ---------------- fused: cast x (fp32->bf16) + LoRA weight fold ----------------
// blocks [0,4096): cast 8 elems/thread; blocks [4096,8192): fold one weight row.
__global__ __launch_bounds__(256) void k_castfold(
    const float* __restrict__ x, u16* __restrict__ xb,
    const float* __restrict__ Wq, const float* __restrict__ Aq, const float* __restrict__ Bq,
    const float* __restrict__ Wk, const float* __restrict__ Ak, const float* __restrict__ Bk,
    const float* __restrict__ Wv, const float* __restrict__ Av, const float* __restrict__ Bv,
    const float* __restrict__ Wp, u16* __restrict__ wqkv, u16* __restrict__ wp) {
  const int bid = (int)blockIdx.x;
  if (bid < 4096) {
    size_t i = (size_t)bid * 256 + threadIdx.x;
    const float4* p = reinterpret_cast<const float4*>(x) + i * 2;
    float4 a = p[0], b = p[1];
    u16x8 r;
    r[0] = f2bf(a.x); r[1] = f2bf(a.y); r[2] = f2bf(a.z); r[3] = f2bf(a.w);
    r[4] = f2bf(b.x); r[5] = f2bf(b.y); r[6] = f2bf(b.z); r[7] = f2bf(b.w);
    *reinterpret_cast<u16x8*>(xb + i * 8) = r;
    return;
  }
  int n = bid - 4096;
  int widx = n >> 10, nr = n & 1023;
  const float *W, *A, *Bm; u16* dst;
  if (widx == 0)      { W = Wq; A = Aq; Bm = Bq; dst = wqkv; }
  else if (widx == 1) { W = Wk; A = Ak; Bm = Bk; dst = wqkv + (1 << 20); }
  else if (widx == 2) { W = Wv; A = Av; Bm = Bv; dst = wqkv + (2 << 20); }
  else                { W = Wp; A = nullptr; Bm = nullptr; dst = wp; }
  int e0 = threadIdx.x * 4;
  float4 w = *reinterpret_cast<const float4*>(W + (size_t)nr * 1024 + e0);
  if (widx < 3) {
    float acx = 0.f, acy = 0.f, acz = 0.f, acw = 0.f;
#pragma unroll
    for (int r = 0; r < 8; r++) {
      float ar = A[nr * 8 + r];
      float4 bm = *reinterpret_cast<const float4*>(Bm + (size_t)r * 1024 + e0);
      acx += ar * bm.x; acy += ar * bm.y; acz += ar * bm.z; acw += ar * bm.w;
    }
    w.x += 2.0f * acx; w.y += 2.0f * acy; w.z += 2.0f * acz; w.w += 2.0f * acw;
  }
  u16x4 r4; r4[0] = f2bf(w.x); r4[1] = f2bf(w.y); r4[2] = f2bf(w.z); r4[3] = f2bf(w.w);
  *reinterpret_cast<u16x4*>(dst + (size_t)nr * 1024 + e0) = r4;
}

// ---------------- GEMM v6: 256x256, depth-2 counted-vmcnt (never drain) ----------------
// C[M,N] = A[M,K(lda)] * Bw[N,K]^T.  BK=64, 8 waves (2Mx4N), wave=128x64, acc[8][4].
// LDS 128KB: As[2][256][64], Bs[2][256][64], full 3-bit XOR swizzle (conflict-free).
// Depth-2 schedule (tile t in buf d=t&1):
//  P1(t): ds fa(m0-3)+fbA(n0-1); stage 2A(t+1->d^1); BAR; lgkm0; 16 MFMA; BAR
//  P2(t): ds fbB(n2-3);          stage 2A(t+1->d^1); BAR; lgkm0; 16 MFMA; BAR
//  P3(t): ds fa(m4-7);           stage 4B(t+2->d);   BAR; lgkm0; 32 MFMA;
//         vmcnt(4) [retires exactly A(t+1)+B(t+1), keeps B(t+2) in flight]; BAR
// Overwrite windows: A(t-1)@d^1 dead since P3(t-1) ENDBAR; B(t)@d dead at P2(t)
// ENDBAR (reads completed before each wave's MIDBAR-lgkm0). No mid-loop vmcnt(0).
template<int OUTF32>
__global__ __launch_bounds__(512) void k_gemm256(const u16* __restrict__ Ag,
                                                 const u16* __restrict__ Bg,
                                                 void* __restrict__ C,
                                                 int K, int N, int lda, int gx) {
  __shared__ __align__(16) u16 As[2][16384];   // [2][256][64]  64KB
  __shared__ __align__(16) u16 Bs[2][16384];   // [2][256][64]  64KB
  const int tid = threadIdx.x;
  const int wid = tid >> 6, lane = tid & 63;
  const int l15 = lane & 15, lg = lane >> 4;
  const int wr = wid >> 2, wc = wid & 3;
  // bijective XCD swizzle (nwg % 8 == 0)
  const int nwg = gridDim.x, cpx = nwg >> 3;
  const int bid = (int)blockIdx.x;
  const int sid = (bid & 7) * cpx + (bid >> 3);
  const int m0 = (sid % gx) * 256, n0 = (sid / gx) * 256;

  const int lrow = lane >> 3;          // row-within-8 for staging
  const int lslot = lane & 7;          // 16B slot for staging

  f32x4 acc[8][4];
#pragma unroll
  for (int i = 0; i < 8; i++)
#pragma unroll
    for (int j = 0; j < 4; j++) acc[i][j] = (f32x4)0.0f;

  auto stA = [&](int d, int t, int i) {
    int row = i * 64 + wid * 8 + lrow;
    int sc = (lslot ^ (row & 7)) << 3;
    gload16(Ag + (size_t)(m0 + row) * lda + t * 64 + sc, &As[d][(i * 64 + wid * 8) * 64]);
  };
  auto stB = [&](int d, int t, int i) {
    int row = i * 64 + wid * 8 + lrow;
    int sc = (lslot ^ (row & 7)) << 3;
    gload16(Bg + (size_t)(n0 + row) * K + t * 64 + sc, &Bs[d][(i * 64 + wid * 8) * 64]);
  };
  auto ldsA = [&](int d, int m, int kk) {
    int rr = wr * 128 + m * 16 + l15;
    return *reinterpret_cast<const bf16x8*>(&As[d][rr * 64 + (((kk * 4 + lg) ^ (rr & 7)) << 3)]);
  };
  auto ldsB = [&](int d, int n, int kk) {
    int rr = wc * 64 + n * 16 + l15;
    return *reinterpret_cast<const bf16x8*>(&Bs[d][rr * 64 + (((kk * 4 + lg) ^ (rr & 7)) << 3)]);
  };

#define MIDBAR do { asm volatile("s_barrier" ::: "memory"); \
                    asm volatile("s_waitcnt lgkmcnt(0)" ::: "memory"); } while (0)
#define ENDBAR asm volatile("s_barrier" ::: "memory")

  const int nt = K >> 6;
  // prologue: A(0),B(0)->buf0, B(1)->buf1; wait A0+B0 (keep B1 in flight)
  stA(0, 0, 0); stA(0, 0, 1); stA(0, 0, 2); stA(0, 0, 3);
  stB(0, 0, 0); stB(0, 0, 1); stB(0, 0, 2); stB(0, 0, 3);
  if (nt > 1) { stB(1, 1, 0); stB(1, 1, 1); stB(1, 1, 2); stB(1, 1, 3); }
  asm volatile("s_waitcnt vmcnt(4)" ::: "memory");
  asm volatile("s_barrier" ::: "memory");

  bf16x8 fa[4][2], fbA[2][2], fbB[2][2];
  for (int t = 0; t < nt; ++t) {
    const int d = t & 1;
    const bool s1 = (t + 1 < nt), s2 = (t + 2 < nt);
    // ---- P1: fa(m0-3) + fbA(n0-1); stage A(t+1) rounds 0-1 ----
#pragma unroll
    for (int m = 0; m < 4; m++)
#pragma unroll
      for (int kk = 0; kk < 2; kk++) fa[m][kk] = ldsA(d, m, kk);
#pragma unroll
    for (int n = 0; n < 2; n++)
#pragma unroll
      for (int kk = 0; kk < 2; kk++) fbA[n][kk] = ldsB(d, n, kk);
    if (s1) { stA(d ^ 1, t + 1, 0); stA(d ^ 1, t + 1, 1); }
    MIDBAR;
    __builtin_amdgcn_s_setprio(1);
#pragma unroll
    for (int m = 0; m < 4; m++)
#pragma unroll
      for (int n = 0; n < 2; n++)
#pragma unroll
        for (int kk = 0; kk < 2; kk++)
          acc[m][n] = mfma16(fa[m][kk], fbA[n][kk], acc[m][n]);
    __builtin_amdgcn_s_setprio(0);
    ENDBAR;
    // ---- P2: fbB(n2-3); stage A(t+1) rounds 2-3 ----
#pragma unroll
    for (int n = 0; n < 2; n++)
#pragma unroll
      for (int kk = 0; kk < 2; kk++) fbB[n][kk] = ldsB(d, n + 2, kk);
    if (s1) { stA(d ^ 1, t + 1, 2); stA(d ^ 1, t + 1, 3); }
    MIDBAR;
    __builtin_amdgcn_s_setprio(1);
#pragma unroll
    for (int m = 0; m < 4; m++)
#pragma unroll
      for (int n = 0; n < 2; n++)
#pragma unroll
        for (int kk = 0; kk < 2; kk++)
          acc[m][n + 2] = mfma16(fa[m][kk], fbB[n][kk], acc[m][n + 2]);
    __builtin_amdgcn_s_setprio(0);
    ENDBAR;
    // ---- P3: fa(m4-7); stage B(t+2) into buf d (B(t) dead since P2 ENDBAR) ----
#pragma unroll
    for (int m = 0; m < 4; m++)
#pragma unroll
      for (int kk = 0; kk < 2; kk++) fa[m][kk] = ldsA(d, m + 4, kk);
    if (s2) { stB(d, t + 2, 0); stB(d, t + 2, 1); stB(d, t + 2, 2); stB(d, t + 2, 3); }
    MIDBAR;
    __builtin_amdgcn_s_setprio(1);
#pragma unroll
    for (int m = 0; m < 4; m++)
#pragma unroll
      for (int n = 0; n < 2; n++)
#pragma unroll
        for (int kk = 0; kk < 2; kk++)
          acc[m + 4][n + 2] = mfma16(fa[m][kk], fbB[n][kk], acc[m + 4][n + 2]);
#pragma unroll
    for (int m = 0; m < 4; m++)
#pragma unroll
      for (int n = 0; n < 2; n++)
#pragma unroll
        for (int kk = 0; kk < 2; kk++)
          acc[m + 4][n] = mfma16(fa[m][kk], fbA[n][kk], acc[m + 4][n]);
    __builtin_amdgcn_s_setprio(0);
    if (s2) asm volatile("s_waitcnt vmcnt(4)" ::: "memory");
    else    asm volatile("s_waitcnt vmcnt(0)" ::: "memory");
    ENDBAR;
  }
#undef MIDBAR
#undef ENDBAR

  const int rbase = m0 + wr * 128, cbase = n0 + wc * 64;
#pragma unroll
  for (int m = 0; m < 8; m++)
#pragma unroll
    for (int n = 0; n < 4; n++)
#pragma unroll
      for (int j = 0; j < 4; j++) {
        int r  = rbase + m * 16 + lg * 4 + j;
        int cc = cbase + n * 16 + l15;
        if constexpr (OUTF32) {
          reinterpret_cast<float*>(C)[(size_t)r * N + cc] = acc[m][n][j];
        } else {
          reinterpret_cast<u16*>(C)[(size_t)r * N + cc] = f2bf(acc[m][n][j]);
        }
      }
}

// ---------------- GEMM v4 (kept for gemm2): 2-phase/K-tile, 128x256 ----------------
template<int OUTF32>
__global__ __launch_bounds__(512) void k_gemm8(const u16* __restrict__ Ag,
                                               const u16* __restrict__ Bg,
                                               void* __restrict__ C,
                                               int K, int N, int lda, int gx) {
  __shared__ __align__(16) u16 As[2][8192];    // [2][128][64]  32KB
  __shared__ __align__(16) u16 Bs[2][16384];   // [2][256][64]  64KB
  const int tid = threadIdx.x;
  const int wid = tid >> 6, lane = tid & 63;
  const int l15 = lane & 15, lg = lane >> 4;
  const int wr = wid >> 2, wc = wid & 3;
  const int nwg = gridDim.x, cpx = nwg >> 3;
  const int bid = (int)blockIdx.x;
  const int sid = (bid & 7) * cpx + (bid >> 3);
  const int m0 = (sid % gx) * 128, n0 = (sid / gx) * 256;

  const int lrow = lane >> 3;
  const int lslot = lane & 7;

  f32x4 acc[4][4];
#pragma unroll
  for (int i = 0; i < 4; i++)
#pragma unroll
    for (int j = 0; j < 4; j++) acc[i][j] = (f32x4)0.0f;

  auto stageA = [&](int d, int t) {
#pragma unroll
    for (int i = 0; i < 2; i++) {
      int row = i * 64 + wid * 8 + lrow;
      int sc = (lslot ^ (row & 7)) << 3;
      gload16(Ag + (size_t)(m0 + row) * lda + t * 64 + sc,
              &As[d][(i * 64 + wid * 8) * 64]);
    }
  };
  auto stageB = [&](int d, int t) {
#pragma unroll
    for (int i = 0; i < 4; i++) {
      int row = i * 64 + wid * 8 + lrow;
      int sc = (lslot ^ (row & 7)) << 3;
      gload16(Bg + (size_t)(n0 + row) * K + t * 64 + sc,
              &Bs[d][(i * 64 + wid * 8) * 64]);
    }
  };
  auto ldsA = [&](int d, int m, int kk) {
    int rr = wr * 64 + m * 16 + l15;
    return *reinterpret_cast<const bf16x8*>(&As[d][rr * 64 + (((kk * 4 + lg) ^ (rr & 7)) << 3)]);
  };
  auto ldsB = [&](int d, int n, int kk) {
    int rr = wc * 64 + n * 16 + l15;
    return *reinterpret_cast<const bf16x8*>(&Bs[d][rr * 64 + (((kk * 4 + lg) ^ (rr & 7)) << 3)]);
  };

#define MIDBAR do { asm volatile("s_barrier" ::: "memory"); \
                    asm volatile("s_waitcnt lgkmcnt(0)" ::: "memory"); } while (0)
#define ENDBAR asm volatile("s_barrier" ::: "memory")

  stageB(0, 0); stageA(0, 0); stageA(1, 1);
  asm volatile("s_waitcnt vmcnt(2)" ::: "memory");
  asm volatile("s_barrier" ::: "memory");

  bf16x8 fa[4][2], fb[2][2];
  const int nt = K >> 6;
  for (int t = 0; t < nt; ++t) {
    const int d = t & 1;
#pragma unroll
    for (int m = 0; m < 4; m++)
#pragma unroll
      for (int kk = 0; kk < 2; kk++) fa[m][kk] = ldsA(d, m, kk);
#pragma unroll
    for (int n = 0; n < 2; n++)
#pragma unroll
      for (int kk = 0; kk < 2; kk++) fb[n][kk] = ldsB(d, n, kk);
    if (t + 1 < nt) stageB(d ^ 1, t + 1);
    MIDBAR;
    __builtin_amdgcn_s_setprio(1);
#pragma unroll
    for (int m = 0; m < 4; m++)
#pragma unroll
      for (int n = 0; n < 2; n++)
#pragma unroll
        for (int kk = 0; kk < 2; kk++)
          acc[m][n] = mfma16(fa[m][kk], fb[n][kk], acc[m][n]);
    __builtin_amdgcn_s_setprio(0);
    ENDBAR;
#pragma unroll
    for (int n = 0; n < 2; n++)
#pragma unroll
      for (int kk = 0; kk < 2; kk++) fb[n][kk] = ldsB(d, n + 2, kk);
    if (t + 2 < nt) stageA(d, t + 2);
    MIDBAR;
    __builtin_amdgcn_s_setprio(1);
#pragma unroll
    for (int m = 0; m < 4; m++)
#pragma unroll
      for (int n = 0; n < 2; n++)
#pragma unroll
        for (int kk = 0; kk < 2; kk++)
          acc[m][n + 2] = mfma16(fa[m][kk], fb[n][kk], acc[m][n + 2]);
    __builtin_amdgcn_s_setprio(0);
    if (t + 2 < nt) asm volatile("s_waitcnt vmcnt(2)" ::: "memory");
    else            asm volatile("s_waitcnt vmcnt(0)" ::: "memory");
    ENDBAR;
  }
#undef MIDBAR
#undef ENDBAR

  const int rbase = m0 + wr * 64, cbase = n0 + wc * 64;
#pragma unroll
  for (int m = 0; m < 4; m++)
#pragma unroll
    for (int n = 0; n < 4; n++)
#pragma unroll
      for (int j = 0; j < 4; j++) {
        int r  = rbase + m * 16 + lg * 4 + j;
        int cc = cbase + n * 16 + l15;
        if constexpr (OUTF32) {
          reinterpret_cast<float*>(C)[(size_t)r * N + cc] = acc[m][n][j];
        } else {
          reinterpret_cast<u16*>(C)[(size_t)r * N + cc] = f2bf(acc[m][n][j]);
        }
      }
}

// ---------------- V transpose: qkv V-section -> vt[b][h][d][t] ----------------
__global__ __launch_bounds__(256) void k_vt(const u16* __restrict__ qkv,
                                            u16* __restrict__ vt) {
  __shared__ __align__(16) u16 tile[64 * 64];
  const int tb = blockIdx.x, h = blockIdx.y, b = blockIdx.z;
  const int tid = threadIdx.x;
  const size_t rb = (size_t)b * 2048;
  const int hv = 2048 + h * 64;
#pragma unroll
  for (int p = 0; p < 2; p++) {
    int r = p * 32 + (tid >> 3);
    int c = (tid & 7) * 8;
    u16x8 v = *reinterpret_cast<const u16x8*>(qkv + (rb + tb * 64 + r) * 3072 + hv + c);
    int slot = (c >> 3) ^ (r & 7) ^ ((r >> 3) & 7);
    *reinterpret_cast<u16x8*>(tile + r * 64 + slot * 8) = v;
  }
  __syncthreads();
#pragma unroll
  for (int p = 0; p < 2; p++) {
    int d = p * 32 + (tid >> 3);
    int t0 = (tid & 7) * 8;
    u16x8 v;
#pragma unroll
    for (int j = 0; j < 8; j++) {
      int r = t0 + j;
      int slot = (d >> 3) ^ (r & 7) ^ ((r >> 3) & 7);
      v[j] = tile[r * 64 + slot * 8 + (d & 7)];
    }
    *reinterpret_cast<u16x8*>(vt + ((size_t)(b * 16 + h) * 64 + d) * 2048 + tb * 64 + t0) = v;
  }
}

// ---------------- flash attention v7: mask-split + max3 ----------------
__global__ __launch_bounds__(256) void k_attn(const u16* __restrict__ qkv,
                                              const u16* __restrict__ vt,
                                              u16* __restrict__ aout) {
  __shared__ __align__(16) u16 Kl[2][64 * 64];   // [key][d], swizzled 16B slots
  __shared__ __align__(16) u16 Vl[2][64 * 64];   // [d][key], same swizzle
  const int tid = threadIdx.x, wave = tid >> 6, lane = tid & 63;
  const int l31 = lane & 31, half = lane >> 5;
  const int i = (int)blockIdx.x;
  const int b = i & 3, p = i >> 2;
  const int k4 = p >> 6, j4 = p & 63;
  const int ridx = (k4 == 0) ? j4 : (k4 == 1) ? 127 - j4 : (k4 == 2) ? 128 + j4 : 255 - j4;
  const int hqv = RANKTBL[ridx];
  const int h = hqv >> 4, qb = hqv & 15;
  const int rb = b * 2048;
  const int hq = h * 64, hk = 1024 + h * 64;
  const int bh64 = (b * 16 + h) * 64;
  const int qB = qb * 128;
  const int q0w = qB + wave * 32;
  const int q = q0w + l31;

  bf16x8 qf[4];
#pragma unroll
  for (int c = 0; c < 4; c++)
    qf[c] = *reinterpret_cast<const bf16x8*>(qkv + (size_t)(rb + q) * 3072 + hq + c * 16 + half * 8);

  const float slope2 = exp2f(-0.5f * (float)(h + 1)) * 1.44269504f;
  const float c0 = 0.18033688f;

  const int kend = min(2 * qb + 1, KBW[h]);

  float mrun = -1e30f, lrun = 0.f;
  f32x16 o0 = (f32x16)0.0f, o1 = (f32x16)0.0f;

  auto stage = [&](int kvr, int dst) {
#pragma unroll
    for (int i2 = 0; i2 < 2; i2++) {
      int row = (i2 * 4 + wave) * 8 + (lane >> 3);
      int scol = ((lane & 7) ^ (row & 7)) << 3;
      gload16(qkv + (size_t)(rb + kvr + row) * 3072 + hk + scol, &Kl[dst][(i2 * 4 + wave) * 512]);
      gload16(vt + (size_t)(bh64 + row) * 2048 + kvr + scol,     &Vl[dst][(i2 * 4 + wave) * 512]);
    }
  };

  stage(0, 0);
  __syncthreads();

  int bfi = 0;
  for (int kb = 0; kb <= kend; ++kb, bfi ^= 1) {
    const int kvr = kb * 64;
    if (kb < kend) stage(kvr + 64, bfi ^ 1);

    if (kvr <= q0w + 31) {
      f32x16 s[2];
#pragma unroll
      for (int t = 0; t < 2; t++) s[t] = (f32x16)0.0f;
      __builtin_amdgcn_s_setprio(1);
#pragma unroll
      for (int t = 0; t < 2; t++) {
        int r = t * 32 + l31;
#pragma unroll
        for (int cc = 0; cc < 4; cc++) {
          bf16x8 kf = *reinterpret_cast<const bf16x8*>(
              &Kl[bfi][r * 64 + (((cc * 2 + half) ^ (r & 7)) << 3)]);
          s[t] = mfma32(kf, qf[cc], s[t]);
        }
      }
      __builtin_amdgcn_s_setprio(0);

      const bool domask = (kvr + 63 > q0w);   // wave-uniform
      const int qrel = q - kvr - half * 4;
      const float qb0 = slope2 * (float)qrel;
      const float qb1 = qb0 - slope2 * 32.0f;
      float mt = -1e30f;
      if (domask) {
#pragma unroll
        for (int t = 0; t < 2; t++) {
          const float qbt = t ? qb1 : qb0;
          const int qmt = t ? (qrel - 32) : qrel;
#pragma unroll
          for (int r = 0; r < 16; r++) {
            const int krel = (r & 3) + 8 * (r >> 2);
            float val = fmaf(s[t][r], c0, fmaf(-slope2, (float)krel, qbt));
            val = (krel <= qmt) ? val : -3.0e38f;
            s[t][r] = val;
            mt = fmaxf(mt, val);
          }
        }
      } else {
#pragma unroll
        for (int t = 0; t < 2; t++) {
          const float qbt = t ? qb1 : qb0;
#pragma unroll
          for (int r = 0; r < 16; r += 2) {
            const int k0 = (r & 3) + 8 * (r >> 2);
            const int k1 = ((r + 1) & 3) + 8 * ((r + 1) >> 2);
            float v0 = fmaf(s[t][r],     c0, fmaf(-slope2, (float)k0, qbt));
            float v1 = fmaf(s[t][r + 1], c0, fmaf(-slope2, (float)k1, qbt));
            s[t][r] = v0; s[t][r + 1] = v1;
            mt = fmaxf(mt, fmaxf(v0, v1));   // max3-fusable
          }
        }
      }
      mt = fmaxf(mt, __shfl_xor(mt, 32));

      if (__any(mt - mrun > 8.0f)) {
        float mn = fmaxf(mrun, mt);
        float al = exp2f(mrun - mn);
        mrun = mn; lrun *= al;
#pragma unroll
        for (int r = 0; r < 16; r++) { o0[r] *= al; o1[r] *= al; }
      }

      float rs0 = 0.f, rs1 = 0.f;
#pragma unroll
      for (int t = 0; t < 2; t++)
#pragma unroll
        for (int r = 0; r < 16; r++) {
          float pp = exp2f(s[t][r] - mrun);
          s[t][r] = pp;
          if (t) rs1 += pp; else rs0 += pp;
        }
      float rs = rs0 + rs1;
      rs += __shfl_xor(rs, 32);
      lrun += rs;

      bf16x8 pf[4];
#pragma unroll
      for (int t = 0; t < 2; t++)
#pragma unroll
        for (int hs = 0; hs < 2; hs++) {
          u32 A0 = packbf(s[t][8 * hs + 0], s[t][8 * hs + 1]);
          u32 B0 = packbf(s[t][8 * hs + 2], s[t][8 * hs + 3]);
          u32 C0 = packbf(s[t][8 * hs + 4], s[t][8 * hs + 5]);
          u32 D0 = packbf(s[t][8 * hs + 6], s[t][8 * hs + 7]);
          asm volatile("v_permlane32_swap_b32 %0, %1" : "+v"(A0), "+v"(C0));
          asm volatile("v_permlane32_swap_b32 %0, %1" : "+v"(B0), "+v"(D0));
          u32x4 fr; fr[0] = A0; fr[1] = B0; fr[2] = C0; fr[3] = D0;
          pf[t * 2 + hs] = __builtin_bit_cast(bf16x8, fr);
        }

      __builtin_amdgcn_s_setprio(1);
#pragma unroll
      for (int dblk = 0; dblk < 2; dblk++) {
        int r = dblk * 32 + l31;
#pragma unroll
        for (int kc = 0; kc < 4; kc++) {
          bf16x8 vf = *reinterpret_cast<const bf16x8*>(
              &Vl[bfi][r * 64 + (((kc * 2 + half) ^ (r & 7)) << 3)]);
          if (dblk) o1 = mfma32(vf, pf[kc], o1);
          else      o0 = mfma32(vf, pf[kc], o0);
        }
      }
      __builtin_amdgcn_s_setprio(0);
    }
    __syncthreads();
  }

  const float linv = 1.0f / lrun;
#pragma unroll
  for (int dblk = 0; dblk < 2; dblk++)
#pragma unroll
    for (int rg = 0; rg < 4; rg++) {
      int d0 = dblk * 32 + 8 * rg + 4 * half;
      u16x4 r4;
#pragma unroll
      for (int j = 0; j < 4; j++) {
        float v = (dblk ? o1[rg * 4 + j] : o0[rg * 4 + j]) * linv;
        r4[j] = f2bf(v);
      }
      *reinterpret_cast<u16x4*>(aout + (size_t)(rb + q) * 3072 + hq + d0) = r4;
    }
}

extern "C" void kernel_launch(void* const* d_in, const int* in_sizes, int n_in,
                              void* d_out, int out_size, void* d_ws, size_t ws_size,
                              hipStream_t stream) {
  (void)in_sizes; (void)n_in; (void)out_size; (void)ws_size;
  const float* x  = (const float*)d_in[0];
  const float* Wq = (const float*)d_in[1];
  const float* Aq = (const float*)d_in[2];
  const float* Bq = (const float*)d_in[3];
  const float* Wk = (const float*)d_in[4];
  const float* Ak = (const float*)d_in[5];
  const float* Bk = (const float*)d_in[6];
  const float* Wv = (const float*)d_in[7];
  const float* Av = (const float*)d_in[8];
  const float* Bv = (const float*)d_in[9];
  const float* Wp = (const float*)d_in[10];

  char* ws = (char*)d_ws;
  u16* xb   = (u16*)(ws);                  // [8192][1024] bf16 (dead after gemm1)
  u16* wqkv = (u16*)(ws + 16777216);       // [3072][1024] bf16
  u16* wp   = (u16*)(ws + 23068672);       // [1024][1024] bf16
  u16* qkv  = (u16*)(ws + 25165824);       // [8192][3072] bf16
  u16* vt   = xb;                          // [4][16][64][2048] bf16, reuses xb
  float* out = (float*)d_out;

  k_castfold<<<dim3(8192), dim3(256), 0, stream>>>(x, xb, Wq, Aq, Bq, Wk, Ak, Bk,
                                                   Wv, Av, Bv, Wp, wqkv, wp);
  // QKV GEMM: M=8192 N=3072 K=1024 -> grid 32x12 = 384 blocks (256^2 tile)
  k_gemm256<0><<<dim3(384), dim3(512), 0, stream>>>(xb, wqkv, (void*)qkv, 1024, 3072, 1024, 32);
  k_vt<<<dim3(32, 16, 4), dim3(256), 0, stream>>>(qkv, vt);
  // attention writes its output into qkv's Q-columns (in-place, stride 3072)
  k_attn<<<dim3(1024), dim3(256), 0, stream>>>(qkv, vt, qkv);
  // output GEMM: M=8192 N=1024 K=1024 -> grid 64x4 = 256 blocks (1/CU exact)
  k_gemm8<1><<<dim3(256), dim3(512), 0, stream>>>(qkv, wp, (void*)out, 1024, 1024, 3072, 64);
}